// Round 1
// baseline (95.370 us; speedup 1.0000x reference)
//
#include <hip/hip_runtime.h>
#include <math.h>

#define NP 30      // points per cloud
#define KNN 20     // neighbors
#define KS 5       // spline control points
#define FN 10      // filter count
#define EPS 1e-8f
#define CPB 8      // clouds per block (kernel 1)
#define T1 256     // block size kernel 1

// Kernel 1: per-point directional spline conv -> sigmoid -> per-cloud mean.
// One thread per point; CPB clouds per 256-thread block (240 active lanes).
__global__ __launch_bounds__(T1) void dsc_kernel(
    const float* __restrict__ pos,     // [B*NP, 3]
    const float* __restrict__ W,       // [KS, FN]
    const float* __restrict__ b_dsc,   // [FN]
    float* __restrict__ ys,            // [B, FN] out
    int B)
{
    __shared__ float pts[CPB * NP * 3];
    __shared__ float sbuf[CPB * NP][FN];

    const int tid  = threadIdx.x;
    const int base = blockIdx.x * CPB;          // first cloud of this block

    // stage this block's point coordinates into LDS (coalesced)
    for (int idx = tid; idx < CPB * NP * 3; idx += T1) {
        pts[idx] = pos[(size_t)base * NP * 3 + idx];
    }
    __syncthreads();

    const int c = tid / NP;       // local cloud
    const int i = tid - c * NP;   // point within cloud
    const bool active = (tid < CPB * NP) && (base + c < B);

    if (active) {
        const float* cp = &pts[c * NP * 3];
        const float xi = cp[i * 3 + 0];
        const float yi = cp[i * 3 + 1];
        const float zi = cp[i * 3 + 2];

        // --- squared distances (self forced huge, like ref's +1e10*eye) ---
        float d2[NP];
        #pragma unroll
        for (int j = 0; j < NP; ++j) {
            float dx = cp[j * 3 + 0] - xi;
            float dy = cp[j * 3 + 1] - yi;
            float dz = cp[j * 3 + 2] - zi;
            float dd = dx * dx + dy * dy + dz * dz;
            d2[j] = (j == i) ? 1e10f : dd;
        }

        // --- kNN: exclude the (NP-KNN)=10 LARGEST (self is among them). ---
        // Static inner indices -> d2 stays in VGPRs (no scratch).
        unsigned excl = 0u;
        for (int it = 0; it < NP - KNN; ++it) {
            float vmax = -1.0f;
            int mi = 0;
            #pragma unroll
            for (int j = 0; j < NP; ++j) {
                bool skip = (excl >> j) & 1u;
                if (!skip && d2[j] > vmax) { vmax = d2[j]; mi = j; }
            }
            excl |= (1u << mi);
        }

        // max squared distance among the selected 20
        float d2max = 0.0f;
        #pragma unroll
        for (int j = 0; j < NP; ++j) {
            if (!((excl >> j) & 1u)) d2max = fmaxf(d2max, d2[j]);
        }
        const float scale = sqrtf(d2max + EPS) + EPS;  // max norm + EPS
        const float inv_s = 1.0f / scale;

        // --- pass A: covariance of normalized rels (6 unique terms) ---
        float cxx = 0.f, cxy = 0.f, cxz = 0.f, cyy = 0.f, cyz = 0.f, czz = 0.f;
        #pragma unroll
        for (int j = 0; j < NP; ++j) {
            if ((excl >> j) & 1u) continue;
            float dx = (cp[j * 3 + 0] - xi) * inv_s;
            float dy = (cp[j * 3 + 1] - yi) * inv_s;
            float dz = (cp[j * 3 + 2] - zi) * inv_s;
            cxx += dx * dx; cxy += dx * dy; cxz += dx * dz;
            cyy += dy * dy; cyz += dy * dz; czz += dz * dz;
        }

        // --- power iteration (8 steps) for dominant direction ---
        float vx = 0.57735027f, vy = 0.57735027f, vz = 0.57735027f;
        #pragma unroll
        for (int it = 0; it < 8; ++it) {
            float nx = cxx * vx + cxy * vy + cxz * vz;
            float ny = cxy * vx + cyy * vy + cyz * vz;
            float nz = cxz * vx + cyz * vy + czz * vz;
            float nrm = sqrtf(nx * nx + ny * ny + nz * nz) + EPS;
            float r = 1.0f / nrm;
            vx = nx * r; vy = ny * r; vz = nz * r;
        }

        // --- pass B: spline parameter -> per-control-point weight sums ---
        float a[KS] = {0.f, 0.f, 0.f, 0.f, 0.f};
        #pragma unroll
        for (int j = 0; j < NP; ++j) {
            if ((excl >> j) & 1u) continue;
            float dx = (cp[j * 3 + 0] - xi) * inv_s;
            float dy = (cp[j * 3 + 1] - yi) * inv_s;
            float dz = (cp[j * 3 + 2] - zi) * inv_s;
            float t = dx * vx + dy * vy + dz * vz;
            float u = fminf(fmaxf((t + 1.0f) * 0.5f, 0.0f), 1.0f) * (float)(KS - 1);
            float fl = fminf(floorf(u), (float)(KS - 2));   // clip to [0, KS-2]
            int   i0 = (int)fl;
            float frac = u - fl;
            float wlo = 1.0f - frac;
            #pragma unroll
            for (int b = 0; b < KS; ++b) {
                a[b] += (b == i0 ? wlo : 0.0f) + (b == i0 + 1 ? frac : 0.0f);
            }
        }

        // --- y = (sum_b a_b * W_b)/K + b_dsc ; sigmoid ---
        #pragma unroll
        for (int f = 0; f < FN; ++f) {
            float acc = 0.0f;
            #pragma unroll
            for (int b = 0; b < KS; ++b) acc += a[b] * W[b * FN + f];
            float y = acc * (1.0f / (float)KNN) + b_dsc[f];
            sbuf[tid][f] = 1.0f / (1.0f + expf(-y));
        }
    }
    __syncthreads();

    // reduce sigmoid features over the NP points of each cloud
    if (tid < CPB * FN) {
        int c2 = tid / FN;
        int f  = tid - c2 * FN;
        if (base + c2 < B) {
            float sum = 0.0f;
            #pragma unroll
            for (int j = 0; j < NP; ++j) sum += sbuf[c2 * NP + j][f];
            ys[(size_t)(base + c2) * FN + f] = sum * (1.0f / (float)NP);
        }
    }
}

// Kernel 2: per-cloud MLP head: elu(ys@w1+b1) @ w2 + b2 -> log_softmax.
// One 256-thread block per cloud.
__global__ __launch_bounds__(256) void head_kernel(
    const float* __restrict__ ys,   // [B, FN]
    const float* __restrict__ w1,   // [FN, 256]
    const float* __restrict__ b1,   // [256]
    const float* __restrict__ w2,   // [256, 40]
    const float* __restrict__ b2,   // [40]
    float* __restrict__ out)        // [B, 40]
{
    const int b = blockIdx.x;
    const int t = threadIdx.x;

    __shared__ float h[256];
    __shared__ float yv[FN];
    if (t < FN) yv[t] = ys[(size_t)b * FN + t];
    __syncthreads();

    // hidden layer: h[t] = elu(ys . w1[:,t] + b1[t])
    float acc = b1[t];
    #pragma unroll
    for (int f = 0; f < FN; ++f) acc += yv[f] * w1[f * 256 + t];
    h[t] = (acc > 0.0f) ? acc : expm1f(acc);
    __syncthreads();

    if (t < 64) {
        float logit = -INFINITY;
        if (t < 40) {
            float l = b2[t];
            for (int j = 0; j < 256; ++j) l += h[j] * w2[j * 40 + t];
            logit = l;
        }
        // wave-wide (64-lane) reductions; lanes >= 40 hold -inf / 0
        float m = logit;
        #pragma unroll
        for (int off = 32; off >= 1; off >>= 1) m = fmaxf(m, __shfl_xor(m, off));
        float e = (t < 40) ? expf(logit - m) : 0.0f;
        float s = e;
        #pragma unroll
        for (int off = 32; off >= 1; off >>= 1) s += __shfl_xor(s, off);
        if (t < 40) out[(size_t)b * 40 + t] = logit - m - logf(s);
    }
}

extern "C" void kernel_launch(void* const* d_in, const int* in_sizes, int n_in,
                              void* d_out, int out_size, void* d_ws, size_t ws_size,
                              hipStream_t stream) {
    const float* pos   = (const float*)d_in[0];
    const float* W     = (const float*)d_in[1];
    const float* b_dsc = (const float*)d_in[2];
    const float* w1    = (const float*)d_in[3];
    const float* b1    = (const float*)d_in[4];
    const float* w2    = (const float*)d_in[5];
    const float* b2    = (const float*)d_in[6];

    const int N = in_sizes[0] / 3;   // B*NP points
    const int B = N / NP;            // clouds

    float* ys = (float*)d_ws;        // [B, FN] scratch

    const int grid1 = (B + CPB - 1) / CPB;
    dsc_kernel<<<grid1, T1, 0, stream>>>(pos, W, b_dsc, ys, B);
    head_kernel<<<B, 256, 0, stream>>>(ys, w1, b1, w2, b2, (float*)d_out);
}

// Round 2
// 72.690 us; speedup vs baseline: 1.3120x; 1.3120x over previous
//
#include <hip/hip_runtime.h>
#include <math.h>

#define NP 30      // points per cloud
#define KNN 20     // neighbors
#define KS 5       // spline control points
#define FN 10      // filter count
#define EPS 1e-8f
#define CPB 8      // clouds per block (kernel 1)
#define T1 256     // block size kernel 1
#define HC 4       // clouds per block (head)

// Kernel 1: per-point directional spline conv -> sigmoid -> per-cloud mean.
__global__ __launch_bounds__(T1) void dsc_kernel(
    const float* __restrict__ pos,     // [B*NP, 3]
    const float* __restrict__ W,       // [KS, FN]
    const float* __restrict__ b_dsc,   // [FN]
    float* __restrict__ ys,            // [B, FN] out
    int B)
{
    __shared__ float pts[CPB][92];          // 90 floats/cloud, padded to 16B mult
    __shared__ float sbuf[CPB * NP][FN + 1]; // +1 pad against bank conflicts
    __shared__ float wS[KS * FN];
    __shared__ float bS[FN];

    const int tid  = threadIdx.x;
    const int base = blockIdx.x * CPB;

    // stage points (coalesced global read)
    for (int g = tid; g < CPB * NP * 3; g += T1) {
        int c   = g / 90;
        int off = g - c * 90;
        pts[c][off] = pos[(size_t)base * 90 + g];
    }
    if (tid < KS * FN) wS[tid] = W[tid];
    if (tid < FN)      bS[tid] = b_dsc[tid];
    __syncthreads();

    const int c = tid / NP;
    const int i = tid - c * NP;
    const bool active = (tid < CPB * NP) && (base + c < B);

    if (active) {
        // cloud points LDS -> registers (all further indexing is static)
        float p[92];
        {
            const float4* cp4 = (const float4*)pts[c];
            #pragma unroll
            for (int r = 0; r < 23; ++r) {
                float4 q = cp4[r];
                p[4*r+0] = q.x; p[4*r+1] = q.y; p[4*r+2] = q.z; p[4*r+3] = q.w;
            }
        }
        // own coords via LDS (dynamic index must NOT touch the register array)
        const float xi = pts[c][3*i+0];
        const float yi = pts[c][3*i+1];
        const float zi = pts[c][3*i+2];

        // --- squared distances into sort array (self forced huge) ---
        float vals[32];
        #pragma unroll
        for (int j = 0; j < NP; ++j) {
            float dx = p[3*j+0] - xi, dy = p[3*j+1] - yi, dz = p[3*j+2] - zi;
            float dd = fmaf(dz, dz, fmaf(dy, dy, dx * dx));
            vals[j] = (j == i) ? 1e10f : dd;
        }
        vals[30] = 1e11f;
        vals[31] = 1e11f;

        // --- bitonic sort (32, ascending), fully static -> registers ---
        #pragma unroll
        for (int k = 2; k <= 32; k <<= 1) {
            #pragma unroll
            for (int jj = k >> 1; jj > 0; jj >>= 1) {
                #pragma unroll
                for (int tt = 0; tt < 32; ++tt) {
                    int l = tt ^ jj;
                    if (l > tt) {
                        float a  = vals[tt], b = vals[l];
                        float lo = fminf(a, b), hi = fmaxf(a, b);
                        if ((tt & k) == 0) { vals[tt] = lo; vals[l] = hi; }
                        else               { vals[tt] = hi; vals[l] = lo; }
                    }
                }
            }
        }
        const float thr   = vals[KNN - 1];           // 20th-smallest d2 = max selected
        const float scale = sqrtf(thr + EPS) + EPS;  // max norm + EPS (sqrt monotone)
        const float inv_s = __builtin_amdgcn_rcpf(scale);

        // --- pass A: covariance of raw rels (scale-invariant), keep mask ---
        // self: dd=0 <= thr -> kept, but rel=(0,0,0) contributes nothing.
        float cxx=0.f, cxy=0.f, cxz=0.f, cyy=0.f, cyz=0.f, czz=0.f;
        unsigned keep = 0u;
        #pragma unroll
        for (int j = 0; j < NP; ++j) {
            float dx = p[3*j+0] - xi, dy = p[3*j+1] - yi, dz = p[3*j+2] - zi;
            float dd = fmaf(dz, dz, fmaf(dy, dy, dx * dx));
            bool  sel = (dd <= thr);
            keep |= sel ? (1u << j) : 0u;
            float mx = sel ? dx : 0.0f;
            float my = sel ? dy : 0.0f;
            float mz = sel ? dz : 0.0f;
            cxx = fmaf(mx, mx, cxx); cxy = fmaf(mx, my, cxy); cxz = fmaf(mx, mz, cxz);
            cyy = fmaf(my, my, cyy); cyz = fmaf(my, mz, cyz); czz = fmaf(mz, mz, czz);
        }

        // --- power iteration (8 steps); direction invariant to cov scaling ---
        float vx = 0.57735027f, vy = 0.57735027f, vz = 0.57735027f;
        #pragma unroll
        for (int it = 0; it < 8; ++it) {
            float nx = fmaf(cxx, vx, fmaf(cxy, vy, cxz * vz));
            float ny = fmaf(cxy, vx, fmaf(cyy, vy, cyz * vz));
            float nz = fmaf(cxz, vx, fmaf(cyz, vy, czz * vz));
            float nn = fmaf(nz, nz, fmaf(ny, ny, nx * nx));
            float r  = __builtin_amdgcn_rcpf(sqrtf(nn) + EPS);
            vx = nx * r; vy = ny * r; vz = nz * r;
        }

        // --- pass B: spline parameter -> hat-function bin accumulation ---
        float a0=0.f, a1=0.f, a2=0.f, a3=0.f, a4=0.f;
        #pragma unroll
        for (int j = 0; j < NP; ++j) {
            float dx = p[3*j+0] - xi, dy = p[3*j+1] - yi, dz = p[3*j+2] - zi;
            float t  = fmaf(dz, vz, fmaf(dy, vy, dx * vx)) * inv_s;
            float u  = fminf(fmaxf(fmaf(t, 0.5f, 0.5f), 0.0f), 1.0f) * 4.0f;
            u = ((keep >> j) & 1u) ? u : 1e9f;   // excluded -> all hats zero
            a0 += fmaxf(0.0f, 1.0f - fabsf(u - 0.0f));
            a1 += fmaxf(0.0f, 1.0f - fabsf(u - 1.0f));
            a2 += fmaxf(0.0f, 1.0f - fabsf(u - 2.0f));
            a3 += fmaxf(0.0f, 1.0f - fabsf(u - 3.0f));
            a4 += fmaxf(0.0f, 1.0f - fabsf(u - 4.0f));
        }
        a2 -= 1.0f;  // self had t=0 -> u=2.0 exactly -> contributed 1.0 to a2

        // --- y = (sum_b a_b * W_b)/K + b_dsc ; sigmoid ---
        #pragma unroll
        for (int f = 0; f < FN; ++f) {
            float acc = fmaf(a0, wS[0*FN+f],
                        fmaf(a1, wS[1*FN+f],
                        fmaf(a2, wS[2*FN+f],
                        fmaf(a3, wS[3*FN+f],
                             a4 * wS[4*FN+f]))));
            float y = fmaf(acc, 1.0f / (float)KNN, bS[f]);
            sbuf[tid][f] = __builtin_amdgcn_rcpf(1.0f + expf(-y));
        }
    }
    __syncthreads();

    // reduce sigmoid features over the NP points of each cloud
    if (tid < CPB * FN) {
        int c2 = tid / FN;
        int f  = tid - c2 * FN;
        if (base + c2 < B) {
            float s = 0.0f;
            #pragma unroll
            for (int jj = 0; jj < NP; ++jj) s += sbuf[c2 * NP + jj][f];
            ys[(size_t)(base + c2) * FN + f] = s * (1.0f / (float)NP);
        }
    }
}

// Kernel 2: per-cloud MLP head, 4 clouds per 256-thread block.
__global__ __launch_bounds__(256) void head_kernel(
    const float* __restrict__ ys,   // [B, FN]
    const float* __restrict__ w1,   // [FN, 256]
    const float* __restrict__ b1,   // [256]
    const float* __restrict__ w2,   // [256, 40]
    const float* __restrict__ b2,   // [40]
    float* __restrict__ out,        // [B, 40]
    int B)
{
    __shared__ float hb[HC][256];
    __shared__ float w2s[256 * 40];
    __shared__ float yv[HC][FN];

    const int t  = threadIdx.x;
    const int b0 = blockIdx.x * HC;

    if (t < HC * FN) {
        int cc = t / FN, f = t - cc * FN;
        yv[cc][f] = (b0 + cc < B) ? ys[(size_t)(b0 + cc) * FN + f] : 0.0f;
    }
    // stage w2 into LDS (2560 float4, 10 per thread, coalesced)
    {
        const float4* s = (const float4*)w2;
        float4*       d = (float4*)w2s;
        #pragma unroll
        for (int r = 0; r < 10; ++r) d[t + 256 * r] = s[t + 256 * r];
    }
    __syncthreads();

    // layer 1: h[c][t] for 4 clouds
    {
        float wv[FN];
        #pragma unroll
        for (int f = 0; f < FN; ++f) wv[f] = w1[f * 256 + t];
        float bb = b1[t];
        #pragma unroll
        for (int cc = 0; cc < HC; ++cc) {
            float acc = bb;
            #pragma unroll
            for (int f = 0; f < FN; ++f) acc = fmaf(yv[cc][f], wv[f], acc);
            hb[cc][t] = acc > 0.0f ? acc : expm1f(acc);
        }
    }
    __syncthreads();

    // layer 2 + log_softmax: wave w handles cloud b0+w; lanes 0..39 = classes
    const int w    = t >> 6;
    const int lane = t & 63;
    const int col  = lane < 40 ? lane : 39;   // clamp to stay in-bounds
    float acc = b2[col];
    #pragma unroll 4
    for (int q = 0; q < 64; ++q) {
        float4 h4 = ((const float4*)hb[w])[q];
        acc = fmaf(h4.x, w2s[(4*q+0)*40 + col], acc);
        acc = fmaf(h4.y, w2s[(4*q+1)*40 + col], acc);
        acc = fmaf(h4.z, w2s[(4*q+2)*40 + col], acc);
        acc = fmaf(h4.w, w2s[(4*q+3)*40 + col], acc);
    }
    float logit = (lane < 40) ? acc : -INFINITY;
    float m = logit;
    #pragma unroll
    for (int off = 32; off >= 1; off >>= 1) m = fmaxf(m, __shfl_xor(m, off));
    float e = (lane < 40) ? expf(logit - m) : 0.0f;
    float s = e;
    #pragma unroll
    for (int off = 32; off >= 1; off >>= 1) s += __shfl_xor(s, off);
    if (lane < 40 && b0 + w < B)
        out[(size_t)(b0 + w) * 40 + lane] = logit - m - logf(s);
}

extern "C" void kernel_launch(void* const* d_in, const int* in_sizes, int n_in,
                              void* d_out, int out_size, void* d_ws, size_t ws_size,
                              hipStream_t stream) {
    const float* pos   = (const float*)d_in[0];
    const float* W     = (const float*)d_in[1];
    const float* b_dsc = (const float*)d_in[2];
    const float* w1    = (const float*)d_in[3];
    const float* b1    = (const float*)d_in[4];
    const float* w2    = (const float*)d_in[5];
    const float* b2    = (const float*)d_in[6];

    const int N = in_sizes[0] / 3;   // B*NP points
    const int B = N / NP;            // clouds

    float* ys = (float*)d_ws;        // [B, FN] scratch

    const int grid1 = (B + CPB - 1) / CPB;
    dsc_kernel<<<grid1, T1, 0, stream>>>(pos, W, b_dsc, ys, B);
    const int grid2 = (B + HC - 1) / HC;
    head_kernel<<<grid2, 256, 0, stream>>>(ys, w1, b1, w2, b2, (float*)d_out, B);
}

// Round 3
// 56.511 us; speedup vs baseline: 1.6876x; 1.2863x over previous
//
#include <hip/hip_runtime.h>
#include <math.h>

#define NP 30      // points per cloud
#define KNN 20     // neighbors
#define KS 5       // spline control points
#define FN 10      // filter count
#define EPS 1e-8f
#define CPB 8      // clouds per block (kernel 1)
#define T1 256     // block size kernel 1
#define HCB 16     // clouds per block (head)

// Kernel 1: per-point directional spline conv -> sigmoid -> per-cloud mean.
__global__ __launch_bounds__(T1) void dsc_kernel(
    const float* __restrict__ pos,     // [B*NP, 3]
    const float* __restrict__ W,       // [KS, FN]
    const float* __restrict__ b_dsc,   // [FN]
    float* __restrict__ ys,            // [B, FN] out
    int B)
{
    __shared__ float pts[CPB][92];            // 90 floats/cloud, pad to 16B mult
    __shared__ float sbuf[CPB * NP][FN + 1];  // +1 pad against bank conflicts
    __shared__ float wS[KS * FN];
    __shared__ float bS[FN];

    const int tid  = threadIdx.x;
    const int base = blockIdx.x * CPB;

    for (int g = tid; g < CPB * NP * 3; g += T1) {
        int c   = g / 90;
        int off = g - c * 90;
        pts[c][off] = pos[(size_t)base * 90 + g];
    }
    if (tid < KS * FN) wS[tid] = W[tid];
    if (tid < FN)      bS[tid] = b_dsc[tid];
    __syncthreads();

    const int c = tid / NP;
    const int i = tid - c * NP;
    const bool active = (tid < CPB * NP) && (base + c < B);

    if (active) {
        float p[92];
        {
            const float4* cp4 = (const float4*)pts[c];
            #pragma unroll
            for (int r = 0; r < 23; ++r) {
                float4 q = cp4[r];
                p[4*r+0] = q.x; p[4*r+1] = q.y; p[4*r+2] = q.z; p[4*r+3] = q.w;
            }
        }
        // own coords via LDS (dynamic index must NOT touch the register array)
        const float xi = pts[c][3*i+0];
        const float yi = pts[c][3*i+1];
        const float zi = pts[c][3*i+2];

        // --- squared distances; self computes exactly 0 (always rank 0) ---
        float vals[32];
        #pragma unroll
        for (int j = 0; j < NP; ++j) {
            float dx = p[3*j+0] - xi, dy = p[3*j+1] - yi, dz = p[3*j+2] - zi;
            vals[j] = fmaf(dz, dz, fmaf(dy, dy, dx * dx));
        }
        vals[30] = 1e11f;
        vals[31] = 1e11f;

        // --- bitonic stages k=2..16 (full), fully static -> registers ---
        #pragma unroll
        for (int k = 2; k <= 16; k <<= 1) {
            #pragma unroll
            for (int jj = k >> 1; jj > 0; jj >>= 1) {
                #pragma unroll
                for (int tt = 0; tt < 32; ++tt) {
                    int l = tt ^ jj;
                    if (l > tt) {
                        float a  = vals[tt], b = vals[l];
                        float lo = fminf(a, b), hi = fmaxf(a, b);
                        if ((tt & k) == 0) { vals[tt] = lo; vals[l] = hi; }
                        else               { vals[tt] = hi; vals[l] = lo; }
                    }
                }
            }
        }
        // --- final merge stage (k=32, ascending) pruned to output idx 20 ---
        // j=16: need hi side at 16..31
        #pragma unroll
        for (int q = 0; q < 16; ++q) vals[16+q] = fmaxf(vals[q], vals[16+q]);
        // j=8: need lo side at 16..23
        #pragma unroll
        for (int q = 0; q < 8; ++q)  vals[16+q] = fminf(vals[16+q], vals[24+q]);
        // j=4: need hi side at 20..23
        #pragma unroll
        for (int q = 0; q < 4; ++q)  vals[20+q] = fmaxf(vals[16+q], vals[20+q]);
        // j=2: need lo side at 20,21
        vals[20] = fminf(vals[20], vals[22]);
        vals[21] = fminf(vals[21], vals[23]);
        // j=1: output 20
        const float thr = fminf(vals[20], vals[21]);   // 20th-smallest non-self d2

        const float scale = sqrtf(thr + EPS) + EPS;    // max selected norm + EPS
        const float inv_s = __builtin_amdgcn_rcpf(scale);

        // --- pass A: covariance of raw rels (scale-invariant), keep mask ---
        // self: dd=0 <= thr -> kept; rel=(0,0,0) contributes nothing to cov.
        float cxx=0.f, cxy=0.f, cxz=0.f, cyy=0.f, cyz=0.f, czz=0.f;
        unsigned keep = 0u;
        #pragma unroll
        for (int j = 0; j < NP; ++j) {
            float dx = p[3*j+0] - xi, dy = p[3*j+1] - yi, dz = p[3*j+2] - zi;
            float dd = fmaf(dz, dz, fmaf(dy, dy, dx * dx));
            bool  sel = (dd <= thr);
            keep |= sel ? (1u << j) : 0u;
            float mx = sel ? dx : 0.0f;
            float my = sel ? dy : 0.0f;
            float mz = sel ? dz : 0.0f;
            cxx = fmaf(mx, mx, cxx); cxy = fmaf(mx, my, cxy); cxz = fmaf(mx, mz, cxz);
            cyy = fmaf(my, my, cyy); cyz = fmaf(my, mz, cyz); czz = fmaf(mz, mz, czz);
        }

        // --- power iteration (8 steps); direction invariant to cov scaling ---
        float vx = 0.57735027f, vy = 0.57735027f, vz = 0.57735027f;
        #pragma unroll
        for (int it = 0; it < 8; ++it) {
            float nx = fmaf(cxx, vx, fmaf(cxy, vy, cxz * vz));
            float ny = fmaf(cxy, vx, fmaf(cyy, vy, cyz * vz));
            float nz = fmaf(cxz, vx, fmaf(cyz, vy, czz * vz));
            float nn = fmaf(nz, nz, fmaf(ny, ny, nx * nx));
            float r  = __builtin_amdgcn_rcpf(sqrtf(nn) + EPS);
            vx = nx * r; vy = ny * r; vz = nz * r;
        }

        // --- pass B: spline parameter -> hat-function bin accumulation ---
        float a0=0.f, a1=0.f, a2=0.f, a3=0.f, a4=0.f;
        #pragma unroll
        for (int j = 0; j < NP; ++j) {
            float dx = p[3*j+0] - xi, dy = p[3*j+1] - yi, dz = p[3*j+2] - zi;
            float t  = fmaf(dz, vz, fmaf(dy, vy, dx * vx)) * inv_s;
            float u  = fminf(fmaxf(fmaf(t, 0.5f, 0.5f), 0.0f), 1.0f) * 4.0f;
            u = ((keep >> j) & 1u) ? u : 1e9f;   // excluded -> all hats zero
            a0 += fmaxf(0.0f, 1.0f - fabsf(u - 0.0f));
            a1 += fmaxf(0.0f, 1.0f - fabsf(u - 1.0f));
            a2 += fmaxf(0.0f, 1.0f - fabsf(u - 2.0f));
            a3 += fmaxf(0.0f, 1.0f - fabsf(u - 3.0f));
            a4 += fmaxf(0.0f, 1.0f - fabsf(u - 4.0f));
        }
        a2 -= 1.0f;  // self: t=0 -> u=2.0 exactly -> contributed 1.0 to a2

        #pragma unroll
        for (int f = 0; f < FN; ++f) {
            float acc = fmaf(a0, wS[0*FN+f],
                        fmaf(a1, wS[1*FN+f],
                        fmaf(a2, wS[2*FN+f],
                        fmaf(a3, wS[3*FN+f],
                             a4 * wS[4*FN+f]))));
            float y = fmaf(acc, 1.0f / (float)KNN, bS[f]);
            sbuf[tid][f] = __builtin_amdgcn_rcpf(1.0f + expf(-y));
        }
    }
    __syncthreads();

    if (tid < CPB * FN) {
        int c2 = tid / FN;
        int f  = tid - c2 * FN;
        if (base + c2 < B) {
            float s = 0.0f;
            #pragma unroll
            for (int jj = 0; jj < NP; ++jj) s += sbuf[c2 * NP + jj][f];
            ys[(size_t)(base + c2) * FN + f] = s * (1.0f / (float)NP);
        }
    }
}

// Kernel 2: MLP head, 16 clouds/block. Layer 2: K=256 split across 4 waves,
// w2 sub-columns held in registers (reused across all 16 clouds).
__global__ __launch_bounds__(256) void head_kernel(
    const float* __restrict__ ys,   // [B, FN]
    const float* __restrict__ w1,   // [FN, 256]
    const float* __restrict__ b1,   // [256]
    const float* __restrict__ w2,   // [256, 40]
    const float* __restrict__ b2,   // [40]
    float* __restrict__ out,        // [B, 40]
    int B)
{
    __shared__ float ysS[HCB][12];
    __shared__ float hS[HCB][256];
    __shared__ float pS[HCB][4][40];

    const int t    = threadIdx.x;
    const int b0   = blockIdx.x * HCB;
    const int w    = t >> 6;
    const int lane = t & 63;
    const int col  = lane < 40 ? lane : 39;   // clamped (inactive lanes harmless)

    // w2 sub-column -> registers (no dependence on LDS; issues early)
    float wreg[64];
    #pragma unroll
    for (int q = 0; q < 64; ++q) wreg[q] = w2[(w * 64 + q) * 40 + col];

    // stage ys for the block's 16 clouds
    if (t < HCB * FN) {
        int cc = t / FN, f = t - cc * FN;
        ysS[cc][f] = (b0 * FN + t < B * FN) ? ys[(size_t)b0 * FN + t] : 0.0f;
    }
    __syncthreads();

    // layer 1: thread t = hidden unit t, loop over 16 clouds
    {
        float wv[FN];
        #pragma unroll
        for (int f = 0; f < FN; ++f) wv[f] = w1[f * 256 + t];
        float bb = b1[t];
        for (int cc = 0; cc < HCB; ++cc) {
            float acc = bb;
            #pragma unroll
            for (int f = 0; f < FN; ++f) acc = fmaf(ysS[cc][f], wv[f], acc);
            hS[cc][t] = acc > 0.0f ? acc : expm1f(acc);
        }
    }
    __syncthreads();

    // layer 2 partials: wave w covers k in [64w, 64w+64); 4-cloud groups for ILP
    for (int cg = 0; cg < HCB; cg += 4) {
        float a0 = 0.f, a1 = 0.f, a2 = 0.f, a3 = 0.f;
        #pragma unroll
        for (int q = 0; q < 64; q += 4) {
            float4 h0 = *(const float4*)&hS[cg + 0][w * 64 + q];
            float4 h1 = *(const float4*)&hS[cg + 1][w * 64 + q];
            float4 h2 = *(const float4*)&hS[cg + 2][w * 64 + q];
            float4 h3 = *(const float4*)&hS[cg + 3][w * 64 + q];
            a0 = fmaf(h0.x, wreg[q+0], a0); a1 = fmaf(h1.x, wreg[q+0], a1);
            a2 = fmaf(h2.x, wreg[q+0], a2); a3 = fmaf(h3.x, wreg[q+0], a3);
            a0 = fmaf(h0.y, wreg[q+1], a0); a1 = fmaf(h1.y, wreg[q+1], a1);
            a2 = fmaf(h2.y, wreg[q+1], a2); a3 = fmaf(h3.y, wreg[q+1], a3);
            a0 = fmaf(h0.z, wreg[q+2], a0); a1 = fmaf(h1.z, wreg[q+2], a1);
            a2 = fmaf(h2.z, wreg[q+2], a2); a3 = fmaf(h3.z, wreg[q+2], a3);
            a0 = fmaf(h0.w, wreg[q+3], a0); a1 = fmaf(h1.w, wreg[q+3], a1);
            a2 = fmaf(h2.w, wreg[q+3], a2); a3 = fmaf(h3.w, wreg[q+3], a3);
        }
        if (lane < 40) {
            pS[cg + 0][w][lane] = a0;
            pS[cg + 1][w][lane] = a1;
            pS[cg + 2][w][lane] = a2;
            pS[cg + 3][w][lane] = a3;
        }
    }
    __syncthreads();

    // reduce partials + log_softmax: wave w -> clouds 4w..4w+3
    const float bcol = (lane < 40) ? b2[lane] : 0.0f;
    for (int g = 0; g < 4; ++g) {
        int cc = w * 4 + g;
        float logit = -INFINITY;
        if (lane < 40) {
            logit = bcol + pS[cc][0][lane] + pS[cc][1][lane]
                         + pS[cc][2][lane] + pS[cc][3][lane];
        }
        float m = logit;
        #pragma unroll
        for (int off = 32; off >= 1; off >>= 1) m = fmaxf(m, __shfl_xor(m, off));
        float e = (lane < 40) ? expf(logit - m) : 0.0f;
        float s = e;
        #pragma unroll
        for (int off = 32; off >= 1; off >>= 1) s += __shfl_xor(s, off);
        if (lane < 40 && b0 + cc < B)
            out[(size_t)(b0 + cc) * 40 + lane] = logit - m - logf(s);
    }
}

extern "C" void kernel_launch(void* const* d_in, const int* in_sizes, int n_in,
                              void* d_out, int out_size, void* d_ws, size_t ws_size,
                              hipStream_t stream) {
    const float* pos   = (const float*)d_in[0];
    const float* W     = (const float*)d_in[1];
    const float* b_dsc = (const float*)d_in[2];
    const float* w1    = (const float*)d_in[3];
    const float* b1    = (const float*)d_in[4];
    const float* w2    = (const float*)d_in[5];
    const float* b2    = (const float*)d_in[6];

    const int N = in_sizes[0] / 3;   // B*NP points
    const int B = N / NP;            // clouds

    float* ys = (float*)d_ws;        // [B, FN] scratch

    const int grid1 = (B + CPB - 1) / CPB;
    dsc_kernel<<<grid1, T1, 0, stream>>>(pos, W, b_dsc, ys, B);
    const int grid2 = (B + HCB - 1) / HCB;
    head_kernel<<<grid2, 256, 0, stream>>>(ys, w1, b1, w2, b2, (float*)d_out, B);
}

// Round 4
// 52.451 us; speedup vs baseline: 1.8183x; 1.0774x over previous
//
#include <hip/hip_runtime.h>
#include <math.h>

#define NP 30      // points per cloud
#define KNN 20     // neighbors
#define KS 5       // spline control points
#define FN 10      // filter count
#define EPS 1e-8f
#define CPB 8      // clouds per block (kernel 1)
#define T1 256     // block size kernel 1
#define HCB 16     // clouds per block (head)

__device__ __forceinline__ float satf(float x) {
    return fminf(fmaxf(x, 0.0f), 1.0f);   // folds to clamp modifier
}

// Kernel 1: per-point directional spline conv -> sigmoid -> per-cloud mean.
// rel vectors held in registers across all passes (no LDS rematerialization).
__global__ __launch_bounds__(T1) void dsc_kernel(
    const float* __restrict__ pos,     // [B*NP, 3]
    const float* __restrict__ W,       // [KS, FN]
    const float* __restrict__ b_dsc,   // [FN]
    float* __restrict__ ys,            // [B, FN] out
    int B)
{
    __shared__ float pts[CPB][92];            // 90 floats/cloud, pad
    __shared__ float sbuf[CPB * NP][FN + 1];  // +1 pad against bank conflicts
    __shared__ float wS[KS * FN];
    __shared__ float bS[FN];

    const int tid  = threadIdx.x;
    const int base = blockIdx.x * CPB;

    for (int g = tid; g < CPB * NP * 3; g += T1) {
        int c   = g / 90;
        int off = g - c * 90;
        pts[c][off] = pos[(size_t)base * 90 + g];
    }
    if (tid < KS * FN) wS[tid] = W[tid];
    if (tid < FN)      bS[tid] = b_dsc[tid];
    __syncthreads();

    const int c = tid / NP;
    const int i = tid - c * NP;
    const bool active = (tid < CPB * NP) && (base + c < B);

    if (active) {
        // own coords (dynamic LDS read; must not touch register arrays)
        const float xi = pts[c][3*i+0];
        const float yi = pts[c][3*i+1];
        const float zi = pts[c][3*i+2];

        // --- rel vectors + squared distances, ALL in registers ---
        float rx[NP], ry[NP], rz[NP];
        float vals[32];
        #pragma unroll
        for (int j = 0; j < NP; ++j) {
            float dx = pts[c][3*j+0] - xi;   // static offsets, broadcast reads
            float dy = pts[c][3*j+1] - yi;
            float dz = pts[c][3*j+2] - zi;
            rx[j] = dx; ry[j] = dy; rz[j] = dz;
            vals[j] = fmaf(dz, dz, fmaf(dy, dy, dx * dx));  // self == 0
        }
        vals[30] = 1e11f;
        vals[31] = 1e11f;

        // --- bitonic stages k=2..16 (full), static -> registers ---
        #pragma unroll
        for (int k = 2; k <= 16; k <<= 1) {
            #pragma unroll
            for (int jj = k >> 1; jj > 0; jj >>= 1) {
                #pragma unroll
                for (int tt = 0; tt < 32; ++tt) {
                    int l = tt ^ jj;
                    if (l > tt) {
                        float a  = vals[tt], b = vals[l];
                        float lo = fminf(a, b), hi = fmaxf(a, b);
                        if ((tt & k) == 0) { vals[tt] = lo; vals[l] = hi; }
                        else               { vals[tt] = hi; vals[l] = lo; }
                    }
                }
            }
        }
        // --- final merge (k=32) pruned to output index 20 ---
        #pragma unroll
        for (int q = 0; q < 16; ++q) vals[16+q] = fmaxf(vals[q], vals[16+q]);
        #pragma unroll
        for (int q = 0; q < 8; ++q)  vals[16+q] = fminf(vals[16+q], vals[24+q]);
        #pragma unroll
        for (int q = 0; q < 4; ++q)  vals[20+q] = fmaxf(vals[16+q], vals[20+q]);
        vals[20] = fminf(vals[20], vals[22]);
        vals[21] = fminf(vals[21], vals[23]);
        const float thr = fminf(vals[20], vals[21]);   // 20th-smallest non-self d2

        const float scale = sqrtf(thr + EPS) + EPS;    // max selected norm + EPS
        const float inv_s = __builtin_amdgcn_rcpf(scale);

        // --- pass A: zero-out excluded rels; covariance of kept rels ---
        // recomputed dd is bit-identical to pre-sort vals (same fmaf sequence)
        float cxx=0.f, cxy=0.f, cxz=0.f, cyy=0.f, cyz=0.f, czz=0.f;
        #pragma unroll
        for (int j = 0; j < NP; ++j) {
            float dd = fmaf(rz[j], rz[j], fmaf(ry[j], ry[j], rx[j]*rx[j]));
            float m  = (dd <= thr) ? 1.0f : 0.0f;
            float mx = rx[j]*m, my = ry[j]*m, mz = rz[j]*m;
            rx[j] = mx; ry[j] = my; rz[j] = mz;
            cxx = fmaf(mx, mx, cxx); cxy = fmaf(mx, my, cxy); cxz = fmaf(mx, mz, cxz);
            cyy = fmaf(my, my, cyy); cyz = fmaf(my, mz, cyz); czz = fmaf(mz, mz, czz);
        }

        // --- power iteration (8 steps); scale-invariant direction ---
        float vx = 0.57735027f, vy = 0.57735027f, vz = 0.57735027f;
        #pragma unroll
        for (int it = 0; it < 8; ++it) {
            float nx = fmaf(cxx, vx, fmaf(cxy, vy, cxz * vz));
            float ny = fmaf(cxy, vx, fmaf(cyy, vy, cyz * vz));
            float nz = fmaf(cxz, vx, fmaf(cyz, vy, czz * vz));
            float nn = fmaf(nz, nz, fmaf(ny, ny, nx * nx));
            float r  = __builtin_amdgcn_rsqf(nn);
            vx = nx * r; vy = ny * r; vz = nz * r;
        }
        // fold normalization scale into the direction vector
        const float vax = vx * inv_s, vay = vy * inv_s, vaz = vz * inv_s;

        // --- pass B: hat-function bins. Excluded/self rels are (0,0,0):
        //     t=0 -> u=2 -> each contributes exactly 1.0 to a2; subtract 10.
        float a0=0.f, a1=0.f, a2=0.f, a3=0.f, a4=0.f;
        #pragma unroll
        for (int j = 0; j < NP; ++j) {
            float t = fmaf(rz[j], vaz, fmaf(ry[j], vay, rx[j] * vax));
            float u = fminf(fmaxf(fmaf(t, 2.0f, 2.0f), 0.0f), 4.0f);  // med3
            a0 += satf(1.0f - fabsf(u));
            a1 += satf(1.0f - fabsf(u - 1.0f));
            a2 += satf(1.0f - fabsf(u - 2.0f));
            a3 += satf(1.0f - fabsf(u - 3.0f));
            a4 += satf(1.0f - fabsf(u - 4.0f));
        }
        a2 -= 10.0f;  // 9 excluded + self, each contributed 1.0 at u=2

        #pragma unroll
        for (int f = 0; f < FN; ++f) {
            float acc = fmaf(a0, wS[0*FN+f],
                        fmaf(a1, wS[1*FN+f],
                        fmaf(a2, wS[2*FN+f],
                        fmaf(a3, wS[3*FN+f],
                             a4 * wS[4*FN+f]))));
            float y = fmaf(acc, 1.0f / (float)KNN, bS[f]);
            sbuf[tid][f] = __builtin_amdgcn_rcpf(1.0f + __expf(-y));
        }
    }
    __syncthreads();

    if (tid < CPB * FN) {
        int c2 = tid / FN;
        int f  = tid - c2 * FN;
        if (base + c2 < B) {
            float s = 0.0f;
            #pragma unroll
            for (int jj = 0; jj < NP; ++jj) s += sbuf[c2 * NP + jj][f];
            ys[(size_t)(base + c2) * FN + f] = s * (1.0f / (float)NP);
        }
    }
}

// Kernel 2: MLP head, 16 clouds/block. Layer 2: K=256 split across 4 waves,
// w2 sub-columns held in registers (reused across all 16 clouds).
__global__ __launch_bounds__(256) void head_kernel(
    const float* __restrict__ ys,   // [B, FN]
    const float* __restrict__ w1,   // [FN, 256]
    const float* __restrict__ b1,   // [256]
    const float* __restrict__ w2,   // [256, 40]
    const float* __restrict__ b2,   // [40]
    float* __restrict__ out,        // [B, 40]
    int B)
{
    __shared__ float ysS[HCB][12];
    __shared__ float hS[HCB][256];
    __shared__ float pS[HCB][4][40];

    const int t    = threadIdx.x;
    const int b0   = blockIdx.x * HCB;
    const int w    = t >> 6;
    const int lane = t & 63;
    const int col  = lane < 40 ? lane : 39;

    // w2 sub-column -> registers
    float wreg[64];
    #pragma unroll
    for (int q = 0; q < 64; ++q) wreg[q] = w2[(w * 64 + q) * 40 + col];

    if (t < HCB * FN) {
        int cc = t / FN, f = t - cc * FN;
        ysS[cc][f] = (b0 * FN + t < B * FN) ? ys[(size_t)b0 * FN + t] : 0.0f;
    }
    __syncthreads();

    // layer 1
    {
        float wv[FN];
        #pragma unroll
        for (int f = 0; f < FN; ++f) wv[f] = w1[f * 256 + t];
        float bb = b1[t];
        for (int cc = 0; cc < HCB; ++cc) {
            float acc = bb;
            #pragma unroll
            for (int f = 0; f < FN; ++f) acc = fmaf(ysS[cc][f], wv[f], acc);
            hS[cc][t] = acc > 0.0f ? acc : __expf(acc) - 1.0f;
        }
    }
    __syncthreads();

    // layer 2 partials
    for (int cg = 0; cg < HCB; cg += 4) {
        float a0 = 0.f, a1 = 0.f, a2 = 0.f, a3 = 0.f;
        #pragma unroll
        for (int q = 0; q < 64; q += 4) {
            float4 h0 = *(const float4*)&hS[cg + 0][w * 64 + q];
            float4 h1 = *(const float4*)&hS[cg + 1][w * 64 + q];
            float4 h2 = *(const float4*)&hS[cg + 2][w * 64 + q];
            float4 h3 = *(const float4*)&hS[cg + 3][w * 64 + q];
            a0 = fmaf(h0.x, wreg[q+0], a0); a1 = fmaf(h1.x, wreg[q+0], a1);
            a2 = fmaf(h2.x, wreg[q+0], a2); a3 = fmaf(h3.x, wreg[q+0], a3);
            a0 = fmaf(h0.y, wreg[q+1], a0); a1 = fmaf(h1.y, wreg[q+1], a1);
            a2 = fmaf(h2.y, wreg[q+1], a2); a3 = fmaf(h3.y, wreg[q+1], a3);
            a0 = fmaf(h0.z, wreg[q+2], a0); a1 = fmaf(h1.z, wreg[q+2], a1);
            a2 = fmaf(h2.z, wreg[q+2], a2); a3 = fmaf(h3.z, wreg[q+2], a3);
            a0 = fmaf(h0.w, wreg[q+3], a0); a1 = fmaf(h1.w, wreg[q+3], a1);
            a2 = fmaf(h2.w, wreg[q+3], a2); a3 = fmaf(h3.w, wreg[q+3], a3);
        }
        if (lane < 40) {
            pS[cg + 0][w][lane] = a0;
            pS[cg + 1][w][lane] = a1;
            pS[cg + 2][w][lane] = a2;
            pS[cg + 3][w][lane] = a3;
        }
    }
    __syncthreads();

    const float bcol = (lane < 40) ? b2[lane] : 0.0f;
    for (int g = 0; g < 4; ++g) {
        int cc = w * 4 + g;
        float logit = -INFINITY;
        if (lane < 40) {
            logit = bcol + pS[cc][0][lane] + pS[cc][1][lane]
                         + pS[cc][2][lane] + pS[cc][3][lane];
        }
        float m = logit;
        #pragma unroll
        for (int off = 32; off >= 1; off >>= 1) m = fmaxf(m, __shfl_xor(m, off));
        float e = (lane < 40) ? __expf(logit - m) : 0.0f;
        float s = e;
        #pragma unroll
        for (int off = 32; off >= 1; off >>= 1) s += __shfl_xor(s, off);
        if (lane < 40 && b0 + cc < B)
            out[(size_t)(b0 + cc) * 40 + lane] = logit - m - __logf(s);
    }
}

extern "C" void kernel_launch(void* const* d_in, const int* in_sizes, int n_in,
                              void* d_out, int out_size, void* d_ws, size_t ws_size,
                              hipStream_t stream) {
    const float* pos   = (const float*)d_in[0];
    const float* W     = (const float*)d_in[1];
    const float* b_dsc = (const float*)d_in[2];
    const float* w1    = (const float*)d_in[3];
    const float* b1    = (const float*)d_in[4];
    const float* w2    = (const float*)d_in[5];
    const float* b2    = (const float*)d_in[6];

    const int N = in_sizes[0] / 3;   // B*NP points
    const int B = N / NP;            // clouds

    float* ys = (float*)d_ws;        // [B, FN] scratch

    const int grid1 = (B + CPB - 1) / CPB;
    dsc_kernel<<<grid1, T1, 0, stream>>>(pos, W, b_dsc, ys, B);
    const int grid2 = (B + HCB - 1) / HCB;
    head_kernel<<<grid2, 256, 0, stream>>>(ys, w1, b1, w2, b2, (float*)d_out, B);
}

// Round 5
// 44.077 us; speedup vs baseline: 2.1637x; 1.1900x over previous
//
#include <hip/hip_runtime.h>
#include <math.h>

#define NP 30      // points per cloud
#define KNN 20     // neighbors
#define KS 5       // spline control points
#define FN 10      // filter count
#define EPS 1e-8f
#define CPB 8      // clouds per block (kernel 1)
#define T1 256     // block size kernel 1
#define HCL 32     // clouds per block (head)

typedef __attribute__((ext_vector_type(8))) short short8v;
typedef __attribute__((ext_vector_type(4))) float float4v;

__device__ __forceinline__ float satf(float x) {
    return fminf(fmaxf(x, 0.0f), 1.0f);
}
__device__ __forceinline__ unsigned short bf16r(float f) {   // f32 -> bf16 RNE
    unsigned u = __float_as_uint(f);
    u += 0x7fffu + ((u >> 16) & 1u);
    return (unsigned short)(u >> 16);
}
__device__ __forceinline__ float rlanef(float v, int l) {    // wave broadcast via SGPR
    return __int_as_float(__builtin_amdgcn_readlane(__float_as_int(v), l));
}

// ---------------- Kernel 1: directional spline conv (unchanged structure) ----
__global__ __launch_bounds__(T1) void dsc_kernel(
    const float* __restrict__ pos, const float* __restrict__ W,
    const float* __restrict__ b_dsc, float* __restrict__ ys, int B)
{
    __shared__ float pts[CPB][92];
    __shared__ float sbuf[CPB * NP][FN + 1];
    __shared__ float wS[KS * FN];
    __shared__ float bS[FN];

    const int tid  = threadIdx.x;
    const int base = blockIdx.x * CPB;

    for (int g = tid; g < CPB * NP * 3; g += T1) {
        int c = g / 90, off = g - c * 90;
        pts[c][off] = pos[(size_t)base * 90 + g];
    }
    if (tid < KS * FN) wS[tid] = W[tid];
    if (tid < FN)      bS[tid] = b_dsc[tid];
    __syncthreads();

    const int c = tid / NP;
    const int i = tid - c * NP;
    const bool active = (tid < CPB * NP) && (base + c < B);

    if (active) {
        const float xi = pts[c][3*i+0];
        const float yi = pts[c][3*i+1];
        const float zi = pts[c][3*i+2];

        float rx[NP], ry[NP], rz[NP];
        float vals[32];
        #pragma unroll
        for (int j = 0; j < NP; ++j) {
            float dx = pts[c][3*j+0] - xi;
            float dy = pts[c][3*j+1] - yi;
            float dz = pts[c][3*j+2] - zi;
            rx[j] = dx; ry[j] = dy; rz[j] = dz;
            vals[j] = fmaf(dz, dz, fmaf(dy, dy, dx * dx));
        }
        vals[30] = 1e11f;
        vals[31] = 1e11f;

        #pragma unroll
        for (int k = 2; k <= 16; k <<= 1) {
            #pragma unroll
            for (int jj = k >> 1; jj > 0; jj >>= 1) {
                #pragma unroll
                for (int tt = 0; tt < 32; ++tt) {
                    int l = tt ^ jj;
                    if (l > tt) {
                        float a  = vals[tt], b = vals[l];
                        float lo = fminf(a, b), hi = fmaxf(a, b);
                        if ((tt & k) == 0) { vals[tt] = lo; vals[l] = hi; }
                        else               { vals[tt] = hi; vals[l] = lo; }
                    }
                }
            }
        }
        #pragma unroll
        for (int q = 0; q < 16; ++q) vals[16+q] = fmaxf(vals[q], vals[16+q]);
        #pragma unroll
        for (int q = 0; q < 8; ++q)  vals[16+q] = fminf(vals[16+q], vals[24+q]);
        #pragma unroll
        for (int q = 0; q < 4; ++q)  vals[20+q] = fmaxf(vals[16+q], vals[20+q]);
        vals[20] = fminf(vals[20], vals[22]);
        vals[21] = fminf(vals[21], vals[23]);
        const float thr = fminf(vals[20], vals[21]);

        const float scale = sqrtf(thr + EPS) + EPS;
        const float inv_s = __builtin_amdgcn_rcpf(scale);

        float cxx=0.f, cxy=0.f, cxz=0.f, cyy=0.f, cyz=0.f, czz=0.f;
        #pragma unroll
        for (int j = 0; j < NP; ++j) {
            float dd = fmaf(rz[j], rz[j], fmaf(ry[j], ry[j], rx[j]*rx[j]));
            float m  = (dd <= thr) ? 1.0f : 0.0f;
            float mx = rx[j]*m, my = ry[j]*m, mz = rz[j]*m;
            rx[j] = mx; ry[j] = my; rz[j] = mz;
            cxx = fmaf(mx, mx, cxx); cxy = fmaf(mx, my, cxy); cxz = fmaf(mx, mz, cxz);
            cyy = fmaf(my, my, cyy); cyz = fmaf(my, mz, cyz); czz = fmaf(mz, mz, czz);
        }

        float vx = 0.57735027f, vy = 0.57735027f, vz = 0.57735027f;
        #pragma unroll
        for (int it = 0; it < 8; ++it) {
            float nx = fmaf(cxx, vx, fmaf(cxy, vy, cxz * vz));
            float ny = fmaf(cxy, vx, fmaf(cyy, vy, cyz * vz));
            float nz = fmaf(cxz, vx, fmaf(cyz, vy, czz * vz));
            float nn = fmaf(nz, nz, fmaf(ny, ny, nx * nx));
            float r  = __builtin_amdgcn_rsqf(nn);
            vx = nx * r; vy = ny * r; vz = nz * r;
        }
        const float vax = vx * inv_s, vay = vy * inv_s, vaz = vz * inv_s;

        // pass B: |t| <= 1+2e-6 guaranteed -> clamp dropped (hat err <= 2e-5)
        float a0=0.f, a1=0.f, a2=0.f, a3=0.f, a4=0.f;
        #pragma unroll
        for (int j = 0; j < NP; ++j) {
            float t = fmaf(rz[j], vaz, fmaf(ry[j], vay, rx[j] * vax));
            float u = fmaf(t, 2.0f, 2.0f);
            a0 += satf(1.0f - fabsf(u));
            a1 += satf(1.0f - fabsf(u - 1.0f));
            a2 += satf(1.0f - fabsf(u - 2.0f));
            a3 += satf(1.0f - fabsf(u - 3.0f));
            a4 += satf(1.0f - fabsf(u - 4.0f));
        }
        a2 -= 10.0f;

        #pragma unroll
        for (int f = 0; f < FN; ++f) {
            float acc = fmaf(a0, wS[0*FN+f],
                        fmaf(a1, wS[1*FN+f],
                        fmaf(a2, wS[2*FN+f],
                        fmaf(a3, wS[3*FN+f],
                             a4 * wS[4*FN+f]))));
            float y = fmaf(acc, 1.0f / (float)KNN, bS[f]);
            sbuf[tid][f] = __builtin_amdgcn_rcpf(1.0f + __expf(-y));
        }
    }
    __syncthreads();

    if (tid < CPB * FN) {
        int c2 = tid / FN;
        int f  = tid - c2 * FN;
        if (base + c2 < B) {
            float s = 0.0f;
            #pragma unroll
            for (int jj = 0; jj < NP; ++jj) s += sbuf[c2 * NP + jj][f];
            ys[(size_t)(base + c2) * FN + f] = s * (1.0f / (float)NP);
        }
    }
}

// ---------------- Kernel 2: MLP head, MFMA layer-2 ----------------
// 32 clouds/block. Layer 1: f32, readlane-broadcast ys (no LDS reads).
// Layer 2: [32,256]x[256,48pad] bf16 MFMA, 2 M-tile waves x 3 N-tiles x 8 K.
__global__ __launch_bounds__(256) void head_kernel(
    const float* __restrict__ ys, const float* __restrict__ w1,
    const float* __restrict__ b1, const float* __restrict__ w2,
    const float* __restrict__ b2, float* __restrict__ out, int B)
{
    __shared__ __align__(16) unsigned short hA[2 * 16 * 256];   // [tile][m][k] bf16
    __shared__ __align__(16) unsigned short bswz[1536 * 8];     // [(s*3+nt)*64+l][j]

    const int t    = threadIdx.x;
    const int w    = t >> 6;
    const int lane = t & 63;
    const int b0   = blockIdx.x * HCL;

    // stage B fragments: my own (group,j)->k bijection, k = (l>>4)*8 + j + 32s
    #pragma unroll
    for (int q = 0; q < 6; ++q) {
        int e  = t * 6 + q;
        int l  = e & 63;
        int sn = e >> 6;                 // s*3 + nt
        int s  = sn / 3, nt = sn - s * 3;
        int k0 = s * 32 + (l >> 4) * 8;
        int n  = nt * 16 + (l & 15);
        short8v v;
        #pragma unroll
        for (int j = 0; j < 8; ++j) {
            float f = (n < 40) ? w2[(k0 + j) * 40 + n] : 0.0f;
            v[j] = (short)bf16r(f);
        }
        *(short8v*)&bswz[e * 8] = v;
    }

    // layer 1: lane l caches ys row of cloud l; broadcast via readlane
    float ysreg[FN];
    {
        bool ok = (lane < HCL) && (b0 + lane < B);
        const float* yp = ys + (size_t)(b0 + lane) * FN;
        #pragma unroll
        for (int f = 0; f < FN; ++f) ysreg[f] = ok ? yp[f] : 0.0f;
    }
    {
        float wv[FN];
        #pragma unroll
        for (int f = 0; f < FN; ++f) wv[f] = w1[f * 256 + t];
        float bb = b1[t];
        #pragma unroll
        for (int cc = 0; cc < HCL; ++cc) {
            float acc = bb;
            #pragma unroll
            for (int f = 0; f < FN; ++f)
                acc = fmaf(rlanef(ysreg[f], cc), wv[f], acc);
            float h = acc > 0.0f ? acc : __expf(acc) - 1.0f;
            hA[cc * 256 + t] = bf16r(h);     // [tile=cc>>4][m=cc&15][k=t]
        }
    }
    __syncthreads();

    if (w < 2) {
        float4v acc0 = {0.f,0.f,0.f,0.f}, acc1 = {0.f,0.f,0.f,0.f}, acc2 = {0.f,0.f,0.f,0.f};
        const unsigned short* Abase = &hA[w * 16 * 256];
        const int arow = (lane & 15) * 256 + (lane >> 4) * 8;
        #pragma unroll
        for (int s = 0; s < 8; ++s) {
            short8v a  = *(const short8v*)&Abase[arow + s * 32];
            short8v q0 = *(const short8v*)&bswz[((s*3+0)*64 + lane) * 8];
            short8v q1 = *(const short8v*)&bswz[((s*3+1)*64 + lane) * 8];
            short8v q2 = *(const short8v*)&bswz[((s*3+2)*64 + lane) * 8];
            acc0 = __builtin_amdgcn_mfma_f32_16x16x32_bf16(a, q0, acc0, 0, 0, 0);
            acc1 = __builtin_amdgcn_mfma_f32_16x16x32_bf16(a, q1, acc1, 0, 0, 0);
            acc2 = __builtin_amdgcn_mfma_f32_16x16x32_bf16(a, q2, acc2, 0, 0, 0);
        }
        // epilogue: C/D layout col=lane&15, row=(lane>>4)*4+reg  [m89-verified]
        const int  col  = lane & 15;
        const bool v2ok = col < 8;                 // cols 32..39 only
        const float bc0 = b2[col], bc1 = b2[16 + col], bc2 = v2ok ? b2[32 + col] : 0.0f;
        #pragma unroll
        for (int r = 0; r < 4; ++r) {
            float v0 = acc0[r] + bc0;
            float v1 = acc1[r] + bc1;
            float v2 = v2ok ? (acc2[r] + bc2) : -1e30f;
            float m = fmaxf(fmaxf(v0, v1), v2);
            #pragma unroll
            for (int msk = 1; msk < 16; msk <<= 1) m = fmaxf(m, __shfl_xor(m, msk));
            float se = __expf(v0 - m) + __expf(v1 - m) + (v2ok ? __expf(v2 - m) : 0.0f);
            #pragma unroll
            for (int msk = 1; msk < 16; msk <<= 1) se += __shfl_xor(se, msk);
            float ls = m + __logf(se);
            int cloud = b0 + w * 16 + (lane >> 4) * 4 + r;
            if (cloud < B) {
                float* op = out + (size_t)cloud * 40;
                op[col]      = v0 - ls;
                op[16 + col] = v1 - ls;
                if (v2ok) op[32 + col] = v2 - ls;
            }
        }
    }
}

extern "C" void kernel_launch(void* const* d_in, const int* in_sizes, int n_in,
                              void* d_out, int out_size, void* d_ws, size_t ws_size,
                              hipStream_t stream) {
    const float* pos   = (const float*)d_in[0];
    const float* W     = (const float*)d_in[1];
    const float* b_dsc = (const float*)d_in[2];
    const float* w1    = (const float*)d_in[3];
    const float* b1    = (const float*)d_in[4];
    const float* w2    = (const float*)d_in[5];
    const float* b2    = (const float*)d_in[6];

    const int N = in_sizes[0] / 3;   // B*NP points
    const int B = N / NP;            // clouds

    float* ys = (float*)d_ws;        // [B, FN] scratch

    const int grid1 = (B + CPB - 1) / CPB;
    dsc_kernel<<<grid1, T1, 0, stream>>>(pos, W, b_dsc, ys, B);
    const int grid2 = (B + HCL - 1) / HCL;
    head_kernel<<<grid2, 256, 0, stream>>>(ys, w1, b1, w2, b2, (float*)d_out, B);
}

// Round 6
// 39.451 us; speedup vs baseline: 2.4174x; 1.1173x over previous
//
#include <hip/hip_runtime.h>
#include <math.h>

#define NP 30      // points per cloud
#define KNN 20     // neighbors
#define KS 5       // spline control points
#define FN 10      // filter count
#define EPS 1e-8f
#define CPB 8      // clouds per block (kernel 1)
#define T1 256     // block size kernel 1
#define HCL 32     // clouds per block (head)

typedef __attribute__((ext_vector_type(8))) short short8v;
typedef __attribute__((ext_vector_type(4))) float float4v;

__device__ __forceinline__ float satf(float x) {
    return fminf(fmaxf(x, 0.0f), 1.0f);   // folds to clamp modifier
}
__device__ __forceinline__ unsigned short bf16r(float f) {   // f32 -> bf16 RNE
    unsigned u = __float_as_uint(f);
    u += 0x7fffu + ((u >> 16) & 1u);
    return (unsigned short)(u >> 16);
}
__device__ __forceinline__ float rlanef(float v, int l) {
    return __int_as_float(__builtin_amdgcn_readlane(__float_as_int(v), l));
}

// access float f of a float2-register-array pp[] with STATIC index f
#define PF(f) (((f) & 1) ? pp[(f) >> 1].y : pp[(f) >> 1].x)

// ---------------- Kernel 1: directional spline conv ----------------
// 1 thread/point. Points loaded straight from global (L1-broadcast within
// cloud). launch_bounds(,3) lifts the VGPR cap so rel[] truly resides in
// registers (round-3 showed the default heuristic capped at 92 and
// rematerialized from LDS every pass).
__global__ __launch_bounds__(T1, 3) void dsc_kernel(
    const float* __restrict__ pos,     // [B*NP, 3]
    const float* __restrict__ W,       // [KS, FN]
    const float* __restrict__ b_dsc,   // [FN]
    float* __restrict__ ys,            // [B, FN] out
    int B)
{
    __shared__ float sbuf[CPB * NP][FN + 1];  // +1 pad against bank conflicts
    __shared__ float wS[KS * FN];
    __shared__ float bS[FN];

    const int tid  = threadIdx.x;
    const int base = blockIdx.x * CPB;

    if (tid < KS * FN) wS[tid] = W[tid];
    if (tid < FN)      bS[tid] = b_dsc[tid];
    __syncthreads();   // cheap: all waves arrive immediately

    const int c = tid / NP;
    const int i = tid - c * NP;
    const bool active = (tid < CPB * NP) && (base + c < B);

    if (active) {
        // --- direct global loads: cloud points (45x float2) + own coords ---
        const float* cb = pos + (size_t)(base + c) * (NP * 3);
        const float* ob = cb + i * 3;
        const float ox = ob[0], oy = ob[1], oz = ob[2];
        float2 pp[45];
        #pragma unroll
        for (int r = 0; r < 45; ++r) pp[r] = ((const float2*)cb)[r];

        // --- rel vectors + squared distances, all in registers ---
        float rx[NP], ry[NP], rz[NP];
        float vals[32];
        #pragma unroll
        for (int j = 0; j < NP; ++j) {
            float dx = PF(3*j+0) - ox;
            float dy = PF(3*j+1) - oy;
            float dz = PF(3*j+2) - oz;
            rx[j] = dx; ry[j] = dy; rz[j] = dz;
            vals[j] = fmaf(dz, dz, fmaf(dy, dy, dx * dx));  // self == 0
        }
        vals[30] = 1e11f;
        vals[31] = 1e11f;

        // --- bitonic stages k=2..16 (full), static -> registers ---
        #pragma unroll
        for (int k = 2; k <= 16; k <<= 1) {
            #pragma unroll
            for (int jj = k >> 1; jj > 0; jj >>= 1) {
                #pragma unroll
                for (int tt = 0; tt < 32; ++tt) {
                    int l = tt ^ jj;
                    if (l > tt) {
                        float a  = vals[tt], b = vals[l];
                        float lo = fminf(a, b), hi = fmaxf(a, b);
                        if ((tt & k) == 0) { vals[tt] = lo; vals[l] = hi; }
                        else               { vals[tt] = hi; vals[l] = lo; }
                    }
                }
            }
        }
        // --- final merge (k=32) pruned to output index 20 ---
        #pragma unroll
        for (int q = 0; q < 16; ++q) vals[16+q] = fmaxf(vals[q], vals[16+q]);
        #pragma unroll
        for (int q = 0; q < 8; ++q)  vals[16+q] = fminf(vals[16+q], vals[24+q]);
        #pragma unroll
        for (int q = 0; q < 4; ++q)  vals[20+q] = fmaxf(vals[16+q], vals[20+q]);
        vals[20] = fminf(vals[20], vals[22]);
        vals[21] = fminf(vals[21], vals[23]);
        const float thr = fminf(vals[20], vals[21]);   // 20th-smallest non-self d2

        const float scale = sqrtf(thr + EPS) + EPS;
        const float inv_s = __builtin_amdgcn_rcpf(scale);

        // --- pass A: zero excluded rels (cndmask), covariance of kept ---
        float cxx=0.f, cxy=0.f, cxz=0.f, cyy=0.f, cyz=0.f, czz=0.f;
        #pragma unroll
        for (int j = 0; j < NP; ++j) {
            float dd = fmaf(rz[j], rz[j], fmaf(ry[j], ry[j], rx[j]*rx[j]));
            bool sel = (dd <= thr);
            float mx = sel ? rx[j] : 0.0f;
            float my = sel ? ry[j] : 0.0f;
            float mz = sel ? rz[j] : 0.0f;
            rx[j] = mx; ry[j] = my; rz[j] = mz;
            cxx = fmaf(mx, mx, cxx); cxy = fmaf(mx, my, cxy); cxz = fmaf(mx, mz, cxz);
            cyy = fmaf(my, my, cyy); cyz = fmaf(my, mz, cyz); czz = fmaf(mz, mz, czz);
        }

        // --- power iteration (8 steps); scale-invariant direction ---
        float vx = 0.57735027f, vy = 0.57735027f, vz = 0.57735027f;
        #pragma unroll
        for (int it = 0; it < 8; ++it) {
            float nx = fmaf(cxx, vx, fmaf(cxy, vy, cxz * vz));
            float ny = fmaf(cxy, vx, fmaf(cyy, vy, cyz * vz));
            float nz = fmaf(cxz, vx, fmaf(cyz, vy, czz * vz));
            float nn = fmaf(nz, nz, fmaf(ny, ny, nx * nx));
            float r  = __builtin_amdgcn_rsqf(nn);
            vx = nx * r; vy = ny * r; vz = nz * r;
        }
        // u = 2*(rel . v*inv_s) + 2, folded into one fma chain
        const float wax = 2.0f * (vx * inv_s);
        const float way = 2.0f * (vy * inv_s);
        const float waz = 2.0f * (vz * inv_s);

        // --- pass B: 3 hat bins + first moment; derive a2, a4 ---
        // hats reproduce constants and linears: sum_b hat_b = 1, sum_b b*hat_b = u
        float a0 = 0.f, a1 = 0.f, a3 = 0.f, s1 = 0.f;
        #pragma unroll
        for (int j = 0; j < NP; ++j) {
            float u = fmaf(rz[j], waz, fmaf(ry[j], way, fmaf(rx[j], wax, 2.0f)));
            a0 += satf(1.0f - fabsf(u));
            a1 += satf(1.0f - fabsf(u - 1.0f));
            a3 += satf(1.0f - fabsf(u - 3.0f));
            s1 += u;
        }
        const float P  = 30.0f - a0 - a1 - a3;        // a2 + a4
        const float Q  = s1 - a1 - 3.0f * a3;         // 2*a2 + 4*a4
        const float a4 = fmaf(0.5f, Q, -P);
        const float a2 = P - a4 - 10.0f;  // self + 9 excluded sit at u=2 exactly

        #pragma unroll
        for (int f = 0; f < FN; ++f) {
            float acc = fmaf(a0, wS[0*FN+f],
                        fmaf(a1, wS[1*FN+f],
                        fmaf(a2, wS[2*FN+f],
                        fmaf(a3, wS[3*FN+f],
                             a4 * wS[4*FN+f]))));
            float y = fmaf(acc, 1.0f / (float)KNN, bS[f]);
            sbuf[tid][f] = __builtin_amdgcn_rcpf(1.0f + __expf(-y));
        }
    }
    __syncthreads();

    if (tid < CPB * FN) {
        int c2 = tid / FN;
        int f  = tid - c2 * FN;
        if (base + c2 < B) {
            float s = 0.0f;
            #pragma unroll
            for (int jj = 0; jj < NP; ++jj) s += sbuf[c2 * NP + jj][f];
            ys[(size_t)(base + c2) * FN + f] = s * (1.0f / (float)NP);
        }
    }
}

// ---------------- Kernel 2: MLP head, MFMA layer-2 (unchanged) ----------------
__global__ __launch_bounds__(256) void head_kernel(
    const float* __restrict__ ys, const float* __restrict__ w1,
    const float* __restrict__ b1, const float* __restrict__ w2,
    const float* __restrict__ b2, float* __restrict__ out, int B)
{
    __shared__ __align__(16) unsigned short hA[2 * 16 * 256];   // [tile][m][k] bf16
    __shared__ __align__(16) unsigned short bswz[1536 * 8];     // [(s*3+nt)*64+l][j]

    const int t    = threadIdx.x;
    const int w    = t >> 6;
    const int lane = t & 63;
    const int b0   = blockIdx.x * HCL;

    #pragma unroll
    for (int q = 0; q < 6; ++q) {
        int e  = t * 6 + q;
        int l  = e & 63;
        int sn = e >> 6;
        int s  = sn / 3, nt = sn - s * 3;
        int k0 = s * 32 + (l >> 4) * 8;
        int n  = nt * 16 + (l & 15);
        short8v v;
        #pragma unroll
        for (int j = 0; j < 8; ++j) {
            float f = (n < 40) ? w2[(k0 + j) * 40 + n] : 0.0f;
            v[j] = (short)bf16r(f);
        }
        *(short8v*)&bswz[e * 8] = v;
    }

    float ysreg[FN];
    {
        bool ok = (lane < HCL) && (b0 + lane < B);
        const float* yp = ys + (size_t)(b0 + lane) * FN;
        #pragma unroll
        for (int f = 0; f < FN; ++f) ysreg[f] = ok ? yp[f] : 0.0f;
    }
    {
        float wv[FN];
        #pragma unroll
        for (int f = 0; f < FN; ++f) wv[f] = w1[f * 256 + t];
        float bb = b1[t];
        #pragma unroll
        for (int cc = 0; cc < HCL; ++cc) {
            float acc = bb;
            #pragma unroll
            for (int f = 0; f < FN; ++f)
                acc = fmaf(rlanef(ysreg[f], cc), wv[f], acc);
            float h = acc > 0.0f ? acc : __expf(acc) - 1.0f;
            hA[cc * 256 + t] = bf16r(h);
        }
    }
    __syncthreads();

    if (w < 2) {
        float4v acc0 = {0.f,0.f,0.f,0.f}, acc1 = {0.f,0.f,0.f,0.f}, acc2 = {0.f,0.f,0.f,0.f};
        const unsigned short* Abase = &hA[w * 16 * 256];
        const int arow = (lane & 15) * 256 + (lane >> 4) * 8;
        #pragma unroll
        for (int s = 0; s < 8; ++s) {
            short8v a  = *(const short8v*)&Abase[arow + s * 32];
            short8v q0 = *(const short8v*)&bswz[((s*3+0)*64 + lane) * 8];
            short8v q1 = *(const short8v*)&bswz[((s*3+1)*64 + lane) * 8];
            short8v q2 = *(const short8v*)&bswz[((s*3+2)*64 + lane) * 8];
            acc0 = __builtin_amdgcn_mfma_f32_16x16x32_bf16(a, q0, acc0, 0, 0, 0);
            acc1 = __builtin_amdgcn_mfma_f32_16x16x32_bf16(a, q1, acc1, 0, 0, 0);
            acc2 = __builtin_amdgcn_mfma_f32_16x16x32_bf16(a, q2, acc2, 0, 0, 0);
        }
        const int  col  = lane & 15;
        const bool v2ok = col < 8;
        const float bc0 = b2[col], bc1 = b2[16 + col], bc2 = v2ok ? b2[32 + col] : 0.0f;
        #pragma unroll
        for (int r = 0; r < 4; ++r) {
            float v0 = acc0[r] + bc0;
            float v1 = acc1[r] + bc1;
            float v2 = v2ok ? (acc2[r] + bc2) : -1e30f;
            float m = fmaxf(fmaxf(v0, v1), v2);
            #pragma unroll
            for (int msk = 1; msk < 16; msk <<= 1) m = fmaxf(m, __shfl_xor(m, msk));
            float se = __expf(v0 - m) + __expf(v1 - m) + (v2ok ? __expf(v2 - m) : 0.0f);
            #pragma unroll
            for (int msk = 1; msk < 16; msk <<= 1) se += __shfl_xor(se, msk);
            float ls = m + __logf(se);
            int cloud = b0 + w * 16 + (lane >> 4) * 4 + r;
            if (cloud < B) {
                float* op = out + (size_t)cloud * 40;
                op[col]      = v0 - ls;
                op[16 + col] = v1 - ls;
                if (v2ok) op[32 + col] = v2 - ls;
            }
        }
    }
}

extern "C" void kernel_launch(void* const* d_in, const int* in_sizes, int n_in,
                              void* d_out, int out_size, void* d_ws, size_t ws_size,
                              hipStream_t stream) {
    const float* pos   = (const float*)d_in[0];
    const float* W     = (const float*)d_in[1];
    const float* b_dsc = (const float*)d_in[2];
    const float* w1    = (const float*)d_in[3];
    const float* b1    = (const float*)d_in[4];
    const float* w2    = (const float*)d_in[5];
    const float* b2    = (const float*)d_in[6];

    const int N = in_sizes[0] / 3;   // B*NP points
    const int B = N / NP;            // clouds

    float* ys = (float*)d_ws;        // [B, FN] scratch

    const int grid1 = (B + CPB - 1) / CPB;
    dsc_kernel<<<grid1, T1, 0, stream>>>(pos, W, b_dsc, ys, B);
    const int grid2 = (B + HCL - 1) / HCL;
    head_kernel<<<grid2, 256, 0, stream>>>(ys, w1, b1, w2, b2, (float*)d_out, B);
}

// Round 7
// 36.333 us; speedup vs baseline: 2.6248x; 1.0858x over previous
//
#include <hip/hip_runtime.h>
#include <math.h>

#define NP 30      // points per cloud
#define KNN 20     // neighbors
#define KS 5       // spline control points
#define FN 10      // filter count
#define EPS 1e-8f
#define CPB 8      // clouds per block
#define T1 256     // block size

typedef __attribute__((ext_vector_type(8))) short short8v;
typedef __attribute__((ext_vector_type(4))) float float4v;

__device__ __forceinline__ float satf(float x) {
    return fminf(fmaxf(x, 0.0f), 1.0f);   // folds to clamp modifier
}
__device__ __forceinline__ unsigned short bf16r(float f) {   // f32 -> bf16 RNE
    unsigned u = __float_as_uint(f);
    u += 0x7fffu + ((u >> 16) & 1u);
    return (unsigned short)(u >> 16);
}

// access float f of a float2-register-array pp[] with STATIC index f
#define PF(f) (((f) & 1) ? pp[(f) >> 1].y : pp[(f) >> 1].x)

// Fully fused: dsc (spline conv + sigmoid + cloud-mean) -> MLP -> log_softmax.
// One 256-thread block handles 8 clouds end-to-end.
__global__ __launch_bounds__(T1, 3) void fused_kernel(
    const float* __restrict__ pos,     // [B*NP, 3]
    const float* __restrict__ W,       // [KS, FN]
    const float* __restrict__ b_dsc,   // [FN]
    const float* __restrict__ w1,      // [FN, 256]
    const float* __restrict__ b1,      // [256]
    const float* __restrict__ w2,      // [256, 40]
    const float* __restrict__ b2,      // [40]
    float* __restrict__ out,           // [B, 40]
    int B)
{
    __shared__ float sbuf[CPB * NP][FN + 1];          // sigmoid staging
    __shared__ float wS[KS * FN];
    __shared__ float bS[FN];
    __shared__ float ysS[CPB][FN];                    // per-cloud mean features
    __shared__ __align__(16) unsigned short hA[16][256];  // bf16 A-tile (rows 8-15 zero)
    __shared__ float Lg[CPB][48];                     // logits

    const int tid  = threadIdx.x;
    const int base = blockIdx.x * CPB;
    const int w    = tid >> 6;
    const int lane = tid & 63;

    if (tid < KS * FN) wS[tid] = W[tid];
    if (tid < FN)      bS[tid] = b_dsc[tid];
    __syncthreads();

    // ---------------- phase 1: per-point spline conv ----------------
    const int c = tid / NP;
    const int i = tid - c * NP;
    const bool active = (tid < CPB * NP) && (base + c < B);

    if (active) {
        const float* cb = pos + (size_t)(base + c) * (NP * 3);
        const float* ob = cb + i * 3;
        const float ox = ob[0], oy = ob[1], oz = ob[2];
        float2 pp[45];
        #pragma unroll
        for (int r = 0; r < 45; ++r) pp[r] = ((const float2*)cb)[r];

        // rel vectors + squared distances, in registers
        float rx[NP], ry[NP], rz[NP];
        float vals[32];
        #pragma unroll
        for (int j = 0; j < NP; ++j) {
            float dx = PF(3*j+0) - ox;
            float dy = PF(3*j+1) - oy;
            float dz = PF(3*j+2) - oz;
            rx[j] = dx; ry[j] = dy; rz[j] = dz;
            vals[j] = fmaf(dz, dz, fmaf(dy, dy, dx * dx));  // self == 0
        }
        vals[30] = 1e11f;
        vals[31] = 1e11f;

        // bitonic stages k=2..16 (two independent 16-sorts), static
        #pragma unroll
        for (int k = 2; k <= 16; k <<= 1) {
            #pragma unroll
            for (int jj = k >> 1; jj > 0; jj >>= 1) {
                #pragma unroll
                for (int tt = 0; tt < 32; ++tt) {
                    int l = tt ^ jj;
                    if (l > tt) {
                        float a  = vals[tt], b = vals[l];
                        float lo = fminf(a, b), hi = fmaxf(a, b);
                        if ((tt & k) == 0) { vals[tt] = lo; vals[l] = hi; }
                        else               { vals[tt] = hi; vals[l] = lo; }
                    }
                }
            }
        }
        // final merge (k=32) pruned to output index 20
        #pragma unroll
        for (int q = 0; q < 16; ++q) vals[16+q] = fmaxf(vals[q], vals[16+q]);
        #pragma unroll
        for (int q = 0; q < 8; ++q)  vals[16+q] = fminf(vals[16+q], vals[24+q]);
        #pragma unroll
        for (int q = 0; q < 4; ++q)  vals[20+q] = fmaxf(vals[16+q], vals[20+q]);
        vals[20] = fminf(vals[20], vals[22]);
        vals[21] = fminf(vals[21], vals[23]);
        const float thr = fminf(vals[20], vals[21]);   // 20th-smallest non-self d2

        const float scale = sqrtf(thr + EPS) + EPS;
        const float inv_s = __builtin_amdgcn_rcpf(scale);

        // pass A: zero excluded rels (cndmask in place), covariance of kept
        float cxx=0.f, cxy=0.f, cxz=0.f, cyy=0.f, cyz=0.f, czz=0.f;
        #pragma unroll
        for (int j = 0; j < NP; ++j) {
            float dd = fmaf(rz[j], rz[j], fmaf(ry[j], ry[j], rx[j]*rx[j]));
            bool sel = (dd <= thr);
            float mx = sel ? rx[j] : 0.0f;
            float my = sel ? ry[j] : 0.0f;
            float mz = sel ? rz[j] : 0.0f;
            rx[j] = mx; ry[j] = my; rz[j] = mz;
            cxx = fmaf(mx, mx, cxx); cxy = fmaf(mx, my, cxy); cxz = fmaf(mx, mz, cxz);
            cyy = fmaf(my, my, cyy); cyz = fmaf(my, mz, cyz); czz = fmaf(mz, mz, czz);
        }

        // power iteration x8 == C^8 v0 (normalization is scale-only):
        // trace-normalize (uniform scale, direction-exact), 3 symmetric squarings
        float tr = cxx + cyy + czz + 1e-30f;
        float rt = __builtin_amdgcn_rcpf(tr);
        float xx = cxx*rt, xy = cxy*rt, xz = cxz*rt;
        float yy = cyy*rt, yz = cyz*rt, zz = czz*rt;
        #pragma unroll
        for (int it = 0; it < 3; ++it) {
            float nxx = fmaf(xx, xx, fmaf(xy, xy, xz * xz));
            float nxy = fmaf(xy, xx + yy, xz * yz);
            float nxz = fmaf(xz, xx + zz, xy * yz);
            float nyy = fmaf(xy, xy, fmaf(yy, yy, yz * yz));
            float nyz = fmaf(yz, yy + zz, xy * xz);
            float nzz = fmaf(xz, xz, fmaf(yz, yz, zz * zz));
            xx = nxx; xy = nxy; xz = nxz; yy = nyy; yz = nyz; zz = nzz;
        }
        // v = C^8 . (1,1,1)  (row sums); fold |v|^-1, inv_s, and the *2 into wa
        float vx = xx + xy + xz;
        float vy = xy + yy + yz;
        float vz = xz + yz + zz;
        float nn = fmaf(vz, vz, fmaf(vy, vy, vx * vx)) + 1e-30f;
        float rr2 = __builtin_amdgcn_rsqf(nn) * inv_s * 2.0f;
        const float wax = vx * rr2, way = vy * rr2, waz = vz * rr2;

        // pass B: 3 hat bins + first moment; derive a2, a4 (exact algebra)
        float a0 = 0.f, a1 = 0.f, a3 = 0.f, s1 = 0.f;
        #pragma unroll
        for (int j = 0; j < NP; ++j) {
            float u = fmaf(rz[j], waz, fmaf(ry[j], way, fmaf(rx[j], wax, 2.0f)));
            a0 += satf(1.0f - fabsf(u));
            a1 += satf(1.0f - fabsf(u - 1.0f));
            a3 += satf(1.0f - fabsf(u - 3.0f));
            s1 += u;
        }
        const float P  = 30.0f - a0 - a1 - a3;        // a2 + a4 (incl. dummies)
        const float Q  = s1 - a1 - 3.0f * a3;         // 2*a2 + 4*a4
        const float a4 = fmaf(0.5f, Q, -P);
        const float a2 = P - a4 - 10.0f;  // self + 9 excluded sit at u=2 exactly

        #pragma unroll
        for (int f = 0; f < FN; ++f) {
            float acc = fmaf(a0, wS[0*FN+f],
                        fmaf(a1, wS[1*FN+f],
                        fmaf(a2, wS[2*FN+f],
                        fmaf(a3, wS[3*FN+f],
                             a4 * wS[4*FN+f]))));
            float y = fmaf(acc, 1.0f / (float)KNN, bS[f]);
            sbuf[tid][f] = __builtin_amdgcn_rcpf(1.0f + __expf(-y));
        }
    }
    __syncthreads();

    // ---------------- phase 2: cloud-mean -> MLP -> log_softmax ----------------
    // ys reduce into LDS
    if (tid < CPB * FN) {
        int c2 = tid / FN;
        int f  = tid - c2 * FN;
        float s = 0.0f;
        #pragma unroll
        for (int jj = 0; jj < NP; ++jj) s += sbuf[c2 * NP + jj][f];
        ysS[c2][f] = (base + c2 < B) ? s * (1.0f / (float)NP) : 0.0f;
    }
    // zero A-tile rows 8..15 (8 rows x 256 cols = 2048 bf16 / 8 per thread)
    {
        short8v z = {0, 0, 0, 0, 0, 0, 0, 0};
        *(short8v*)&hA[8 + (tid >> 5)][(tid & 31) * 8] = z;
    }
    __syncthreads();

    // layer 1: thread t = hidden unit t, for all 8 clouds (ysS broadcast reads)
    {
        float wv[FN];
        #pragma unroll
        for (int f = 0; f < FN; ++f) wv[f] = w1[f * 256 + tid];
        float bb = b1[tid];
        #pragma unroll
        for (int cc = 0; cc < CPB; ++cc) {
            float acc = bb;
            #pragma unroll
            for (int f = 0; f < FN; ++f) acc = fmaf(ysS[cc][f], wv[f], acc);
            float h = acc > 0.0f ? acc : __expf(acc) - 1.0f;
            hA[cc][tid] = bf16r(h);
        }
    }
    __syncthreads();

    // layer 2: waves 0..2 each own one 16-col N-tile; B-frags global->regs
    if (w < 3) {
        const int  n   = w * 16 + (lane & 15);
        const bool nok = n < 40;
        const int  kg  = (lane >> 4) * 8;      // k-group offset within 32-step
        float4v acc = {0.f, 0.f, 0.f, 0.f};
        #pragma unroll
        for (int s = 0; s < 8; ++s) {
            short8v bfr;
            #pragma unroll
            for (int j = 0; j < 8; ++j) {
                float f = nok ? w2[(s * 32 + kg + j) * 40 + n] : 0.0f;
                bfr[j] = (short)bf16r(f);
            }
            short8v a = *(const short8v*)&hA[lane & 15][kg + s * 32];
            acc = __builtin_amdgcn_mfma_f32_16x16x32_bf16(a, bfr, acc, 0, 0, 0);
        }
        // C/D: col=lane&15 (our n), row=(lane>>4)*4+r  [m89-verified]
        if (nok) {
            const float bc = b2[n];
            const int   r0 = (lane >> 4) * 4;
            #pragma unroll
            for (int r = 0; r < 4; ++r) {
                int rr = r0 + r;
                if (rr < CPB) Lg[rr][n] = acc[r] + bc;
            }
        }
    }
    __syncthreads();

    // log_softmax: 16-lane group per cloud (threads 0..127, groups lane-aligned)
    if (tid < CPB * 16) {
        int cl = tid >> 4, l = tid & 15;
        float v0 = Lg[cl][l];
        float v1 = Lg[cl][l + 16];
        float v2 = (l < 8) ? Lg[cl][l + 32] : -INFINITY;
        float m = fmaxf(fmaxf(v0, v1), v2);
        #pragma unroll
        for (int msk = 1; msk < 16; msk <<= 1) m = fmaxf(m, __shfl_xor(m, msk));
        float e = __expf(v0 - m) + __expf(v1 - m) + ((l < 8) ? __expf(v2 - m) : 0.0f);
        #pragma unroll
        for (int msk = 1; msk < 16; msk <<= 1) e += __shfl_xor(e, msk);
        float ls = m + __logf(e);
        int cloud = base + cl;
        if (cloud < B) {
            float* op = out + (size_t)cloud * 40;
            op[l]      = v0 - ls;
            op[16 + l] = v1 - ls;
            if (l < 8) op[32 + l] = v2 - ls;
        }
    }
}

extern "C" void kernel_launch(void* const* d_in, const int* in_sizes, int n_in,
                              void* d_out, int out_size, void* d_ws, size_t ws_size,
                              hipStream_t stream) {
    const float* pos   = (const float*)d_in[0];
    const float* W     = (const float*)d_in[1];
    const float* b_dsc = (const float*)d_in[2];
    const float* w1    = (const float*)d_in[3];
    const float* b1    = (const float*)d_in[4];
    const float* w2    = (const float*)d_in[5];
    const float* b2    = (const float*)d_in[6];

    const int N = in_sizes[0] / 3;   // B*NP points
    const int B = N / NP;            // clouds

    const int grid = (B + CPB - 1) / CPB;
    fused_kernel<<<grid, T1, 0, stream>>>(pos, W, b_dsc, w1, b1, w2, b2,
                                          (float*)d_out, B);
}

// Round 8
// 36.119 us; speedup vs baseline: 2.6404x; 1.0059x over previous
//
#include <hip/hip_runtime.h>
#include <math.h>

#define NP 30      // points per cloud
#define KNN 20     // neighbors
#define KS 5       // spline control points
#define FN 10      // filter count
#define EPS 1e-8f
#define CPB 8      // clouds per block
#define T1 256     // block size

typedef __attribute__((ext_vector_type(8))) short short8v;
typedef __attribute__((ext_vector_type(4))) float float4v;

__device__ __forceinline__ float satf(float x) {
    return fminf(fmaxf(x, 0.0f), 1.0f);   // folds to clamp modifier
}
__device__ __forceinline__ unsigned short bf16r(float f) {   // f32 -> bf16 RNE
    unsigned u = __float_as_uint(f);
    u += 0x7fffu + ((u >> 16) & 1u);
    return (unsigned short)(u >> 16);
}
// hA swizzle: 16B granule g of row r -> g ^ (r&7). Kills the stride-512B
// 16-way bank conflict on the MFMA A-tile read (R7: 1.4M conflict cycles).
__device__ __forceinline__ int hA_idx(int row, int col /*ushort*/) {
    return row * 256 + ((((col >> 3) ^ (row & 7)) << 3) | (col & 7));
}

// Fully fused: dsc (spline conv + sigmoid + cloud-mean) -> MLP -> log_softmax.
// One 256-thread block handles 8 clouds end-to-end.
// Design rule this round: per-thread live state <= ~50 floats (vals[32] only);
// point data stays in LDS and is re-read per pass (broadcast b128, ~free) so
// the register allocator never spills/remats (R7: ~2x VALU inflation at VGPR=84).
__global__ __launch_bounds__(T1, 6) void fused_kernel(
    const float* __restrict__ pos,     // [B*NP, 3]
    const float* __restrict__ W,       // [KS, FN]
    const float* __restrict__ b_dsc,   // [FN]
    const float* __restrict__ w1,      // [FN, 256]
    const float* __restrict__ b1,      // [256]
    const float* __restrict__ w2,      // [256, 40]
    const float* __restrict__ b2,      // [40]
    float* __restrict__ out,           // [B, 40]
    int B)
{
    __shared__ float4 ptsF[CPB * NP];                 // xyz + dead w, 3840 B
    __shared__ float sbuf[CPB * NP][FN + 1];          // sigmoid staging
    __shared__ float wS[KS * FN];
    __shared__ float bS[FN];
    __shared__ float ysS[CPB][FN];                    // per-cloud mean features
    __shared__ __align__(16) unsigned short hA[16 * 256];  // bf16 A-tile, swizzled
    __shared__ float Lg[CPB][48];                     // logits

    const int tid  = threadIdx.x;
    const int base = blockIdx.x * CPB;
    const int w    = tid >> 6;
    const int lane = tid & 63;

    // stage points (coalesced dword reads, scatter to float4 slots)
    {
        const int lim = min(CPB * NP * 3, B * NP * 3 - base * NP * 3);
        for (int d = tid; d < lim; d += T1) {
            float v  = pos[(size_t)base * (NP * 3) + d];
            int   pt = d / 3;
            ((float*)&ptsF[pt])[d - pt * 3] = v;
        }
    }
    if (tid < KS * FN) wS[tid] = W[tid];
    if (tid < FN)      bS[tid] = b_dsc[tid];
    __syncthreads();

    // ---------------- phase 1: per-point spline conv ----------------
    const int c = tid / NP;
    const int i = tid - c * NP;
    const bool active = (tid < CPB * NP) && (base + c < B);

    if (active) {
        const float4* cp = &ptsF[c * NP];
        const float4 own = cp[i];                 // dynamic LDS read, once
        const float ox = own.x, oy = own.y, oz = own.z;

        // --- distances only; rel recomputed per pass from LDS ---
        float vals[32];
        #pragma unroll
        for (int j = 0; j < NP; ++j) {
            float4 q = cp[j];                     // broadcast b128
            float dx = q.x - ox, dy = q.y - oy, dz = q.z - oz;
            vals[j] = fmaf(dz, dz, fmaf(dy, dy, dx * dx));  // self == 0
        }
        vals[30] = 1e11f;
        vals[31] = 1e11f;

        // --- bitonic stages k=2..16 (full), static -> registers ---
        #pragma unroll
        for (int k = 2; k <= 16; k <<= 1) {
            #pragma unroll
            for (int jj = k >> 1; jj > 0; jj >>= 1) {
                #pragma unroll
                for (int tt = 0; tt < 32; ++tt) {
                    int l = tt ^ jj;
                    if (l > tt) {
                        float a  = vals[tt], b = vals[l];
                        float lo = fminf(a, b), hi = fmaxf(a, b);
                        if ((tt & k) == 0) { vals[tt] = lo; vals[l] = hi; }
                        else               { vals[tt] = hi; vals[l] = lo; }
                    }
                }
            }
        }
        // --- final merge (k=32) pruned to output index 20 ---
        #pragma unroll
        for (int q = 0; q < 16; ++q) vals[16+q] = fmaxf(vals[q], vals[16+q]);
        #pragma unroll
        for (int q = 0; q < 8; ++q)  vals[16+q] = fminf(vals[16+q], vals[24+q]);
        #pragma unroll
        for (int q = 0; q < 4; ++q)  vals[20+q] = fmaxf(vals[16+q], vals[20+q]);
        vals[20] = fminf(vals[20], vals[22]);
        vals[21] = fminf(vals[21], vals[23]);
        const float thr = fminf(vals[20], vals[21]);   // 20th-smallest non-self d2

        const float scale = sqrtf(thr + EPS) + EPS;
        const float inv_s = __builtin_amdgcn_rcpf(scale);

        asm volatile("" ::: "memory");   // forbid CSE of cp[j] across passes

        // --- pass A: re-read LDS, recompute rel (bit-identical dd), covariance ---
        float cxx=0.f, cxy=0.f, cxz=0.f, cyy=0.f, cyz=0.f, czz=0.f;
        #pragma unroll
        for (int j = 0; j < NP; ++j) {
            float4 q = cp[j];
            float dx = q.x - ox, dy = q.y - oy, dz = q.z - oz;
            float dd = fmaf(dz, dz, fmaf(dy, dy, dx * dx));
            bool sel = (dd <= thr);
            float mx = sel ? dx : 0.0f;
            float my = sel ? dy : 0.0f;
            float mz = sel ? dz : 0.0f;
            cxx = fmaf(mx, mx, cxx); cxy = fmaf(mx, my, cxy); cxz = fmaf(mx, mz, cxz);
            cyy = fmaf(my, my, cyy); cyz = fmaf(my, mz, cyz); czz = fmaf(mz, mz, czz);
        }

        // power iteration x8 == C^8 v0: trace-normalize + 3 symmetric squarings
        float tr = cxx + cyy + czz + 1e-30f;
        float rt = __builtin_amdgcn_rcpf(tr);
        float xx = cxx*rt, xy = cxy*rt, xz = cxz*rt;
        float yy = cyy*rt, yz = cyz*rt, zz = czz*rt;
        #pragma unroll
        for (int it = 0; it < 3; ++it) {
            float nxx = fmaf(xx, xx, fmaf(xy, xy, xz * xz));
            float nxy = fmaf(xy, xx + yy, xz * yz);
            float nxz = fmaf(xz, xx + zz, xy * yz);
            float nyy = fmaf(xy, xy, fmaf(yy, yy, yz * yz));
            float nyz = fmaf(yz, yy + zz, xy * xz);
            float nzz = fmaf(xz, xz, fmaf(yz, yz, zz * zz));
            xx = nxx; xy = nxy; xz = nxz; yy = nyy; yz = nyz; zz = nzz;
        }
        float vx = xx + xy + xz;
        float vy = xy + yy + yz;
        float vz = xz + yz + zz;
        float nn = fmaf(vz, vz, fmaf(vy, vy, vx * vx)) + 1e-30f;
        float rr2 = __builtin_amdgcn_rsqf(nn) * inv_s * 2.0f;
        const float wax = vx * rr2, way = vy * rr2, waz = vz * rr2;

        asm volatile("" ::: "memory");

        // --- pass B: re-read LDS; excluded points forced to u=2 (mask) ---
        float a0 = 0.f, a1 = 0.f, a3 = 0.f, s1 = 0.f;
        #pragma unroll
        for (int j = 0; j < NP; ++j) {
            float4 q = cp[j];
            float dx = q.x - ox, dy = q.y - oy, dz = q.z - oz;
            float dd = fmaf(dz, dz, fmaf(dy, dy, dx * dx));
            float ur = fmaf(dz, waz, fmaf(dy, way, fmaf(dx, wax, 2.0f)));
            float u  = (dd <= thr) ? ur : 2.0f;
            a0 += satf(1.0f - fabsf(u));
            a1 += satf(1.0f - fabsf(u - 1.0f));
            a3 += satf(1.0f - fabsf(u - 3.0f));
            s1 += u;
        }
        const float P  = 30.0f - a0 - a1 - a3;        // a2 + a4 (incl. dummies)
        const float Q  = s1 - a1 - 3.0f * a3;         // 2*a2 + 4*a4
        const float a4 = fmaf(0.5f, Q, -P);
        const float a2 = P - a4 - 10.0f;  // self + 9 excluded sit at u=2 exactly

        #pragma unroll
        for (int f = 0; f < FN; ++f) {
            float acc = fmaf(a0, wS[0*FN+f],
                        fmaf(a1, wS[1*FN+f],
                        fmaf(a2, wS[2*FN+f],
                        fmaf(a3, wS[3*FN+f],
                             a4 * wS[4*FN+f]))));
            float y = fmaf(acc, 1.0f / (float)KNN, bS[f]);
            sbuf[tid][f] = __builtin_amdgcn_rcpf(1.0f + __expf(-y));
        }
    }
    __syncthreads();

    // ---------------- phase 2: cloud-mean -> MLP -> log_softmax ----------------
    if (tid < CPB * FN) {
        int c2 = tid / FN;
        int f  = tid - c2 * FN;
        float s = 0.0f;
        #pragma unroll
        for (int jj = 0; jj < NP; ++jj) s += sbuf[c2 * NP + jj][f];
        ysS[c2][f] = (base + c2 < B) ? s * (1.0f / (float)NP) : 0.0f;
    }
    // zero A-tile rows 8..15 (row-internal swizzle keeps zero-fill valid)
    {
        short8v z = {0, 0, 0, 0, 0, 0, 0, 0};
        *(short8v*)&hA[(8 + (tid >> 5)) * 256 + (tid & 31) * 8] = z;
    }
    __syncthreads();

    // layer 1: thread t = hidden unit t, for all 8 clouds (ysS broadcast reads)
    {
        float wv[FN];
        #pragma unroll
        for (int f = 0; f < FN; ++f) wv[f] = w1[f * 256 + tid];
        float bb = b1[tid];
        #pragma unroll
        for (int cc = 0; cc < CPB; ++cc) {
            float acc = bb;
            #pragma unroll
            for (int f = 0; f < FN; ++f) acc = fmaf(ysS[cc][f], wv[f], acc);
            float h = acc > 0.0f ? acc : __expf(acc) - 1.0f;
            hA[hA_idx(cc, tid)] = bf16r(h);
        }
    }
    __syncthreads();

    // layer 2: waves 0..2 each own one 16-col N-tile; B-frags global->regs
    if (w < 3) {
        const int  n   = w * 16 + (lane & 15);
        const bool nok = n < 40;
        const int  kg  = (lane >> 4) * 8;      // k-group offset within 32-step
        float4v acc = {0.f, 0.f, 0.f, 0.f};
        #pragma unroll
        for (int s = 0; s < 8; ++s) {
            short8v bfr;
            #pragma unroll
            for (int j = 0; j < 8; ++j) {
                float f = nok ? w2[(s * 32 + kg + j) * 40 + n] : 0.0f;
                bfr[j] = (short)bf16r(f);
            }
            short8v a = *(const short8v*)&hA[hA_idx(lane & 15, kg + s * 32)];
            acc = __builtin_amdgcn_mfma_f32_16x16x32_bf16(a, bfr, acc, 0, 0, 0);
        }
        // C/D: col=lane&15 (our n), row=(lane>>4)*4+r  [m89-verified]
        if (nok) {
            const float bc = b2[n];
            const int   r0 = (lane >> 4) * 4;
            #pragma unroll
            for (int r = 0; r < 4; ++r) {
                int rr = r0 + r;
                if (rr < CPB) Lg[rr][n] = acc[r] + bc;
            }
        }
    }
    __syncthreads();

    // log_softmax: 16-lane group per cloud
    if (tid < CPB * 16) {
        int cl = tid >> 4, l = tid & 15;
        float v0 = Lg[cl][l];
        float v1 = Lg[cl][l + 16];
        float v2 = (l < 8) ? Lg[cl][l + 32] : -INFINITY;
        float m = fmaxf(fmaxf(v0, v1), v2);
        #pragma unroll
        for (int msk = 1; msk < 16; msk <<= 1) m = fmaxf(m, __shfl_xor(m, msk));
        float e = __expf(v0 - m) + __expf(v1 - m) + ((l < 8) ? __expf(v2 - m) : 0.0f);
        #pragma unroll
        for (int msk = 1; msk < 16; msk <<= 1) e += __shfl_xor(e, msk);
        float ls = m + __logf(e);
        int cloud = base + cl;
        if (cloud < B) {
            float* op = out + (size_t)cloud * 40;
            op[l]      = v0 - ls;
            op[16 + l] = v1 - ls;
            if (l < 8) op[32 + l] = v2 - ls;
        }
    }
}

extern "C" void kernel_launch(void* const* d_in, const int* in_sizes, int n_in,
                              void* d_out, int out_size, void* d_ws, size_t ws_size,
                              hipStream_t stream) {
    const float* pos   = (const float*)d_in[0];
    const float* W     = (const float*)d_in[1];
    const float* b_dsc = (const float*)d_in[2];
    const float* w1    = (const float*)d_in[3];
    const float* b1    = (const float*)d_in[4];
    const float* w2    = (const float*)d_in[5];
    const float* b2    = (const float*)d_in[6];

    const int N = in_sizes[0] / 3;   // B*NP points
    const int B = N / NP;            // clouds

    const int grid = (B + CPB - 1) / CPB;
    fused_kernel<<<grid, T1, 0, stream>>>(pos, W, b_dsc, w1, b1, w2, b2,
                                          (float*)d_out, B);
}

// Round 9
// 34.839 us; speedup vs baseline: 2.7375x; 1.0368x over previous
//
#include <hip/hip_runtime.h>
#include <math.h>

#define NP 30      // points per cloud
#define KNN 20     // neighbors
#define KS 5       // spline control points
#define FN 10      // filter count
#define EPS 1e-8f
#define CPB 8      // clouds per block
#define T1 256     // block size

typedef __attribute__((ext_vector_type(8))) short short8v;
typedef __attribute__((ext_vector_type(4))) float float4v;

__device__ __forceinline__ float satf(float x) {
    return fminf(fmaxf(x, 0.0f), 1.0f);   // folds to clamp modifier
}
__device__ __forceinline__ unsigned short bf16r(float f) {   // f32 -> bf16 RNE
    unsigned u = __float_as_uint(f);
    u += 0x7fffu + ((u >> 16) & 1u);
    return (unsigned short)(u >> 16);
}
// hA swizzle: 16B granule g of row r -> g ^ (r&7). Kills the stride-512B
// 16-way bank conflict on the MFMA A-tile read.
__device__ __forceinline__ int hA_idx(int row, int col /*ushort*/) {
    return row * 256 + ((((col >> 3) ^ (row & 7)) << 3) | (col & 7));
}

// Fused dsc -> MLP -> log_softmax. One 256-thread block = 8 clouds.
// R9 design rule: true live state ~50 regs; BOUND in-flight LDS loads so the
// scheduler can't balloon live ranges into AGPR-caching (R7: VGPR=84 shown +
// hidden AGPRs -> 2 waves/SIMD + phantom accvgpr VALU traffic).
__global__ __launch_bounds__(T1, 7) void fused_kernel(
    const float* __restrict__ pos,     // [B*NP, 3]
    const float* __restrict__ W,       // [KS, FN]
    const float* __restrict__ b_dsc,   // [FN]
    const float* __restrict__ w1,      // [FN, 256]
    const float* __restrict__ b1,      // [256]
    const float* __restrict__ w2,      // [256, 40]
    const float* __restrict__ b2,      // [40]
    float* __restrict__ out,           // [B, 40]
    int B)
{
    __shared__ float4 ptsF[CPB * NP];                 // xyz + dead w
    __shared__ float sbuf[CPB * NP][FN + 1];          // sigmoid staging
    __shared__ float wS[KS * FN];
    __shared__ float bS[FN];
    __shared__ float ysS[CPB][FN];                    // per-cloud mean features
    __shared__ __align__(16) unsigned short hA[16 * 256];  // bf16 A-tile, swizzled
    __shared__ float Lg[CPB][48];                     // logits

    const int tid  = threadIdx.x;
    const int base = blockIdx.x * CPB;
    const int w    = tid >> 6;
    const int lane = tid & 63;

    // stage points (coalesced dword reads, scatter to float4 slots)
    {
        const int lim = min(CPB * NP * 3, B * NP * 3 - base * NP * 3);
        for (int d = tid; d < lim; d += T1) {
            float v  = pos[(size_t)base * (NP * 3) + d];
            int   pt = d / 3;
            ((float*)&ptsF[pt])[d - pt * 3] = v;
        }
    }
    if (tid < KS * FN) wS[tid] = W[tid];
    if (tid < FN)      bS[tid] = b_dsc[tid];
    __syncthreads();

    // ---------------- phase 1: per-point spline conv ----------------
    const int c = tid / NP;
    const int i = tid - c * NP;
    const bool active = (tid < CPB * NP) && (base + c < B);

    if (active) {
        const float4* cp = &ptsF[c * NP];
        const float4 own = cp[i];                 // dynamic LDS read, once
        const float ox = own.x, oy = own.y, oz = own.z;

        // --- distances (static vals[j] => must stay unrolled); chunk-barrier
        //     every 5 iters bounds in-flight ds_reads to ~5-10 (not 30) ---
        float vals[32];
        #pragma unroll
        for (int j = 0; j < NP; ++j) {
            float4 q = cp[j];                     // broadcast b128
            float dx = q.x - ox, dy = q.y - oy, dz = q.z - oz;
            vals[j] = fmaf(dz, dz, fmaf(dy, dy, dx * dx));  // self == 0
            if ((j % 5) == 4) asm volatile("" ::: "memory");
        }
        vals[30] = 1e11f;
        vals[31] = 1e11f;

        // --- bitonic stages k=2..16 (register-only, fully unrolled) ---
        #pragma unroll
        for (int k = 2; k <= 16; k <<= 1) {
            #pragma unroll
            for (int jj = k >> 1; jj > 0; jj >>= 1) {
                #pragma unroll
                for (int tt = 0; tt < 32; ++tt) {
                    int l = tt ^ jj;
                    if (l > tt) {
                        float a  = vals[tt], b = vals[l];
                        float lo = fminf(a, b), hi = fmaxf(a, b);
                        if ((tt & k) == 0) { vals[tt] = lo; vals[l] = hi; }
                        else               { vals[tt] = hi; vals[l] = lo; }
                    }
                }
            }
        }
        // --- final merge (k=32) pruned to output index 20 ---
        #pragma unroll
        for (int q = 0; q < 16; ++q) vals[16+q] = fmaxf(vals[q], vals[16+q]);
        #pragma unroll
        for (int q = 0; q < 8; ++q)  vals[16+q] = fminf(vals[16+q], vals[24+q]);
        #pragma unroll
        for (int q = 0; q < 4; ++q)  vals[20+q] = fmaxf(vals[16+q], vals[20+q]);
        vals[20] = fminf(vals[20], vals[22]);
        vals[21] = fminf(vals[21], vals[23]);
        const float thr = fminf(vals[20], vals[21]);   // 20th-smallest non-self d2

        const float scale = sqrtf(thr + EPS) + EPS;
        const float inv_s = __builtin_amdgcn_rcpf(scale);

        asm volatile("" ::: "memory");

        // --- pass A: RUNTIME loop (unroll 5) — dynamic LDS reads are fine,
        //     backedge stops load hoisting. Recomputed dd is bit-identical. ---
        float cxx=0.f, cxy=0.f, cxz=0.f, cyy=0.f, cyz=0.f, czz=0.f;
        #pragma unroll 5
        for (int j = 0; j < NP; ++j) {
            float4 q = cp[j];
            float dx = q.x - ox, dy = q.y - oy, dz = q.z - oz;
            float dd = fmaf(dz, dz, fmaf(dy, dy, dx * dx));
            bool sel = (dd <= thr);
            float mx = sel ? dx : 0.0f;
            float my = sel ? dy : 0.0f;
            float mz = sel ? dz : 0.0f;
            cxx = fmaf(mx, mx, cxx); cxy = fmaf(mx, my, cxy); cxz = fmaf(mx, mz, cxz);
            cyy = fmaf(my, my, cyy); cyz = fmaf(my, mz, cyz); czz = fmaf(mz, mz, czz);
        }

        // power iteration x8 == C^8 v0: trace-normalize + 3 symmetric squarings
        float tr = cxx + cyy + czz + 1e-30f;
        float rt = __builtin_amdgcn_rcpf(tr);
        float xx = cxx*rt, xy = cxy*rt, xz = cxz*rt;
        float yy = cyy*rt, yz = cyz*rt, zz = czz*rt;
        #pragma unroll
        for (int it = 0; it < 3; ++it) {
            float nxx = fmaf(xx, xx, fmaf(xy, xy, xz * xz));
            float nxy = fmaf(xy, xx + yy, xz * yz);
            float nxz = fmaf(xz, xx + zz, xy * yz);
            float nyy = fmaf(xy, xy, fmaf(yy, yy, yz * yz));
            float nyz = fmaf(yz, yy + zz, xy * xz);
            float nzz = fmaf(xz, xz, fmaf(yz, yz, zz * zz));
            xx = nxx; xy = nxy; xz = nxz; yy = nyy; yz = nyz; zz = nzz;
        }
        float vx = xx + xy + xz;
        float vy = xy + yy + yz;
        float vz = xz + yz + zz;
        float nn = fmaf(vz, vz, fmaf(vy, vy, vx * vx)) + 1e-30f;
        float rr2 = __builtin_amdgcn_rsqf(nn) * inv_s * 2.0f;
        const float wax = vx * rr2, way = vy * rr2, waz = vz * rr2;

        asm volatile("" ::: "memory");

        // --- pass B: RUNTIME loop (unroll 5); excluded forced to u=2 ---
        float a0 = 0.f, a1 = 0.f, a3 = 0.f, s1 = 0.f;
        #pragma unroll 5
        for (int j = 0; j < NP; ++j) {
            float4 q = cp[j];
            float dx = q.x - ox, dy = q.y - oy, dz = q.z - oz;
            float dd = fmaf(dz, dz, fmaf(dy, dy, dx * dx));
            float ur = fmaf(dz, waz, fmaf(dy, way, fmaf(dx, wax, 2.0f)));
            float u  = (dd <= thr) ? ur : 2.0f;
            a0 += satf(1.0f - fabsf(u));
            a1 += satf(1.0f - fabsf(u - 1.0f));
            a3 += satf(1.0f - fabsf(u - 3.0f));
            s1 += u;
        }
        const float P  = 30.0f - a0 - a1 - a3;        // a2 + a4 (incl. dummies)
        const float Q  = s1 - a1 - 3.0f * a3;         // 2*a2 + 4*a4
        const float a4 = fmaf(0.5f, Q, -P);
        const float a2 = P - a4 - 10.0f;  // self + 9 excluded sit at u=2 exactly

        #pragma unroll
        for (int f = 0; f < FN; ++f) {
            float acc = fmaf(a0, wS[0*FN+f],
                        fmaf(a1, wS[1*FN+f],
                        fmaf(a2, wS[2*FN+f],
                        fmaf(a3, wS[3*FN+f],
                             a4 * wS[4*FN+f]))));
            float y = fmaf(acc, 1.0f / (float)KNN, bS[f]);
            sbuf[tid][f] = __builtin_amdgcn_rcpf(1.0f + __expf(-y));
        }
    }
    __syncthreads();

    // ---------------- phase 2: cloud-mean -> MLP -> log_softmax ----------------
    if (tid < CPB * FN) {
        int c2 = tid / FN;
        int f  = tid - c2 * FN;
        float s = 0.0f;
        #pragma unroll
        for (int jj = 0; jj < NP; ++jj) s += sbuf[c2 * NP + jj][f];
        ysS[c2][f] = (base + c2 < B) ? s * (1.0f / (float)NP) : 0.0f;
    }
    // zero A-tile rows 8..15 (row-internal swizzle keeps zero-fill valid)
    {
        short8v z = {0, 0, 0, 0, 0, 0, 0, 0};
        *(short8v*)&hA[(8 + (tid >> 5)) * 256 + (tid & 31) * 8] = z;
    }
    __syncthreads();

    // layer 1: thread t = hidden unit t, for all 8 clouds (ysS broadcast reads)
    {
        float wv[FN];
        #pragma unroll
        for (int f = 0; f < FN; ++f) wv[f] = w1[f * 256 + tid];
        float bb = b1[tid];
        #pragma unroll
        for (int cc = 0; cc < CPB; ++cc) {
            float acc = bb;
            #pragma unroll
            for (int f = 0; f < FN; ++f) acc = fmaf(ysS[cc][f], wv[f], acc);
            float h = acc > 0.0f ? acc : __expf(acc) - 1.0f;
            hA[hA_idx(cc, tid)] = bf16r(h);
        }
    }
    __syncthreads();

    // layer 2: waves 0..2 each own one 16-col N-tile; B-frags global->regs
    if (w < 3) {
        const int  n   = w * 16 + (lane & 15);
        const bool nok = n < 40;
        const int  kg  = (lane >> 4) * 8;      // k-group offset within 32-step
        float4v acc = {0.f, 0.f, 0.f, 0.f};
        #pragma unroll
        for (int s = 0; s < 8; ++s) {
            short8v bfr;
            #pragma unroll
            for (int j = 0; j < 8; ++j) {
                float f = nok ? w2[(s * 32 + kg + j) * 40 + n] : 0.0f;
                bfr[j] = (short)bf16r(f);
            }
            short8v a = *(const short8v*)&hA[hA_idx(lane & 15, kg + s * 32)];
            acc = __builtin_amdgcn_mfma_f32_16x16x32_bf16(a, bfr, acc, 0, 0, 0);
        }
        // C/D: col=lane&15 (our n), row=(lane>>4)*4+r  [m89-verified]
        if (nok) {
            const float bc = b2[n];
            const int   r0 = (lane >> 4) * 4;
            #pragma unroll
            for (int r = 0; r < 4; ++r) {
                int rr = r0 + r;
                if (rr < CPB) Lg[rr][n] = acc[r] + bc;
            }
        }
    }
    __syncthreads();

    // log_softmax: 16-lane group per cloud
    if (tid < CPB * 16) {
        int cl = tid >> 4, l = tid & 15;
        float v0 = Lg[cl][l];
        float v1 = Lg[cl][l + 16];
        float v2 = (l < 8) ? Lg[cl][l + 32] : -INFINITY;
        float m = fmaxf(fmaxf(v0, v1), v2);
        #pragma unroll
        for (int msk = 1; msk < 16; msk <<= 1) m = fmaxf(m, __shfl_xor(m, msk));
        float e = __expf(v0 - m) + __expf(v1 - m) + ((l < 8) ? __expf(v2 - m) : 0.0f);
        #pragma unroll
        for (int msk = 1; msk < 16; msk <<= 1) e += __shfl_xor(e, msk);
        float ls = m + __logf(e);
        int cloud = base + cl;
        if (cloud < B) {
            float* op = out + (size_t)cloud * 40;
            op[l]      = v0 - ls;
            op[16 + l] = v1 - ls;
            if (l < 8) op[32 + l] = v2 - ls;
        }
    }
}

extern "C" void kernel_launch(void* const* d_in, const int* in_sizes, int n_in,
                              void* d_out, int out_size, void* d_ws, size_t ws_size,
                              hipStream_t stream) {
    const float* pos   = (const float*)d_in[0];
    const float* W     = (const float*)d_in[1];
    const float* b_dsc = (const float*)d_in[2];
    const float* w1    = (const float*)d_in[3];
    const float* b1    = (const float*)d_in[4];
    const float* w2    = (const float*)d_in[5];
    const float* b2    = (const float*)d_in[6];

    const int N = in_sizes[0] / 3;   // B*NP points
    const int B = N / NP;            // clouds

    const int grid = (B + CPB - 1) / CPB;
    fused_kernel<<<grid, T1, 0, stream>>>(pos, W, b_dsc, w1, b1, w2, b2,
                                          (float*)d_out, B);
}

// Round 10
// 33.369 us; speedup vs baseline: 2.8580x; 1.0440x over previous
//
#include <hip/hip_runtime.h>
#include <math.h>

#define NP 30      // points per cloud
#define KNN 20     // neighbors
#define KS 5       // spline control points
#define FN 10      // filter count
#define EPS 1e-8f
#define CPB 8      // clouds per block
#define T1 256     // block size

typedef __attribute__((ext_vector_type(8))) short short8v;
typedef __attribute__((ext_vector_type(4))) float float4v;

__device__ __forceinline__ float satf(float x) {
    return fminf(fmaxf(x, 0.0f), 1.0f);   // folds to clamp modifier
}
__device__ __forceinline__ unsigned short bf16r(float f) {   // f32 -> bf16 RNE
    unsigned u = __float_as_uint(f);
    u += 0x7fffu + ((u >> 16) & 1u);
    return (unsigned short)(u >> 16);
}
__device__ __forceinline__ float rlanef(float v, int l) {    // wave broadcast
    return __int_as_float(__builtin_amdgcn_readlane(__float_as_int(v), l));
}
// hA swizzle: 16B granule g of row r -> g ^ (r&7); kills stride-512B conflicts
__device__ __forceinline__ int hA_idx(int row, int col) {
    return row * 256 + ((((col >> 3) ^ (row & 7)) << 3) | (col & 7));
}
// pack point index into low 5 mantissa bits of d2 (sort stays float-compare)
__device__ __forceinline__ float packdi(float d2, int j) {
    return __uint_as_float((__float_as_uint(d2) & ~31u) | (unsigned)j);
}

// Fused dsc -> MLP -> log_softmax. One 256-thread block = 8 clouds.
// R10: LDS-pipe is the bottleneck (per-CU shared; ~1740cyc/wave vs VALU 3700
// on 4 SIMDs). Cut LDS work: merge dist+cov pass via index-packed sort
// (90->69 b128 reads) and replace layer-1's 80 LDS broadcasts with readlane.
__global__ __launch_bounds__(T1, 7) void fused_kernel(
    const float* __restrict__ pos,     // [B*NP, 3]
    const float* __restrict__ W,       // [KS, FN]
    const float* __restrict__ b_dsc,   // [FN]
    const float* __restrict__ w1,      // [FN, 256]
    const float* __restrict__ b1,      // [256]
    const float* __restrict__ w2,      // [256, 40]
    const float* __restrict__ b2,      // [40]
    float* __restrict__ out,           // [B, 40]
    int B)
{
    __shared__ float4 ptsF[CPB * NP];                 // xyz + dead w
    __shared__ float sbuf[CPB * NP][FN + 1];          // sigmoid staging
    __shared__ float wS[KS * FN];
    __shared__ float bS[FN];
    __shared__ float ysS[CPB * FN];                   // flat [80]
    __shared__ __align__(16) unsigned short hA[16 * 256];  // bf16 A-tile, swizzled
    __shared__ float Lg[CPB][48];                     // logits

    const int tid  = threadIdx.x;
    const int base = blockIdx.x * CPB;
    const int w    = tid >> 6;
    const int lane = tid & 63;

    // stage points (coalesced dword reads, scatter to float4 slots)
    {
        const int lim = min(CPB * NP * 3, B * NP * 3 - base * NP * 3);
        for (int d = tid; d < lim; d += T1) {
            float v  = pos[(size_t)base * (NP * 3) + d];
            int   pt = d / 3;
            ((float*)&ptsF[pt])[d - pt * 3] = v;
        }
    }
    if (tid < KS * FN) wS[tid] = W[tid];
    if (tid < FN)      bS[tid] = b_dsc[tid];
    __syncthreads();

    // ---------------- phase 1: per-point spline conv ----------------
    const int c = tid / NP;
    const int i = tid - c * NP;
    const bool active = (tid < CPB * NP) && (base + c < B);

    if (active) {
        const float4* cp = &ptsF[c * NP];
        const float4 own = cp[i];
        const float ox = own.x, oy = own.y, oz = own.z;

        // --- pass 1 (merged): d2+index pack AND full (unmasked) covariance ---
        float vals[32];
        float cxx=0.f, cxy=0.f, cxz=0.f, cyy=0.f, cyz=0.f, czz=0.f;
        #pragma unroll
        for (int j = 0; j < NP; ++j) {
            float4 q = cp[j];                     // broadcast b128
            float dx = q.x - ox, dy = q.y - oy, dz = q.z - oz;
            float d2 = fmaf(dz, dz, fmaf(dy, dy, dx * dx));  // self == 0
            vals[j] = packdi(d2, j);
            cxx = fmaf(dx, dx, cxx); cxy = fmaf(dx, dy, cxy); cxz = fmaf(dx, dz, cxz);
            cyy = fmaf(dy, dy, cyy); cyz = fmaf(dy, dz, cyz); czz = fmaf(dz, dz, czz);
            if ((j % 5) == 4) asm volatile("" ::: "memory");  // bound in-flight loads
        }
        vals[30] = packdi(1e11f, 30);
        vals[31] = packdi(1e11f, 31);

        // --- bitonic stages k=2..16: halves [0..15] asc, [16..31] desc ---
        #pragma unroll
        for (int k = 2; k <= 16; k <<= 1) {
            #pragma unroll
            for (int jj = k >> 1; jj > 0; jj >>= 1) {
                #pragma unroll
                for (int tt = 0; tt < 32; ++tt) {
                    int l = tt ^ jj;
                    if (l > tt) {
                        float a  = vals[tt], b = vals[l];
                        float lo = fminf(a, b), hi = fmaxf(a, b);
                        if ((tt & k) == 0) { vals[tt] = lo; vals[l] = hi; }
                        else               { vals[tt] = hi; vals[l] = lo; }
                    }
                }
            }
        }
        // k=32 merge, j=16: lower half = 16 smallest, upper = 16 largest
        #pragma unroll
        for (int q = 0; q < 16; ++q) {
            float a = vals[q], b = vals[16 + q];
            vals[q] = fminf(a, b); vals[16 + q] = fmaxf(a, b);
        }
        // fully sort upper 16 ascending (bitonic merge j=8,4,2,1)
        #pragma unroll
        for (int jj = 8; jj > 0; jj >>= 1) {
            #pragma unroll
            for (int tt = 16; tt < 32; ++tt) {
                int l = tt ^ jj;
                if (l > tt) {
                    float a = vals[tt], b = vals[l];
                    vals[tt] = fminf(a, b); vals[l] = fmaxf(a, b);
                }
            }
        }
        // rank 20 (self + 20 neighbors selected); ranks 21..29 = excluded reals
        const float thr_d2 = __uint_as_float(__float_as_uint(vals[20]) & ~31u);
        const float scale  = sqrtf(thr_d2 + EPS) + EPS;
        const float inv_s  = __builtin_amdgcn_rcpf(scale);

        // --- subtract excluded outer products; build exclusion bitmask ---
        unsigned excl = 0u;
        #pragma unroll
        for (int q = 21; q < 30; ++q) {
            unsigned bq  = __float_as_uint(vals[q]);
            int      idx = (int)(bq & 31u);
            float4 p = cp[idx];                   // scattered LDS b128
            float dx = p.x - ox, dy = p.y - oy, dz = p.z - oz;
            cxx = fmaf(-dx, dx, cxx); cxy = fmaf(-dx, dy, cxy); cxz = fmaf(-dx, dz, cxz);
            cyy = fmaf(-dy, dy, cyy); cyz = fmaf(-dy, dz, cyz); czz = fmaf(-dz, dz, czz);
            excl |= (1u << idx);
        }

        // --- power iteration x8 == C^8 v0: trace-norm + 3 symmetric squarings ---
        float tr = cxx + cyy + czz + 1e-30f;
        float rt = __builtin_amdgcn_rcpf(tr);
        float xx = cxx*rt, xy = cxy*rt, xz = cxz*rt;
        float yy = cyy*rt, yz = cyz*rt, zz = czz*rt;
        #pragma unroll
        for (int it = 0; it < 3; ++it) {
            float nxx = fmaf(xx, xx, fmaf(xy, xy, xz * xz));
            float nxy = fmaf(xy, xx + yy, xz * yz);
            float nxz = fmaf(xz, xx + zz, xy * yz);
            float nyy = fmaf(xy, xy, fmaf(yy, yy, yz * yz));
            float nyz = fmaf(yz, yy + zz, xy * xz);
            float nzz = fmaf(xz, xz, fmaf(yz, yz, zz * zz));
            xx = nxx; xy = nxy; xz = nxz; yy = nyy; yz = nyz; zz = nzz;
        }
        float vx = xx + xy + xz;
        float vy = xy + yy + yz;
        float vz = xz + yz + zz;
        float nn = fmaf(vz, vz, fmaf(vy, vy, vx * vx)) + 1e-30f;
        float rr2 = __builtin_amdgcn_rsqf(nn) * inv_s * 2.0f;
        const float wax = vx * rr2, way = vy * rr2, waz = vz * rr2;

        asm volatile("" ::: "memory");

        // --- pass B: excluded forced to u=2 via bitmask (no dd recompute) ---
        float a0 = 0.f, a1 = 0.f, a3 = 0.f, s1 = 0.f;
        #pragma unroll 5
        for (int j = 0; j < NP; ++j) {
            float4 q = cp[j];
            float dx = q.x - ox, dy = q.y - oy, dz = q.z - oz;
            float ur = fmaf(dz, waz, fmaf(dy, way, fmaf(dx, wax, 2.0f)));
            float u  = ((excl >> j) & 1u) ? 2.0f : ur;
            a0 += satf(1.0f - fabsf(u));
            a1 += satf(1.0f - fabsf(u - 1.0f));
            a3 += satf(1.0f - fabsf(u - 3.0f));
            s1 += u;
        }
        const float P  = 30.0f - a0 - a1 - a3;        // a2 + a4 (incl. dummies)
        const float Q  = s1 - a1 - 3.0f * a3;         // 2*a2 + 4*a4
        const float a4 = fmaf(0.5f, Q, -P);
        const float a2 = P - a4 - 10.0f;  // self + 9 excluded sit at u=2 exactly

        #pragma unroll
        for (int f = 0; f < FN; ++f) {
            float acc = fmaf(a0, wS[0*FN+f],
                        fmaf(a1, wS[1*FN+f],
                        fmaf(a2, wS[2*FN+f],
                        fmaf(a3, wS[3*FN+f],
                             a4 * wS[4*FN+f]))));
            float y = fmaf(acc, 1.0f / (float)KNN, bS[f]);
            sbuf[tid][f] = __builtin_amdgcn_rcpf(1.0f + __expf(-y));
        }
    }
    __syncthreads();

    // ---------------- phase 2: cloud-mean -> MLP -> log_softmax ----------------
    if (tid < CPB * FN) {
        int c2 = tid / FN;
        int f  = tid - c2 * FN;
        float s = 0.0f;
        #pragma unroll
        for (int jj = 0; jj < NP; ++jj) s += sbuf[c2 * NP + jj][f];
        ysS[tid] = (base + c2 < B) ? s * (1.0f / (float)NP) : 0.0f;
        (void)f;
    }
    // zero A-tile rows 8..15
    {
        short8v z = {0, 0, 0, 0, 0, 0, 0, 0};
        *(short8v*)&hA[(8 + (tid >> 5)) * 256 + (tid & 31) * 8] = z;
    }
    __syncthreads();

    // layer 1: readlane-broadcast ys (2 LDS reads/thread instead of 80)
    {
        float ya = ysS[lane];                 // lanes 0..63 hold ys[0..63]
        float yb = ysS[64 + (lane & 15)];     // lanes 0..15 hold ys[64..79]
        float wv[FN];
        #pragma unroll
        for (int f = 0; f < FN; ++f) wv[f] = w1[f * 256 + tid];
        float bb = b1[tid];
        #pragma unroll
        for (int cc = 0; cc < CPB; ++cc) {
            float acc = bb;
            #pragma unroll
            for (int f = 0; f < FN; ++f) {
                const int flat = cc * FN + f;
                float yv = (flat < 64) ? rlanef(ya, flat) : rlanef(yb, flat - 64);
                acc = fmaf(yv, wv[f], acc);
            }
            float h = acc > 0.0f ? acc : __expf(acc) - 1.0f;
            hA[hA_idx(cc, tid)] = bf16r(h);
        }
    }
    __syncthreads();

    // layer 2: waves 0..2 each own one 16-col N-tile; B-frags global->regs
    if (w < 3) {
        const int  n   = w * 16 + (lane & 15);
        const bool nok = n < 40;
        const int  kg  = (lane >> 4) * 8;      // k-group offset within 32-step
        float4v acc = {0.f, 0.f, 0.f, 0.f};
        #pragma unroll
        for (int s = 0; s < 8; ++s) {
            short8v bfr;
            #pragma unroll
            for (int j = 0; j < 8; ++j) {
                float f = nok ? w2[(s * 32 + kg + j) * 40 + n] : 0.0f;
                bfr[j] = (short)bf16r(f);
            }
            short8v a = *(const short8v*)&hA[hA_idx(lane & 15, kg + s * 32)];
            acc = __builtin_amdgcn_mfma_f32_16x16x32_bf16(a, bfr, acc, 0, 0, 0);
        }
        // C/D: col=lane&15 (our n), row=(lane>>4)*4+r  [m89-verified]
        if (nok) {
            const float bc = b2[n];
            const int   r0 = (lane >> 4) * 4;
            #pragma unroll
            for (int r = 0; r < 4; ++r) {
                int rr = r0 + r;
                if (rr < CPB) Lg[rr][n] = acc[r] + bc;
            }
        }
    }
    __syncthreads();

    // log_softmax: 16-lane group per cloud
    if (tid < CPB * 16) {
        int cl = tid >> 4, l = tid & 15;
        float v0 = Lg[cl][l];
        float v1 = Lg[cl][l + 16];
        float v2 = (l < 8) ? Lg[cl][l + 32] : -INFINITY;
        float m = fmaxf(fmaxf(v0, v1), v2);
        #pragma unroll
        for (int msk = 1; msk < 16; msk <<= 1) m = fmaxf(m, __shfl_xor(m, msk));
        float e = __expf(v0 - m) + __expf(v1 - m) + ((l < 8) ? __expf(v2 - m) : 0.0f);
        #pragma unroll
        for (int msk = 1; msk < 16; msk <<= 1) e += __shfl_xor(e, msk);
        float ls = m + __logf(e);
        int cloud = base + cl;
        if (cloud < B) {
            float* op = out + (size_t)cloud * 40;
            op[l]      = v0 - ls;
            op[16 + l] = v1 - ls;
            if (l < 8) op[32 + l] = v2 - ls;
        }
    }
}

extern "C" void kernel_launch(void* const* d_in, const int* in_sizes, int n_in,
                              void* d_out, int out_size, void* d_ws, size_t ws_size,
                              hipStream_t stream) {
    const float* pos   = (const float*)d_in[0];
    const float* W     = (const float*)d_in[1];
    const float* b_dsc = (const float*)d_in[2];
    const float* w1    = (const float*)d_in[3];
    const float* b1    = (const float*)d_in[4];
    const float* w2    = (const float*)d_in[5];
    const float* b2    = (const float*)d_in[6];

    const int N = in_sizes[0] / 3;   // B*NP points
    const int B = N / NP;            // clouds

    const int grid = (B + CPB - 1) / CPB;
    fused_kernel<<<grid, T1, 0, stream>>>(pos, W, b_dsc, w1, b1, w2, b2,
                                          (float*)d_out, B);
}

// Round 11
// 32.682 us; speedup vs baseline: 2.9181x; 1.0210x over previous
//
#include <hip/hip_runtime.h>
#include <math.h>

#define NP 30      // points per cloud
#define KNN 20     // neighbors
#define KS 5       // spline control points
#define FN 10      // filter count
#define EPS 1e-8f
#define CPB 8      // clouds per block
#define T1 256     // block size

typedef __attribute__((ext_vector_type(8))) short short8v;
typedef __attribute__((ext_vector_type(4))) float float4v;

__device__ __forceinline__ float satf(float x) {
    return fminf(fmaxf(x, 0.0f), 1.0f);   // folds to clamp modifier
}
__device__ __forceinline__ unsigned short bf16r(float f) {   // f32 -> bf16 RNE
    unsigned u = __float_as_uint(f);
    u += 0x7fffu + ((u >> 16) & 1u);
    return (unsigned short)(u >> 16);
}
__device__ __forceinline__ float rlanef(float v, int l) {    // wave broadcast
    return __int_as_float(__builtin_amdgcn_readlane(__float_as_int(v), l));
}
// hA swizzle: 16B granule g of row r -> g ^ (r&7); kills stride-512B conflicts
__device__ __forceinline__ int hA_idx(int row, int col) {
    return row * 256 + ((((col >> 3) ^ (row & 7)) << 3) | (col & 7));
}
// pack point index into low 5 mantissa bits (sort stays float-compare)
__device__ __forceinline__ float packdi(float v, int j) {
    return __uint_as_float((__float_as_uint(v) & ~31u) | (unsigned)j);
}

// Fused dsc -> MLP -> log_softmax. One 256-thread block = 8 clouds.
// R11: cov via cloud-level G=sum(p p^T), s=sum(p) (LDS-reduced once per cloud)
// + dot-form distances (n2 staged in float4.w) + dot-form spline parameter.
__global__ __launch_bounds__(T1, 7) void fused_kernel(
    const float* __restrict__ pos,     // [B*NP, 3]
    const float* __restrict__ W,       // [KS, FN]
    const float* __restrict__ b_dsc,   // [FN]
    const float* __restrict__ w1,      // [FN, 256]
    const float* __restrict__ b1,      // [256]
    const float* __restrict__ w2,      // [256, 40]
    const float* __restrict__ b2,      // [40]
    float* __restrict__ out,           // [B, 40]
    int B)
{
    __shared__ float4 ptsF[CPB * NP];                 // x,y,z,|p|^2
    __shared__ float sb[CPB * NP][11];                // outer-staging, then sigmoid
    __shared__ __align__(16) float Gs[CPB][12];       // gxx gxy gxz gyy gyz gzz sx sy sz
    __shared__ float wS[KS * FN];                     // pre-scaled by -log2e/20
    __shared__ float bS[FN];                          // pre-scaled by -log2e
    __shared__ float ysS[CPB * FN];
    __shared__ __align__(16) unsigned short hA[16 * 256];
    __shared__ float Lg[CPB][48];

    const int tid  = threadIdx.x;
    const int base = blockIdx.x * CPB;
    const int w    = tid >> 6;
    const int lane = tid & 63;

    // stage: one point per thread (xyz + |p|^2), no div-by-3 addressing
    if (tid < CPB * NP) {
        int gp = base * NP + tid;
        if (gp < B * NP) {
            const float* pp = pos + (size_t)gp * 3;
            float x = pp[0], y = pp[1], z = pp[2];
            float n2 = fmaf(z, z, fmaf(y, y, x * x));
            ptsF[tid] = make_float4(x, y, z, n2);
        } else {
            ptsF[tid] = make_float4(0.f, 0.f, 0.f, 0.f);
        }
    }
    if (tid < KS * FN) wS[tid] = W[tid] * (-0.07213475204444817f);  // -log2e/20
    if (tid < FN)      bS[tid] = b_dsc[tid] * (-1.4426950408889634f);
    __syncthreads();                                              // S1

    const int c = tid / NP;
    const int i = tid - c * NP;
    const bool active = (tid < CPB * NP) && (base + c < B);

    float vals[32];
    float ox = 0.f, oy = 0.f, oz = 0.f, oo = 0.f;

    if (active) {
        const float4* cp = &ptsF[c * NP];
        float4 own = cp[i];                       // dynamic LDS read, once
        ox = own.x; oy = own.y; oz = own.z; oo = own.w;

        // own outer products + coords -> LDS (for cloud-level G,s reduce)
        sb[tid][0] = ox * ox; sb[tid][1] = ox * oy; sb[tid][2] = ox * oz;
        sb[tid][3] = oy * oy; sb[tid][4] = oy * oz; sb[tid][5] = oz * oz;
        sb[tid][6] = ox;      sb[tid][7] = oy;     sb[tid][8] = oz;

        // keys: key_j = n2_j - 2 p_j.o = d2_j - oo (monotone shift; self = -oo exact)
        #pragma unroll
        for (int j = 0; j < NP; ++j) {
            float4 q = cp[j];
            float dt = fmaf(q.z, oz, fmaf(q.y, oy, q.x * ox));
            float key = fmaf(-2.0f, dt, q.w);
            vals[j] = packdi(key, j);
            if ((j % 5) == 4) asm volatile("" ::: "memory");  // bound in-flight loads
        }
        vals[30] = packdi(1e11f, 30);
        vals[31] = packdi(1e11f, 31);

        // bitonic stages k=2..16: halves [0..15] asc, [16..31] desc
        #pragma unroll
        for (int k = 2; k <= 16; k <<= 1) {
            #pragma unroll
            for (int jj = k >> 1; jj > 0; jj >>= 1) {
                #pragma unroll
                for (int tt = 0; tt < 32; ++tt) {
                    int l = tt ^ jj;
                    if (l > tt) {
                        float a  = vals[tt], b = vals[l];
                        float lo = fminf(a, b), hi = fmaxf(a, b);
                        if ((tt & k) == 0) { vals[tt] = lo; vals[l] = hi; }
                        else               { vals[tt] = hi; vals[l] = lo; }
                    }
                }
            }
        }
        // k=32 merge, j=16: upper half = 16 largest (lower half dead -> DCE)
        #pragma unroll
        for (int q = 0; q < 16; ++q) {
            float a = vals[q], b = vals[16 + q];
            vals[q] = fminf(a, b); vals[16 + q] = fmaxf(a, b);
        }
        // fully sort upper 16 ascending
        #pragma unroll
        for (int jj = 8; jj > 0; jj >>= 1) {
            #pragma unroll
            for (int tt = 16; tt < 32; ++tt) {
                int l = tt ^ jj;
                if (l > tt) {
                    float a = vals[tt], b = vals[l];
                    vals[tt] = fminf(a, b); vals[l] = fmaxf(a, b);
                }
            }
        }
    }
    __syncthreads();                                              // S2

    // G,s reduce: 72 threads (9 components x 8 clouds)
    if (tid >= T1 - 72) {
        int r    = tid - (T1 - 72);
        int cc   = r / 9;
        int comp = r - cc * 9;
        if (base + cc < B) {
            float s = 0.0f;
            #pragma unroll
            for (int k = 0; k < NP; ++k) s += sb[cc * NP + k][comp];
            Gs[cc][comp] = s;
        }
    }
    __syncthreads();                                              // S3

    if (active) {
        const float4* cp = &ptsF[c * NP];
        const float thr_key = __uint_as_float(__float_as_uint(vals[20]) & ~31u);
        const float thr_d2  = thr_key + oo;                 // rank-20 d2
        const float scale   = sqrtf(thr_d2 + EPS) + EPS;
        const float inv_s   = __builtin_amdgcn_rcpf(scale);

        // cov of ALL 30 rels from cloud G,s:  C = G - s o^T - o s^T + 30 o o^T
        float4 g0 = *(const float4*)&Gs[c][0];   // gxx gxy gxz gyy
        float4 g1 = *(const float4*)&Gs[c][4];   // gyz gzz sx  sy
        float  sx = g1.z, sy = g1.w, sz = Gs[c][8];
        float ax = fmaf(30.f, ox, -sx);
        float ay = fmaf(30.f, oy, -sy);
        float az = fmaf(30.f, oz, -sz);
        float cxx = fmaf(ox, ax, fmaf(-sx, ox, g0.x));
        float cxy = fmaf(oy, ax, fmaf(-sy, ox, g0.y));
        float cxz = fmaf(oz, ax, fmaf(-sz, ox, g0.z));
        float cyy = fmaf(oy, ay, fmaf(-sy, oy, g0.w));
        float cyz = fmaf(oz, ay, fmaf(-sz, oy, g1.x));
        float czz = fmaf(oz, az, fmaf(-sz, oz, g1.y));

        // subtract the 9 excluded outer products; build exclusion bitmask
        unsigned excl = 0u;
        #pragma unroll
        for (int q2 = 21; q2 < 30; ++q2) {
            unsigned bq  = __float_as_uint(vals[q2]);
            int      idx = (int)(bq & 31u);
            float4 p = cp[idx];
            float dx = p.x - ox, dy = p.y - oy, dz = p.z - oz;
            cxx = fmaf(-dx, dx, cxx); cxy = fmaf(-dx, dy, cxy); cxz = fmaf(-dx, dz, cxz);
            cyy = fmaf(-dy, dy, cyy); cyz = fmaf(-dy, dz, cyz); czz = fmaf(-dz, dz, czz);
            excl |= (1u << idx);
        }

        // power iteration x8 == C^8 v0: trace-norm + 3 symmetric squarings
        float tr = cxx + cyy + czz + 1e-30f;
        float rt = __builtin_amdgcn_rcpf(tr);
        float xx = cxx*rt, xy = cxy*rt, xz = cxz*rt;
        float yy = cyy*rt, yz = cyz*rt, zz = czz*rt;
        #pragma unroll
        for (int it = 0; it < 3; ++it) {
            float nxx = fmaf(xx, xx, fmaf(xy, xy, xz * xz));
            float nxy = fmaf(xy, xx + yy, xz * yz);
            float nxz = fmaf(xz, xx + zz, xy * yz);
            float nyy = fmaf(xy, xy, fmaf(yy, yy, yz * yz));
            float nyz = fmaf(yz, yy + zz, xy * xz);
            float nzz = fmaf(xz, xz, fmaf(yz, yz, zz * zz));
            xx = nxx; xy = nxy; xz = nxz; yy = nyy; yz = nyz; zz = nzz;
        }
        float vx = xx + xy + xz;
        float vy = xy + yy + yz;
        float vz = xz + yz + zz;
        float nn = fmaf(vz, vz, fmaf(vy, vy, vx * vx)) + 1e-30f;
        float rr2 = __builtin_amdgcn_rsqf(nn) * inv_s * 2.0f;
        const float wax = vx * rr2, way = vy * rr2, waz = vz * rr2;
        const float c0  = 2.0f - fmaf(oz, waz, fmaf(oy, way, ox * wax));

        // pass B: u = c0 + p.wa (dot form); excluded forced to u=2
        float a0 = 0.f, a1 = 0.f, a3 = 0.f, s1 = 0.f;
        #pragma unroll 5
        for (int j = 0; j < NP; ++j) {
            float4 q = cp[j];
            float ur = fmaf(q.z, waz, fmaf(q.y, way, fmaf(q.x, wax, c0)));
            float u  = ((excl >> j) & 1u) ? 2.0f : ur;
            a0 += satf(1.0f - fabsf(u));
            a1 += satf(1.0f - fabsf(u - 1.0f));
            a3 += satf(1.0f - fabsf(u - 3.0f));
            s1 += u;
        }
        const float P  = 30.0f - a0 - a1 - a3;
        const float Q  = s1 - a1 - 3.0f * a3;
        const float a4 = fmaf(0.5f, Q, -P);
        const float a2 = P - a4 - 10.0f;   // self + 9 excluded sit at u=2

        // sigmoid via exp2 (constants folded into wS/bS at stage time)
        #pragma unroll
        for (int f = 0; f < FN; ++f) {
            float acc = fmaf(a0, wS[0*FN+f],
                        fmaf(a1, wS[1*FN+f],
                        fmaf(a2, wS[2*FN+f],
                        fmaf(a3, wS[3*FN+f],
                             a4 * wS[4*FN+f]))));
            float z2 = acc + bS[f];                 // -y*log2e
            sb[tid][f] = __builtin_amdgcn_rcpf(1.0f + exp2f(z2));
        }
    }
    __syncthreads();                                              // S4

    // ys reduce (tid<80)
    if (tid < CPB * FN) {
        int c2 = tid / FN;
        float s = 0.0f;
        #pragma unroll
        for (int jj = 0; jj < NP; ++jj) s += sb[c2 * NP + jj][tid - c2 * FN];
        ysS[tid] = (base + c2 < B) ? s * (1.0f / (float)NP) : 0.0f;
    }
    // zero A-tile rows 8..15
    {
        short8v z = {0, 0, 0, 0, 0, 0, 0, 0};
        *(short8v*)&hA[(8 + (tid >> 5)) * 256 + (tid & 31) * 8] = z;
    }
    __syncthreads();                                              // S5

    // layer 1: readlane-broadcast ys (2 LDS reads/thread)
    {
        float ya = ysS[lane];
        float yb = ysS[64 + (lane & 15)];
        float wv[FN];
        #pragma unroll
        for (int f = 0; f < FN; ++f) wv[f] = w1[f * 256 + tid];
        float bb = b1[tid];
        #pragma unroll
        for (int cc = 0; cc < CPB; ++cc) {
            float acc = bb;
            #pragma unroll
            for (int f = 0; f < FN; ++f) {
                const int flat = cc * FN + f;
                float yv = (flat < 64) ? rlanef(ya, flat) : rlanef(yb, flat - 64);
                acc = fmaf(yv, wv[f], acc);
            }
            float h = acc > 0.0f ? acc : __expf(acc) - 1.0f;
            hA[hA_idx(cc, tid)] = bf16r(h);
        }
    }
    __syncthreads();                                              // S6

    // layer 2: waves 0..2 each own one 16-col N-tile; B-frags global->regs
    if (w < 3) {
        const int  n   = w * 16 + (lane & 15);
        const bool nok = n < 40;
        const int  kg  = (lane >> 4) * 8;
        float4v acc = {0.f, 0.f, 0.f, 0.f};
        #pragma unroll
        for (int s = 0; s < 8; ++s) {
            short8v bfr;
            #pragma unroll
            for (int j = 0; j < 8; ++j) {
                float f = nok ? w2[(s * 32 + kg + j) * 40 + n] : 0.0f;
                bfr[j] = (short)bf16r(f);
            }
            short8v a = *(const short8v*)&hA[hA_idx(lane & 15, kg + s * 32)];
            acc = __builtin_amdgcn_mfma_f32_16x16x32_bf16(a, bfr, acc, 0, 0, 0);
        }
        if (nok) {
            const float bc = b2[n];
            const int   r0 = (lane >> 4) * 4;
            #pragma unroll
            for (int r = 0; r < 4; ++r) {
                int rr = r0 + r;
                if (rr < CPB) Lg[rr][n] = acc[r] + bc;
            }
        }
    }
    __syncthreads();                                              // S7

    // log_softmax: 16-lane group per cloud
    if (tid < CPB * 16) {
        int cl = tid >> 4, l = tid & 15;
        float v0 = Lg[cl][l];
        float v1 = Lg[cl][l + 16];
        float v2 = (l < 8) ? Lg[cl][l + 32] : -INFINITY;
        float m = fmaxf(fmaxf(v0, v1), v2);
        #pragma unroll
        for (int msk = 1; msk < 16; msk <<= 1) m = fmaxf(m, __shfl_xor(m, msk));
        float e = __expf(v0 - m) + __expf(v1 - m) + ((l < 8) ? __expf(v2 - m) : 0.0f);
        #pragma unroll
        for (int msk = 1; msk < 16; msk <<= 1) e += __shfl_xor(e, msk);
        float ls = m + __logf(e);
        int cloud = base + cl;
        if (cloud < B) {
            float* op = out + (size_t)cloud * 40;
            op[l]      = v0 - ls;
            op[16 + l] = v1 - ls;
            if (l < 8) op[32 + l] = v2 - ls;
        }
    }
}

extern "C" void kernel_launch(void* const* d_in, const int* in_sizes, int n_in,
                              void* d_out, int out_size, void* d_ws, size_t ws_size,
                              hipStream_t stream) {
    const float* pos   = (const float*)d_in[0];
    const float* W     = (const float*)d_in[1];
    const float* b_dsc = (const float*)d_in[2];
    const float* w1    = (const float*)d_in[3];
    const float* b1    = (const float*)d_in[4];
    const float* w2    = (const float*)d_in[5];
    const float* b2    = (const float*)d_in[6];

    const int N = in_sizes[0] / 3;   // B*NP points
    const int B = N / NP;            // clouds

    const int grid = (B + CPB - 1) / CPB;
    fused_kernel<<<grid, T1, 0, stream>>>(pos, W, b_dsc, w1, b1, w2, b2,
                                          (float*)d_out, B);
}

// Round 12
// 32.459 us; speedup vs baseline: 2.9381x; 1.0069x over previous
//
#include <hip/hip_runtime.h>
#include <math.h>

#define NP 30      // points per cloud
#define KNN 20     // neighbors
#define KS 5       // spline control points
#define FN 10      // filter count
#define EPS 1e-8f
#define CPB 8      // clouds per block
#define T1 256     // block size

typedef __attribute__((ext_vector_type(8))) short short8v;
typedef __attribute__((ext_vector_type(4))) float float4v;

__device__ __forceinline__ float satf(float x) {
    return fminf(fmaxf(x, 0.0f), 1.0f);   // folds to clamp modifier
}
__device__ __forceinline__ unsigned short bf16r(float f) {   // f32 -> bf16 RNE
    unsigned u = __float_as_uint(f);
    u += 0x7fffu + ((u >> 16) & 1u);
    return (unsigned short)(u >> 16);
}
__device__ __forceinline__ float rlanef(float v, int l) {    // wave broadcast
    return __int_as_float(__builtin_amdgcn_readlane(__float_as_int(v), l));
}
// hA swizzle: 16B granule g of row r -> g ^ (r&7); kills stride-512B conflicts
__device__ __forceinline__ int hA_idx(int row, int col) {
    return row * 256 + ((((col >> 3) ^ (row & 7)) << 3) | (col & 7));
}
// pack point index into low 5 mantissa bits (sort stays float-compare)
__device__ __forceinline__ float packdi(float v, int j) {
    return __uint_as_float((__float_as_uint(v) & ~31u) | (unsigned)j);
}

// Fused dsc -> MLP -> log_softmax. One 256-thread block = 8 clouds.
// R12: __launch_bounds__(256,4) — target the 128-VGPR bracket exactly.
// (R7-R11 showed: asking for 6-7 waves/EU caps arch-VGPRs at ~73, the
// allocator overflows into AGPRs (unified file), total regs cross 128 and
// ACTUAL residency collapses to 2 waves/SIMD with phantom accvgpr traffic.
// 4 waves/EU = 128 regs is what vals[32]+scalars genuinely needs.)
__global__ __launch_bounds__(T1, 4) void fused_kernel(
    const float* __restrict__ pos,     // [B*NP, 3]
    const float* __restrict__ W,       // [KS, FN]
    const float* __restrict__ b_dsc,   // [FN]
    const float* __restrict__ w1,      // [FN, 256]
    const float* __restrict__ b1,      // [256]
    const float* __restrict__ w2,      // [256, 40]
    const float* __restrict__ b2,      // [40]
    float* __restrict__ out,           // [B, 40]
    int B)
{
    __shared__ float4 ptsF[CPB * NP];                 // x,y,z,|p|^2
    __shared__ float sb[CPB * NP][11];                // outer-staging, then sigmoid
    __shared__ __align__(16) float Gs[CPB][12];       // gxx gxy gxz gyy gyz gzz sx sy sz
    __shared__ float wS[KS * FN];                     // pre-scaled by -log2e/20
    __shared__ float bS[FN];                          // pre-scaled by -log2e
    __shared__ float ysS[CPB * FN];
    __shared__ __align__(16) unsigned short hA[16 * 256];
    __shared__ float Lg[CPB][48];

    const int tid  = threadIdx.x;
    const int base = blockIdx.x * CPB;
    const int w    = tid >> 6;
    const int lane = tid & 63;

    // stage: one point per thread (xyz + |p|^2)
    if (tid < CPB * NP) {
        int gp = base * NP + tid;
        if (gp < B * NP) {
            const float* pp = pos + (size_t)gp * 3;
            float x = pp[0], y = pp[1], z = pp[2];
            float n2 = fmaf(z, z, fmaf(y, y, x * x));
            ptsF[tid] = make_float4(x, y, z, n2);
        } else {
            ptsF[tid] = make_float4(0.f, 0.f, 0.f, 0.f);
        }
    }
    if (tid < KS * FN) wS[tid] = W[tid] * (-0.07213475204444817f);  // -log2e/20
    if (tid < FN)      bS[tid] = b_dsc[tid] * (-1.4426950408889634f);
    __syncthreads();                                              // S1

    const int c = tid / NP;
    const int i = tid - c * NP;
    const bool active = (tid < CPB * NP) && (base + c < B);

    float vals[32];
    float ox = 0.f, oy = 0.f, oz = 0.f, oo = 0.f;

    if (active) {
        const float4* cp = &ptsF[c * NP];
        float4 own = cp[i];                       // dynamic LDS read, once
        ox = own.x; oy = own.y; oz = own.z; oo = own.w;

        // own outer products + coords -> LDS (for cloud-level G,s reduce)
        sb[tid][0] = ox * ox; sb[tid][1] = ox * oy; sb[tid][2] = ox * oz;
        sb[tid][3] = oy * oy; sb[tid][4] = oy * oz; sb[tid][5] = oz * oz;
        sb[tid][6] = ox;      sb[tid][7] = oy;     sb[tid][8] = oz;

        // keys: key_j = n2_j - 2 p_j.o = d2_j - oo (monotone shift; self exact)
        #pragma unroll
        for (int j = 0; j < NP; ++j) {
            float4 q = cp[j];
            float dt = fmaf(q.z, oz, fmaf(q.y, oy, q.x * ox));
            float key = fmaf(-2.0f, dt, q.w);
            vals[j] = packdi(key, j);
            if ((j % 5) == 4) asm volatile("" ::: "memory");  // bound in-flight loads
        }
        vals[30] = packdi(1e11f, 30);
        vals[31] = packdi(1e11f, 31);

        // bitonic stages k=2..16: halves [0..15] asc, [16..31] desc
        #pragma unroll
        for (int k = 2; k <= 16; k <<= 1) {
            #pragma unroll
            for (int jj = k >> 1; jj > 0; jj >>= 1) {
                #pragma unroll
                for (int tt = 0; tt < 32; ++tt) {
                    int l = tt ^ jj;
                    if (l > tt) {
                        float a  = vals[tt], b = vals[l];
                        float lo = fminf(a, b), hi = fmaxf(a, b);
                        if ((tt & k) == 0) { vals[tt] = lo; vals[l] = hi; }
                        else               { vals[tt] = hi; vals[l] = lo; }
                    }
                }
            }
        }
        // k=32 merge, j=16: upper half = 16 largest (lower half dead -> DCE)
        #pragma unroll
        for (int q = 0; q < 16; ++q) {
            float a = vals[q], b = vals[16 + q];
            vals[q] = fminf(a, b); vals[16 + q] = fmaxf(a, b);
        }
        // fully sort upper 16 ascending
        #pragma unroll
        for (int jj = 8; jj > 0; jj >>= 1) {
            #pragma unroll
            for (int tt = 16; tt < 32; ++tt) {
                int l = tt ^ jj;
                if (l > tt) {
                    float a = vals[tt], b = vals[l];
                    vals[tt] = fminf(a, b); vals[l] = fmaxf(a, b);
                }
            }
        }
    }
    __syncthreads();                                              // S2

    // G,s reduce: 72 threads (9 components x 8 clouds)
    if (tid >= T1 - 72) {
        int r    = tid - (T1 - 72);
        int cc   = r / 9;
        int comp = r - cc * 9;
        if (base + cc < B) {
            float s = 0.0f;
            #pragma unroll
            for (int k = 0; k < NP; ++k) s += sb[cc * NP + k][comp];
            Gs[cc][comp] = s;
        }
    }
    __syncthreads();                                              // S3

    if (active) {
        const float4* cp = &ptsF[c * NP];
        const float thr_key = __uint_as_float(__float_as_uint(vals[20]) & ~31u);
        const float thr_d2  = thr_key + oo;                 // rank-20 d2
        const float scale   = sqrtf(thr_d2 + EPS) + EPS;
        const float inv_s   = __builtin_amdgcn_rcpf(scale);

        // cov of ALL 30 rels from cloud G,s:  C = G - s o^T - o s^T + 30 o o^T
        float4 g0 = *(const float4*)&Gs[c][0];   // gxx gxy gxz gyy
        float4 g1 = *(const float4*)&Gs[c][4];   // gyz gzz sx  sy
        float  sx = g1.z, sy = g1.w, sz = Gs[c][8];
        float ax = fmaf(30.f, ox, -sx);
        float ay = fmaf(30.f, oy, -sy);
        float az = fmaf(30.f, oz, -sz);
        float cxx = fmaf(ox, ax, fmaf(-sx, ox, g0.x));
        float cxy = fmaf(oy, ax, fmaf(-sy, ox, g0.y));
        float cxz = fmaf(oz, ax, fmaf(-sz, ox, g0.z));
        float cyy = fmaf(oy, ay, fmaf(-sy, oy, g0.w));
        float cyz = fmaf(oz, ay, fmaf(-sz, oy, g1.x));
        float czz = fmaf(oz, az, fmaf(-sz, oz, g1.y));

        // subtract the 9 excluded outer products; build exclusion bitmask
        unsigned excl = 0u;
        #pragma unroll
        for (int q2 = 21; q2 < 30; ++q2) {
            unsigned bq  = __float_as_uint(vals[q2]);
            int      idx = (int)(bq & 31u);
            float4 p = cp[idx];
            float dx = p.x - ox, dy = p.y - oy, dz = p.z - oz;
            cxx = fmaf(-dx, dx, cxx); cxy = fmaf(-dx, dy, cxy); cxz = fmaf(-dx, dz, cxz);
            cyy = fmaf(-dy, dy, cyy); cyz = fmaf(-dy, dz, cyz); czz = fmaf(-dz, dz, czz);
            excl |= (1u << idx);
        }

        // power iteration x8 == C^8 v0: trace-norm + 3 symmetric squarings
        float tr = cxx + cyy + czz + 1e-30f;
        float rt = __builtin_amdgcn_rcpf(tr);
        float xx = cxx*rt, xy = cxy*rt, xz = cxz*rt;
        float yy = cyy*rt, yz = cyz*rt, zz = czz*rt;
        #pragma unroll
        for (int it = 0; it < 3; ++it) {
            float nxx = fmaf(xx, xx, fmaf(xy, xy, xz * xz));
            float nxy = fmaf(xy, xx + yy, xz * yz);
            float nxz = fmaf(xz, xx + zz, xy * yz);
            float nyy = fmaf(xy, xy, fmaf(yy, yy, yz * yz));
            float nyz = fmaf(yz, yy + zz, xy * xz);
            float nzz = fmaf(xz, xz, fmaf(yz, yz, zz * zz));
            xx = nxx; xy = nxy; xz = nxz; yy = nyy; yz = nyz; zz = nzz;
        }
        float vx = xx + xy + xz;
        float vy = xy + yy + yz;
        float vz = xz + yz + zz;
        float nn = fmaf(vz, vz, fmaf(vy, vy, vx * vx)) + 1e-30f;
        float rr2 = __builtin_amdgcn_rsqf(nn) * inv_s * 2.0f;
        const float wax = vx * rr2, way = vy * rr2, waz = vz * rr2;
        const float c0  = 2.0f - fmaf(oz, waz, fmaf(oy, way, ox * wax));

        // pass B: u = c0 + p.wa (dot form); excluded forced to u=2
        float a0 = 0.f, a1 = 0.f, a3 = 0.f, s1 = 0.f;
        #pragma unroll 5
        for (int j = 0; j < NP; ++j) {
            float4 q = cp[j];
            float ur = fmaf(q.z, waz, fmaf(q.y, way, fmaf(q.x, wax, c0)));
            float u  = ((excl >> j) & 1u) ? 2.0f : ur;
            a0 += satf(1.0f - u);                // u >= -eps: no abs needed
            a1 += satf(1.0f - fabsf(u - 1.0f));
            a3 += satf(1.0f - fabsf(u - 3.0f));
            s1 += u;
        }
        const float P  = 30.0f - a0 - a1 - a3;
        const float Q  = s1 - a1 - 3.0f * a3;
        const float a4 = fmaf(0.5f, Q, -P);
        const float a2 = P - a4 - 10.0f;   // self + 9 excluded sit at u=2

        // sigmoid via exp2 (constants folded into wS/bS at stage time)
        #pragma unroll
        for (int f = 0; f < FN; ++f) {
            float acc = fmaf(a0, wS[0*FN+f],
                        fmaf(a1, wS[1*FN+f],
                        fmaf(a2, wS[2*FN+f],
                        fmaf(a3, wS[3*FN+f],
                             a4 * wS[4*FN+f]))));
            float z2 = acc + bS[f];                 // -y*log2e
            sb[tid][f] = __builtin_amdgcn_rcpf(1.0f + exp2f(z2));
        }
    }
    __syncthreads();                                              // S4

    // ys reduce (tid<80)
    if (tid < CPB * FN) {
        int c2 = tid / FN;
        float s = 0.0f;
        #pragma unroll
        for (int jj = 0; jj < NP; ++jj) s += sb[c2 * NP + jj][tid - c2 * FN];
        ysS[tid] = (base + c2 < B) ? s * (1.0f / (float)NP) : 0.0f;
    }
    // zero A-tile rows 8..15
    {
        short8v z = {0, 0, 0, 0, 0, 0, 0, 0};
        *(short8v*)&hA[(8 + (tid >> 5)) * 256 + (tid & 31) * 8] = z;
    }
    __syncthreads();                                              // S5

    // layer 1: readlane-broadcast ys (2 LDS reads/thread)
    {
        float ya = ysS[lane];
        float yb = ysS[64 + (lane & 15)];
        float wv[FN];
        #pragma unroll
        for (int f = 0; f < FN; ++f) wv[f] = w1[f * 256 + tid];
        float bb = b1[tid];
        #pragma unroll
        for (int cc = 0; cc < CPB; ++cc) {
            float acc = bb;
            #pragma unroll
            for (int f = 0; f < FN; ++f) {
                const int flat = cc * FN + f;
                float yv = (flat < 64) ? rlanef(ya, flat) : rlanef(yb, flat - 64);
                acc = fmaf(yv, wv[f], acc);
            }
            float h = acc > 0.0f ? acc : __expf(acc) - 1.0f;
            hA[hA_idx(cc, tid)] = bf16r(h);
        }
    }
    __syncthreads();                                              // S6

    // layer 2: waves 0..2 each own one 16-col N-tile; B-frags global->regs
    if (w < 3) {
        const int  n   = w * 16 + (lane & 15);
        const bool nok = n < 40;
        const int  kg  = (lane >> 4) * 8;
        float4v acc = {0.f, 0.f, 0.f, 0.f};
        #pragma unroll
        for (int s = 0; s < 8; ++s) {
            short8v bfr;
            #pragma unroll
            for (int j = 0; j < 8; ++j) {
                float f = nok ? w2[(s * 32 + kg + j) * 40 + n] : 0.0f;
                bfr[j] = (short)bf16r(f);
            }
            short8v a = *(const short8v*)&hA[hA_idx(lane & 15, kg + s * 32)];
            acc = __builtin_amdgcn_mfma_f32_16x16x32_bf16(a, bfr, acc, 0, 0, 0);
        }
        if (nok) {
            const float bc = b2[n];
            const int   r0 = (lane >> 4) * 4;
            #pragma unroll
            for (int r = 0; r < 4; ++r) {
                int rr = r0 + r;
                if (rr < CPB) Lg[rr][n] = acc[r] + bc;
            }
        }
    }
    __syncthreads();                                              // S7

    // log_softmax: 16-lane group per cloud
    if (tid < CPB * 16) {
        int cl = tid >> 4, l = tid & 15;
        float v0 = Lg[cl][l];
        float v1 = Lg[cl][l + 16];
        float v2 = (l < 8) ? Lg[cl][l + 32] : -INFINITY;
        float m = fmaxf(fmaxf(v0, v1), v2);
        #pragma unroll
        for (int msk = 1; msk < 16; msk <<= 1) m = fmaxf(m, __shfl_xor(m, msk));
        float e = __expf(v0 - m) + __expf(v1 - m) + ((l < 8) ? __expf(v2 - m) : 0.0f);
        #pragma unroll
        for (int msk = 1; msk < 16; msk <<= 1) e += __shfl_xor(e, msk);
        float ls = m + __logf(e);
        int cloud = base + cl;
        if (cloud < B) {
            float* op = out + (size_t)cloud * 40;
            op[l]      = v0 - ls;
            op[16 + l] = v1 - ls;
            if (l < 8) op[32 + l] = v2 - ls;
        }
    }
}

extern "C" void kernel_launch(void* const* d_in, const int* in_sizes, int n_in,
                              void* d_out, int out_size, void* d_ws, size_t ws_size,
                              hipStream_t stream) {
    const float* pos   = (const float*)d_in[0];
    const float* W     = (const float*)d_in[1];
    const float* b_dsc = (const float*)d_in[2];
    const float* w1    = (const float*)d_in[3];
    const float* b1    = (const float*)d_in[4];
    const float* w2    = (const float*)d_in[5];
    const float* b2    = (const float*)d_in[6];

    const int N = in_sizes[0] / 3;   // B*NP points
    const int B = N / NP;            // clouds

    const int grid = (B + CPB - 1) / CPB;
    fused_kernel<<<grid, T1, 0, stream>>>(pos, W, b_dsc, w1, b1, w2, b2,
                                          (float*)d_out, B);
}

// Round 13
// 31.557 us; speedup vs baseline: 3.0222x; 1.0286x over previous
//
#include <hip/hip_runtime.h>
#include <math.h>

#define NP 30      // points per cloud
#define KNN 20     // neighbors
#define KS 5       // spline control points
#define FN 10      // filter count
#define EPS 1e-8f
#define CPB 16     // clouds per block (R13: fills the 16-row MFMA A-tile)
#define T1 512     // block size (8 waves)

typedef __attribute__((ext_vector_type(8))) short short8v;
typedef __attribute__((ext_vector_type(4))) float float4v;

__device__ __forceinline__ float satf(float x) {
    return fminf(fmaxf(x, 0.0f), 1.0f);   // folds to clamp modifier
}
__device__ __forceinline__ unsigned short bf16r(float f) {   // f32 -> bf16 RNE
    unsigned u = __float_as_uint(f);
    u += 0x7fffu + ((u >> 16) & 1u);
    return (unsigned short)(u >> 16);
}
__device__ __forceinline__ float rlanef(float v, int l) {    // wave broadcast
    return __int_as_float(__builtin_amdgcn_readlane(__float_as_int(v), l));
}
// hA swizzle: 16B granule g of row r -> g ^ (r&7); kills stride-512B conflicts
__device__ __forceinline__ int hA_idx(int row, int col) {
    return row * 256 + ((((col >> 3) ^ (row & 7)) << 3) | (col & 7));
}
// pack point index into low 5 mantissa bits (sort stays float-compare)
__device__ __forceinline__ float packdi(float v, int j) {
    return __uint_as_float((__float_as_uint(v) & ~31u) | (unsigned)j);
}

// Fused dsc -> MLP -> log_softmax. One 512-thread block = 16 clouds.
// R13: CPB 8->16. Layer-2's A-tile rows 8-15 were zero padding (half of
// every MFMA wasted) and its 64 w2 loads + 192 cvt ops were repeated per
// 8 clouds. With 16 clouds/block the whole layer-2 section amortizes 2x.
__global__ __launch_bounds__(T1, 4) void fused_kernel(
    const float* __restrict__ pos,     // [B*NP, 3]
    const float* __restrict__ W,       // [KS, FN]
    const float* __restrict__ b_dsc,   // [FN]
    const float* __restrict__ w1,      // [FN, 256]
    const float* __restrict__ b1,      // [256]
    const float* __restrict__ w2,      // [256, 40]
    const float* __restrict__ b2,      // [40]
    float* __restrict__ out,           // [B, 40]
    int B)
{
    __shared__ float4 ptsF[CPB * NP];                 // x,y,z,|p|^2  (7680 B)
    __shared__ float sb[CPB * NP][11];                // outer-staging / sigmoid
    __shared__ __align__(16) float Gs[CPB][12];       // gxx..gzz sx sy sz
    __shared__ float wS[KS * FN];                     // pre-scaled by -log2e/20
    __shared__ float bS[FN];                          // pre-scaled by -log2e
    __shared__ float ysS[CPB * FN];                   // [160]
    __shared__ __align__(16) unsigned short hA[16 * 256];  // bf16 A-tile (all rows live)
    __shared__ float Lg[CPB][48];

    const int tid  = threadIdx.x;
    const int base = blockIdx.x * CPB;
    const int w    = tid >> 6;
    const int lane = tid & 63;

    // stage: one point per thread (xyz + |p|^2)
    if (tid < CPB * NP) {
        int gp = base * NP + tid;
        if (gp < B * NP) {
            const float* pp = pos + (size_t)gp * 3;
            float x = pp[0], y = pp[1], z = pp[2];
            float n2 = fmaf(z, z, fmaf(y, y, x * x));
            ptsF[tid] = make_float4(x, y, z, n2);
        } else {
            ptsF[tid] = make_float4(0.f, 0.f, 0.f, 0.f);
        }
    }
    if (tid < KS * FN) wS[tid] = W[tid] * (-0.07213475204444817f);  // -log2e/20
    if (tid < FN)      bS[tid] = b_dsc[tid] * (-1.4426950408889634f);
    __syncthreads();                                              // S1

    const int c = tid / NP;
    const int i = tid - c * NP;
    const bool active = (tid < CPB * NP) && (base + c < B);

    float vals[32];
    float ox = 0.f, oy = 0.f, oz = 0.f, oo = 0.f;

    if (active) {
        const float4* cp = &ptsF[c * NP];
        float4 own = cp[i];                       // dynamic LDS read, once
        ox = own.x; oy = own.y; oz = own.z; oo = own.w;

        // own outer products + coords -> LDS (cloud-level G,s reduce)
        sb[tid][0] = ox * ox; sb[tid][1] = ox * oy; sb[tid][2] = ox * oz;
        sb[tid][3] = oy * oy; sb[tid][4] = oy * oz; sb[tid][5] = oz * oz;
        sb[tid][6] = ox;      sb[tid][7] = oy;     sb[tid][8] = oz;

        // keys: key_j = n2_j - 2 p_j.o = d2_j - oo (monotone shift; self exact)
        #pragma unroll
        for (int j = 0; j < NP; ++j) {
            float4 q = cp[j];
            float dt = fmaf(q.z, oz, fmaf(q.y, oy, q.x * ox));
            float key = fmaf(-2.0f, dt, q.w);
            vals[j] = packdi(key, j);
            if ((j % 5) == 4) asm volatile("" ::: "memory");  // bound in-flight loads
        }
        vals[30] = packdi(1e11f, 30);
        vals[31] = packdi(1e11f, 31);

        // bitonic stages k=2..16: halves [0..15] asc, [16..31] desc
        #pragma unroll
        for (int k = 2; k <= 16; k <<= 1) {
            #pragma unroll
            for (int jj = k >> 1; jj > 0; jj >>= 1) {
                #pragma unroll
                for (int tt = 0; tt < 32; ++tt) {
                    int l = tt ^ jj;
                    if (l > tt) {
                        float a  = vals[tt], b = vals[l];
                        float lo = fminf(a, b), hi = fmaxf(a, b);
                        if ((tt & k) == 0) { vals[tt] = lo; vals[l] = hi; }
                        else               { vals[tt] = hi; vals[l] = lo; }
                    }
                }
            }
        }
        // k=32 merge, j=16: upper half = 16 largest (lower half dead -> DCE)
        #pragma unroll
        for (int q = 0; q < 16; ++q) {
            float a = vals[q], b = vals[16 + q];
            vals[q] = fminf(a, b); vals[16 + q] = fmaxf(a, b);
        }
        // fully sort upper 16 ascending
        #pragma unroll
        for (int jj = 8; jj > 0; jj >>= 1) {
            #pragma unroll
            for (int tt = 16; tt < 32; ++tt) {
                int l = tt ^ jj;
                if (l > tt) {
                    float a = vals[tt], b = vals[l];
                    vals[tt] = fminf(a, b); vals[l] = fmaxf(a, b);
                }
            }
        }
    }
    __syncthreads();                                              // S2

    // G,s reduce: 144 threads (9 components x 16 clouds)
    if (tid < CPB * 9) {
        int cc   = tid / 9;
        int comp = tid - cc * 9;
        if (base + cc < B) {
            float s = 0.0f;
            #pragma unroll
            for (int k = 0; k < NP; ++k) s += sb[cc * NP + k][comp];
            Gs[cc][comp] = s;
        }
    }
    __syncthreads();                                              // S3

    if (active) {
        const float4* cp = &ptsF[c * NP];
        const float thr_key = __uint_as_float(__float_as_uint(vals[20]) & ~31u);
        const float thr_d2  = thr_key + oo;                 // rank-20 d2
        const float scale   = sqrtf(thr_d2 + EPS) + EPS;
        const float inv_s   = __builtin_amdgcn_rcpf(scale);

        // cov of ALL 30 rels from cloud G,s:  C = G - s o^T - o s^T + 30 o o^T
        float4 g0 = *(const float4*)&Gs[c][0];   // gxx gxy gxz gyy
        float4 g1 = *(const float4*)&Gs[c][4];   // gyz gzz sx  sy
        float  sx = g1.z, sy = g1.w, sz = Gs[c][8];
        float ax = fmaf(30.f, ox, -sx);
        float ay = fmaf(30.f, oy, -sy);
        float az = fmaf(30.f, oz, -sz);
        float cxx = fmaf(ox, ax, fmaf(-sx, ox, g0.x));
        float cxy = fmaf(oy, ax, fmaf(-sy, ox, g0.y));
        float cxz = fmaf(oz, ax, fmaf(-sz, ox, g0.z));
        float cyy = fmaf(oy, ay, fmaf(-sy, oy, g0.w));
        float cyz = fmaf(oz, ay, fmaf(-sz, oy, g1.x));
        float czz = fmaf(oz, az, fmaf(-sz, oz, g1.y));

        // subtract the 9 excluded outer products; build exclusion bitmask
        unsigned excl = 0u;
        #pragma unroll
        for (int q2 = 21; q2 < 30; ++q2) {
            unsigned bq  = __float_as_uint(vals[q2]);
            int      idx = (int)(bq & 31u);
            float4 p = cp[idx];
            float dx = p.x - ox, dy = p.y - oy, dz = p.z - oz;
            cxx = fmaf(-dx, dx, cxx); cxy = fmaf(-dx, dy, cxy); cxz = fmaf(-dx, dz, cxz);
            cyy = fmaf(-dy, dy, cyy); cyz = fmaf(-dy, dz, cyz); czz = fmaf(-dz, dz, czz);
            excl |= (1u << idx);
        }

        // power iteration x8 == C^8 v0: trace-norm + 3 symmetric squarings
        float tr = cxx + cyy + czz + 1e-30f;
        float rt = __builtin_amdgcn_rcpf(tr);
        float xx = cxx*rt, xy = cxy*rt, xz = cxz*rt;
        float yy = cyy*rt, yz = cyz*rt, zz = czz*rt;
        #pragma unroll
        for (int it = 0; it < 3; ++it) {
            float nxx = fmaf(xx, xx, fmaf(xy, xy, xz * xz));
            float nxy = fmaf(xy, xx + yy, xz * yz);
            float nxz = fmaf(xz, xx + zz, xy * yz);
            float nyy = fmaf(xy, xy, fmaf(yy, yy, yz * yz));
            float nyz = fmaf(yz, yy + zz, xy * xz);
            float nzz = fmaf(xz, xz, fmaf(yz, yz, zz * zz));
            xx = nxx; xy = nxy; xz = nxz; yy = nyy; yz = nyz; zz = nzz;
        }
        float vx = xx + xy + xz;
        float vy = xy + yy + yz;
        float vz = xz + yz + zz;
        float nn = fmaf(vz, vz, fmaf(vy, vy, vx * vx)) + 1e-30f;
        float rr2 = __builtin_amdgcn_rsqf(nn) * inv_s * 2.0f;
        const float wax = vx * rr2, way = vy * rr2, waz = vz * rr2;
        const float c0  = 2.0f - fmaf(oz, waz, fmaf(oy, way, ox * wax));

        // pass B: u = c0 + p.wa (dot form); excluded forced to u=2
        float a0 = 0.f, a1 = 0.f, a3 = 0.f, s1 = 0.f;
        #pragma unroll 5
        for (int j = 0; j < NP; ++j) {
            float4 q = cp[j];
            float ur = fmaf(q.z, waz, fmaf(q.y, way, fmaf(q.x, wax, c0)));
            float u  = ((excl >> j) & 1u) ? 2.0f : ur;
            a0 += satf(1.0f - u);                // u >= -eps: no abs needed
            a1 += satf(1.0f - fabsf(u - 1.0f));
            a3 += satf(1.0f - fabsf(u - 3.0f));
            s1 += u;
        }
        const float P  = 30.0f - a0 - a1 - a3;
        const float Q  = s1 - a1 - 3.0f * a3;
        const float a4 = fmaf(0.5f, Q, -P);
        const float a2 = P - a4 - 10.0f;   // self + 9 excluded sit at u=2

        // sigmoid via exp2 (constants folded into wS/bS at stage time)
        #pragma unroll
        for (int f = 0; f < FN; ++f) {
            float acc = fmaf(a0, wS[0*FN+f],
                        fmaf(a1, wS[1*FN+f],
                        fmaf(a2, wS[2*FN+f],
                        fmaf(a3, wS[3*FN+f],
                             a4 * wS[4*FN+f]))));
            float z2 = acc + bS[f];                 // -y*log2e
            sb[tid][f] = __builtin_amdgcn_rcpf(1.0f + exp2f(z2));
        }
    }
    __syncthreads();                                              // S4

    // ys reduce (tid<160)
    if (tid < CPB * FN) {
        int c2 = tid / FN;
        float s = 0.0f;
        #pragma unroll
        for (int jj = 0; jj < NP; ++jj) s += sb[c2 * NP + jj][tid - c2 * FN];
        ysS[tid] = (base + c2 < B) ? s * (1.0f / (float)NP) : 0.0f;
    }
    __syncthreads();                                              // S5

    // layer 1: half 0 (waves 0-3) = clouds 0..7, half 1 (waves 4-7) = clouds 8..15.
    // Each thread: hidden unit (tid&255) for its half's 8 clouds. readlane ys.
    {
        const int  hu    = tid & 255;
        const int  ybase = (w >= 4) ? 80 : 0;     // wave-uniform
        const int  rbase = (w >= 4) ? 8 : 0;
        float ya = ysS[ybase + lane];
        float yb = ysS[ybase + 64 + (lane & 15)];
        float wv[FN];
        #pragma unroll
        for (int f = 0; f < FN; ++f) wv[f] = w1[f * 256 + hu];
        float bb = b1[hu];
        #pragma unroll
        for (int cc = 0; cc < 8; ++cc) {
            float acc = bb;
            #pragma unroll
            for (int f = 0; f < FN; ++f) {
                const int flat = cc * FN + f;
                float yv = (flat < 64) ? rlanef(ya, flat) : rlanef(yb, flat - 64);
                acc = fmaf(yv, wv[f], acc);
            }
            float h = acc > 0.0f ? acc : __expf(acc) - 1.0f;
            hA[hA_idx(rbase + cc, hu)] = bf16r(h);
        }
    }
    __syncthreads();                                              // S6

    // layer 2: waves 0..2 each own one 16-col N-tile; B-frags global->regs.
    // A-tile is now 16 fully-live rows = 16 clouds per MFMA set.
    if (w < 3) {
        const int  n   = w * 16 + (lane & 15);
        const bool nok = n < 40;
        const int  kg  = (lane >> 4) * 8;
        float4v acc = {0.f, 0.f, 0.f, 0.f};
        #pragma unroll
        for (int s = 0; s < 8; ++s) {
            short8v bfr;
            #pragma unroll
            for (int j = 0; j < 8; ++j) {
                float f = nok ? w2[(s * 32 + kg + j) * 40 + n] : 0.0f;
                bfr[j] = (short)bf16r(f);
            }
            short8v a = *(const short8v*)&hA[hA_idx(lane & 15, kg + s * 32)];
            acc = __builtin_amdgcn_mfma_f32_16x16x32_bf16(a, bfr, acc, 0, 0, 0);
        }
        // C/D: col=lane&15 (our n), row=(lane>>4)*4+r  [m89-verified]
        if (nok) {
            const float bc = b2[n];
            const int   r0 = (lane >> 4) * 4;
            #pragma unroll
            for (int r = 0; r < 4; ++r) {
                Lg[r0 + r][n] = acc[r] + bc;
            }
        }
    }
    __syncthreads();                                              // S7

    // log_softmax: 16-lane group per cloud (tid<256)
    if (tid < CPB * 16) {
        int cl = tid >> 4, l = tid & 15;
        float v0 = Lg[cl][l];
        float v1 = Lg[cl][l + 16];
        float v2 = (l < 8) ? Lg[cl][l + 32] : -INFINITY;
        float m = fmaxf(fmaxf(v0, v1), v2);
        #pragma unroll
        for (int msk = 1; msk < 16; msk <<= 1) m = fmaxf(m, __shfl_xor(m, msk));
        float e = __expf(v0 - m) + __expf(v1 - m) + ((l < 8) ? __expf(v2 - m) : 0.0f);
        #pragma unroll
        for (int msk = 1; msk < 16; msk <<= 1) e += __shfl_xor(e, msk);
        float ls = m + __logf(e);
        int cloud = base + cl;
        if (cloud < B) {
            float* op = out + (size_t)cloud * 40;
            op[l]      = v0 - ls;
            op[16 + l] = v1 - ls;
            if (l < 8) op[32 + l] = v2 - ls;
        }
    }
}

extern "C" void kernel_launch(void* const* d_in, const int* in_sizes, int n_in,
                              void* d_out, int out_size, void* d_ws, size_t ws_size,
                              hipStream_t stream) {
    const float* pos   = (const float*)d_in[0];
    const float* W     = (const float*)d_in[1];
    const float* b_dsc = (const float*)d_in[2];
    const float* w1    = (const float*)d_in[3];
    const float* b1    = (const float*)d_in[4];
    const float* w2    = (const float*)d_in[5];
    const float* b2    = (const float*)d_in[6];

    const int N = in_sizes[0] / 3;   // B*NP points
    const int B = N / NP;            // clouds

    const int grid = (B + CPB - 1) / CPB;
    fused_kernel<<<grid, T1, 0, stream>>>(pos, W, b_dsc, w1, b1, w2, b2,
                                          (float*)d_out, B);
}

// Round 14
// 30.850 us; speedup vs baseline: 3.0914x; 1.0229x over previous
//
#include <hip/hip_runtime.h>
#include <math.h>

#define NP 30      // points per cloud
#define KNN 20     // neighbors
#define KS 5       // spline control points
#define FN 10      // filter count
#define EPS 1e-8f
#define CPB 16     // clouds per block (fills the 16-row MFMA A-tile)
#define T1 512     // block size (8 waves)

typedef __attribute__((ext_vector_type(8))) short short8v;
typedef __attribute__((ext_vector_type(4))) float float4v;

__device__ __forceinline__ float satf(float x) {
    return fminf(fmaxf(x, 0.0f), 1.0f);   // folds to clamp modifier
}
__device__ __forceinline__ unsigned short bf16r(float f) {   // f32 -> bf16 RNE
    unsigned u = __float_as_uint(f);
    u += 0x7fffu + ((u >> 16) & 1u);
    return (unsigned short)(u >> 16);
}
__device__ __forceinline__ float rlanef(float v, int l) {    // wave broadcast
    return __int_as_float(__builtin_amdgcn_readlane(__float_as_int(v), l));
}
// hA swizzle: 16B granule g of row r -> g ^ (r&7); kills stride-512B conflicts
__device__ __forceinline__ int hA_idx(int row, int col) {
    return row * 256 + ((((col >> 3) ^ (row & 7)) << 3) | (col & 7));
}
// pack point index into low 5 mantissa bits (sort stays float-compare)
__device__ __forceinline__ float packdi(float v, int j) {
    return __uint_as_float((__float_as_uint(v) & ~31u) | (unsigned)j);
}

// compare-exchange helpers (ascending / descending)
#define CEA(A, B) { float a_ = vals[A], b_ = vals[B]; vals[A] = fminf(a_, b_); vals[B] = fmaxf(a_, b_); }
#define CED(A, B) { float a_ = vals[A], b_ = vals[B]; vals[A] = fmaxf(a_, b_); vals[B] = fminf(a_, b_); }

// Fused dsc -> MLP -> log_softmax. One 512-thread block = 16 clouds.
// R14: Batcher odd-even mergesort halves (63 CE vs bitonic 80) + merge pruned
// to outputs 20..29; W/b_dsc moved from LDS broadcasts to uniform scalar loads.
__global__ __launch_bounds__(T1, 4) void fused_kernel(
    const float* __restrict__ pos,     // [B*NP, 3]
    const float* __restrict__ W,       // [KS, FN]
    const float* __restrict__ b_dsc,   // [FN]
    const float* __restrict__ w1,      // [FN, 256]
    const float* __restrict__ b1,      // [256]
    const float* __restrict__ w2,      // [256, 40]
    const float* __restrict__ b2,      // [40]
    float* __restrict__ out,           // [B, 40]
    int B)
{
    __shared__ float4 ptsF[CPB * NP];                 // x,y,z,|p|^2
    __shared__ float sb[CPB * NP][11];                // outer-staging / sigmoid
    __shared__ __align__(16) float Gs[CPB][12];       // gxx..gzz sx sy sz
    __shared__ float ysS[CPB * FN];                   // [160]
    __shared__ __align__(16) unsigned short hA[16 * 256];  // bf16 A-tile
    __shared__ float Lg[CPB][48];

    const int tid  = threadIdx.x;
    const int base = blockIdx.x * CPB;
    const int w    = tid >> 6;
    const int lane = tid & 63;

    // stage: one point per thread (xyz + |p|^2)
    if (tid < CPB * NP) {
        int gp = base * NP + tid;
        if (gp < B * NP) {
            const float* pp = pos + (size_t)gp * 3;
            float x = pp[0], y = pp[1], z = pp[2];
            float n2 = fmaf(z, z, fmaf(y, y, x * x));
            ptsF[tid] = make_float4(x, y, z, n2);
        } else {
            ptsF[tid] = make_float4(0.f, 0.f, 0.f, 0.f);
        }
    }
    __syncthreads();                                              // S1

    const int c = tid / NP;
    const int i = tid - c * NP;
    const bool active = (tid < CPB * NP) && (base + c < B);

    float vals[32];
    float ox = 0.f, oy = 0.f, oz = 0.f, oo = 0.f;

    if (active) {
        const float4* cp = &ptsF[c * NP];
        float4 own = cp[i];                       // dynamic LDS read, once
        ox = own.x; oy = own.y; oz = own.z; oo = own.w;

        // own outer products + coords -> LDS (cloud-level G,s reduce)
        sb[tid][0] = ox * ox; sb[tid][1] = ox * oy; sb[tid][2] = ox * oz;
        sb[tid][3] = oy * oy; sb[tid][4] = oy * oz; sb[tid][5] = oz * oz;
        sb[tid][6] = ox;      sb[tid][7] = oy;     sb[tid][8] = oz;

        // keys: key_j = n2_j - 2 p_j.o = d2_j - oo (monotone shift; self exact)
        #pragma unroll
        for (int j = 0; j < NP; ++j) {
            float4 q = cp[j];
            float dt = fmaf(q.z, oz, fmaf(q.y, oy, q.x * ox));
            float key = fmaf(-2.0f, dt, q.w);
            vals[j] = packdi(key, j);
            if ((j % 5) == 4) asm volatile("" ::: "memory");  // bound in-flight loads
        }
        vals[30] = packdi(1e11f, 30);
        vals[31] = packdi(1e11f, 31);

        // --- Batcher odd-even mergesort: lower 16 asc, upper 16 desc ---
        // (all keys distinct via packed index bits -> result identical to any
        //  correct sort; 63 CEs per half vs bitonic's 80)
        #pragma unroll
        for (int p = 1; p < 16; p <<= 1) {
            #pragma unroll
            for (int k = p; k >= 1; k >>= 1) {
                #pragma unroll
                for (int j = (k & (p - 1)); j + k < 16; j += 2 * k) {
                    #pragma unroll
                    for (int ii = 0; ii < k; ++ii) {
                        if (ii + j + k < 16 &&
                            ((ii + j) / (2 * p)) == ((ii + j + k) / (2 * p))) {
                            CEA(ii + j, ii + j + k);
                            CED(16 + ii + j, 16 + ii + j + k);
                        }
                    }
                }
            }
        }
        // --- bitonic k=32 first stage: upper half = 16 largest (bitonic) ---
        #pragma unroll
        for (int q = 0; q < 16; ++q) vals[16 + q] = fmaxf(vals[q], vals[16 + q]);
        // --- bitonic merge of upper 16, pruned to outputs 20..29 ---
        // j=8 (all)
        #pragma unroll
        for (int q = 0; q < 8; ++q) { CEA(16 + q, 24 + q); }
        // j=4 (all)
        CEA(16, 20) CEA(17, 21) CEA(18, 22) CEA(19, 23)
        CEA(24, 28) CEA(25, 29) CEA(26, 30) CEA(27, 31)
        // j=2 (cone of 20..29)
        CEA(20, 22) CEA(21, 23) CEA(24, 26) CEA(25, 27) CEA(28, 30) CEA(29, 31)
        // j=1 (cone of 20..29)
        CEA(20, 21) CEA(22, 23) CEA(24, 25) CEA(26, 27) CEA(28, 29)
    }
    __syncthreads();                                              // S2

    // G,s reduce: 144 threads (9 components x 16 clouds)
    if (tid < CPB * 9) {
        int cc   = tid / 9;
        int comp = tid - cc * 9;
        if (base + cc < B) {
            float s = 0.0f;
            #pragma unroll
            for (int k = 0; k < NP; ++k) s += sb[cc * NP + k][comp];
            Gs[cc][comp] = s;
        }
    }
    __syncthreads();                                              // S3

    if (active) {
        const float4* cp = &ptsF[c * NP];
        const float thr_key = __uint_as_float(__float_as_uint(vals[20]) & ~31u);
        const float thr_d2  = thr_key + oo;                 // rank-20 d2
        const float scale   = sqrtf(thr_d2 + EPS) + EPS;
        const float inv_s   = __builtin_amdgcn_rcpf(scale);

        // cov of ALL 30 rels from cloud G,s:  C = G - s o^T - o s^T + 30 o o^T
        float4 g0 = *(const float4*)&Gs[c][0];   // gxx gxy gxz gyy
        float4 g1 = *(const float4*)&Gs[c][4];   // gyz gzz sx  sy
        float  sx = g1.z, sy = g1.w, sz = Gs[c][8];
        float ax = fmaf(30.f, ox, -sx);
        float ay = fmaf(30.f, oy, -sy);
        float az = fmaf(30.f, oz, -sz);
        float cxx = fmaf(ox, ax, fmaf(-sx, ox, g0.x));
        float cxy = fmaf(oy, ax, fmaf(-sy, ox, g0.y));
        float cxz = fmaf(oz, ax, fmaf(-sz, ox, g0.z));
        float cyy = fmaf(oy, ay, fmaf(-sy, oy, g0.w));
        float cyz = fmaf(oz, ay, fmaf(-sz, oy, g1.x));
        float czz = fmaf(oz, az, fmaf(-sz, oz, g1.y));

        // subtract the 9 excluded outer products; build exclusion bitmask
        unsigned excl = 0u;
        #pragma unroll
        for (int q2 = 21; q2 < 30; ++q2) {
            unsigned bq  = __float_as_uint(vals[q2]);
            int      idx = (int)(bq & 31u);
            float4 p = cp[idx];
            float dx = p.x - ox, dy = p.y - oy, dz = p.z - oz;
            cxx = fmaf(-dx, dx, cxx); cxy = fmaf(-dx, dy, cxy); cxz = fmaf(-dx, dz, cxz);
            cyy = fmaf(-dy, dy, cyy); cyz = fmaf(-dy, dz, cyz); czz = fmaf(-dz, dz, czz);
            excl |= (1u << idx);
        }

        // power iteration x8 == C^8 v0: trace-norm + 3 symmetric squarings
        float tr = cxx + cyy + czz + 1e-30f;
        float rt = __builtin_amdgcn_rcpf(tr);
        float xx = cxx*rt, xy = cxy*rt, xz = cxz*rt;
        float yy = cyy*rt, yz = cyz*rt, zz = czz*rt;
        #pragma unroll
        for (int it = 0; it < 3; ++it) {
            float nxx = fmaf(xx, xx, fmaf(xy, xy, xz * xz));
            float nxy = fmaf(xy, xx + yy, xz * yz);
            float nxz = fmaf(xz, xx + zz, xy * yz);
            float nyy = fmaf(xy, xy, fmaf(yy, yy, yz * yz));
            float nyz = fmaf(yz, yy + zz, xy * xz);
            float nzz = fmaf(xz, xz, fmaf(yz, yz, zz * zz));
            xx = nxx; xy = nxy; xz = nxz; yy = nyy; yz = nyz; zz = nzz;
        }
        float vx = xx + xy + xz;
        float vy = xy + yy + yz;
        float vz = xz + yz + zz;
        float nn = fmaf(vz, vz, fmaf(vy, vy, vx * vx)) + 1e-30f;
        float rr2 = __builtin_amdgcn_rsqf(nn) * inv_s * 2.0f;
        const float wax = vx * rr2, way = vy * rr2, waz = vz * rr2;
        const float c0  = 2.0f - fmaf(oz, waz, fmaf(oy, way, ox * wax));

        // pass B: u = c0 + p.wa (dot form); excluded forced to u=2
        float a0 = 0.f, a1 = 0.f, a3 = 0.f, s1 = 0.f;
        #pragma unroll 5
        for (int j = 0; j < NP; ++j) {
            float4 q = cp[j];
            float ur = fmaf(q.z, waz, fmaf(q.y, way, fmaf(q.x, wax, c0)));
            float u  = ((excl >> j) & 1u) ? 2.0f : ur;
            a0 += satf(1.0f - u);                // u >= -eps: no abs needed
            a1 += satf(1.0f - fabsf(u - 1.0f));
            a3 += satf(1.0f - fabsf(u - 3.0f));
            s1 += u;
        }
        const float P  = 30.0f - a0 - a1 - a3;
        const float Q  = s1 - a1 - 3.0f * a3;
        const float a4 = fmaf(0.5f, Q, -P);
        const float a2 = P - a4 - 10.0f;   // self + 9 excluded sit at u=2

        // sigmoid via exp2; W/b_dsc read with UNIFORM indices -> scalar loads
        // (SGPR operands, zero LDS traffic). y = acc/20 + b ; z2 = -y*log2e.
        #pragma unroll
        for (int f = 0; f < FN; ++f) {
            float acc = fmaf(a0, W[0*FN+f],
                        fmaf(a1, W[1*FN+f],
                        fmaf(a2, W[2*FN+f],
                        fmaf(a3, W[3*FN+f],
                             a4 * W[4*FN+f]))));
            float bn = b_dsc[f] * (-1.4426950408889634f);        // -log2e * b
            float z2 = fmaf(acc, -0.07213475204444817f, bn);     // -log2e/20
            sb[tid][f] = __builtin_amdgcn_rcpf(1.0f + exp2f(z2));
        }
    }
    __syncthreads();                                              // S4

    // ys reduce (tid<160)
    if (tid < CPB * FN) {
        int c2 = tid / FN;
        float s = 0.0f;
        #pragma unroll
        for (int jj = 0; jj < NP; ++jj) s += sb[c2 * NP + jj][tid - c2 * FN];
        ysS[tid] = (base + c2 < B) ? s * (1.0f / (float)NP) : 0.0f;
    }
    __syncthreads();                                              // S5

    // layer 1: half 0 (waves 0-3) = clouds 0..7, half 1 (waves 4-7) = 8..15.
    {
        const int  hu    = tid & 255;
        const int  ybase = (w >= 4) ? 80 : 0;     // wave-uniform
        const int  rbase = (w >= 4) ? 8 : 0;
        float ya = ysS[ybase + lane];
        float yb = ysS[ybase + 64 + (lane & 15)];
        float wv[FN];
        #pragma unroll
        for (int f = 0; f < FN; ++f) wv[f] = w1[f * 256 + hu];
        float bb = b1[hu];
        #pragma unroll
        for (int cc = 0; cc < 8; ++cc) {
            float acc = bb;
            #pragma unroll
            for (int f = 0; f < FN; ++f) {
                const int flat = cc * FN + f;
                float yv = (flat < 64) ? rlanef(ya, flat) : rlanef(yb, flat - 64);
                acc = fmaf(yv, wv[f], acc);
            }
            float h = acc > 0.0f ? acc : __expf(acc) - 1.0f;
            hA[hA_idx(rbase + cc, hu)] = bf16r(h);
        }
    }
    __syncthreads();                                              // S6

    // layer 2: waves 0..2 each own one 16-col N-tile; B-frags global->regs.
    if (w < 3) {
        const int  n   = w * 16 + (lane & 15);
        const bool nok = n < 40;
        const int  kg  = (lane >> 4) * 8;
        float4v acc = {0.f, 0.f, 0.f, 0.f};
        #pragma unroll
        for (int s = 0; s < 8; ++s) {
            short8v bfr;
            #pragma unroll
            for (int j = 0; j < 8; ++j) {
                float f = nok ? w2[(s * 32 + kg + j) * 40 + n] : 0.0f;
                bfr[j] = (short)bf16r(f);
            }
            short8v a = *(const short8v*)&hA[hA_idx(lane & 15, kg + s * 32)];
            acc = __builtin_amdgcn_mfma_f32_16x16x32_bf16(a, bfr, acc, 0, 0, 0);
        }
        // C/D: col=lane&15 (our n), row=(lane>>4)*4+r  [m89-verified]
        if (nok) {
            const float bc = b2[n];
            const int   r0 = (lane >> 4) * 4;
            #pragma unroll
            for (int r = 0; r < 4; ++r) {
                Lg[r0 + r][n] = acc[r] + bc;
            }
        }
    }
    __syncthreads();                                              // S7

    // log_softmax: 16-lane group per cloud (tid<256)
    if (tid < CPB * 16) {
        int cl = tid >> 4, l = tid & 15;
        float v0 = Lg[cl][l];
        float v1 = Lg[cl][l + 16];
        float v2 = (l < 8) ? Lg[cl][l + 32] : -INFINITY;
        float m = fmaxf(fmaxf(v0, v1), v2);
        #pragma unroll
        for (int msk = 1; msk < 16; msk <<= 1) m = fmaxf(m, __shfl_xor(m, msk));
        float e = __expf(v0 - m) + __expf(v1 - m) + ((l < 8) ? __expf(v2 - m) : 0.0f);
        #pragma unroll
        for (int msk = 1; msk < 16; msk <<= 1) e += __shfl_xor(e, msk);
        float ls = m + __logf(e);
        int cloud = base + cl;
        if (cloud < B) {
            float* op = out + (size_t)cloud * 40;
            op[l]      = v0 - ls;
            op[16 + l] = v1 - ls;
            if (l < 8) op[32 + l] = v2 - ls;
        }
    }
}

extern "C" void kernel_launch(void* const* d_in, const int* in_sizes, int n_in,
                              void* d_out, int out_size, void* d_ws, size_t ws_size,
                              hipStream_t stream) {
    const float* pos   = (const float*)d_in[0];
    const float* W     = (const float*)d_in[1];
    const float* b_dsc = (const float*)d_in[2];
    const float* w1    = (const float*)d_in[3];
    const float* b1    = (const float*)d_in[4];
    const float* w2    = (const float*)d_in[5];
    const float* b2    = (const float*)d_in[6];

    const int N = in_sizes[0] / 3;   // B*NP points
    const int B = N / NP;            // clouds

    const int grid = (B + CPB - 1) / CPB;
    fused_kernel<<<grid, T1, 0, stream>>>(pos, W, b_dsc, w1, b1, w2, b2,
                                          (float*)d_out, B);
}

// Round 16
// 29.976 us; speedup vs baseline: 3.1815x; 1.0291x over previous
//
#include <hip/hip_runtime.h>
#include <math.h>

#define NP 30      // points per cloud
#define KNN 20     // neighbors
#define KS 5       // spline control points
#define FN 10      // filter count
#define EPS 1e-8f
#define CPB 16     // clouds per block (fills the 16-row MFMA A-tile)
#define T1 512     // block size (8 waves)

typedef __attribute__((ext_vector_type(8))) short short8v;
typedef __attribute__((ext_vector_type(4))) float float4v;

__device__ __forceinline__ float satf(float x) {
    return fminf(fmaxf(x, 0.0f), 1.0f);   // folds to clamp modifier
}
__device__ __forceinline__ unsigned short bf16r(float f) {   // f32 -> bf16 RNE
    unsigned u = __float_as_uint(f);
    u += 0x7fffu + ((u >> 16) & 1u);
    return (unsigned short)(u >> 16);
}
__device__ __forceinline__ float rlanef(float v, int l) {    // wave broadcast
    return __int_as_float(__builtin_amdgcn_readlane(__float_as_int(v), l));
}
// hA swizzle: 16B granule g of row r -> g ^ (r&7); kills stride-512B conflicts
__device__ __forceinline__ int hA_idx(int row, int col) {
    return row * 256 + ((((col >> 3) ^ (row & 7)) << 3) | (col & 7));
}
// pack point index into low 5 mantissa bits (sort stays float-compare)
__device__ __forceinline__ float packdi(float v, int j) {
    return __uint_as_float((__float_as_uint(v) & ~31u) | (unsigned)j);
}

// compare-exchange helpers (ascending / descending)
#define CEA(A, B) { float a_ = vals[A], b_ = vals[B]; vals[A] = fminf(a_, b_); vals[B] = fmaxf(a_, b_); }
#define CED(A, B) { float a_ = vals[A], b_ = vals[B]; vals[A] = fmaxf(a_, b_); vals[B] = fminf(a_, b_); }

// Fused dsc -> MLP -> log_softmax. One 512-thread block = 16 clouds.
// R16 = R15 + the k=32 merge MIN side restored (R15 bug: vals[0..15] was the
// positional lower half, not the global 16-nearest; bitonic-split property
// needs the elementwise fminf to make the lower half the 16-smallest SET).
__global__ __launch_bounds__(T1, 4) void fused_kernel(
    const float* __restrict__ pos,     // [B*NP, 3]
    const float* __restrict__ W,       // [KS, FN]
    const float* __restrict__ b_dsc,   // [FN]
    const float* __restrict__ w1,      // [FN, 256]
    const float* __restrict__ b1,      // [256]
    const float* __restrict__ w2,      // [256, 40]
    const float* __restrict__ b2,      // [40]
    float* __restrict__ out,           // [B, 40]
    int B)
{
    __shared__ float4 ptsF[CPB * NP];                       // x,y,z,|p|^2
    __shared__ __align__(16) float sb[CPB * NP][12];        // outer-staging / sigmoid
    __shared__ __align__(16) float Gs[CPB][12];             // gxx..gzz sx sy sz
    __shared__ float ysS[CPB * FN];                         // [160]
    __shared__ __align__(16) unsigned short hA[16 * 256];   // bf16 A-tile
    __shared__ float Lg[CPB][48];

    const int tid  = threadIdx.x;
    const int base = blockIdx.x * CPB;
    const int w    = tid >> 6;
    const int lane = tid & 63;

    // stage: one point per thread (xyz + |p|^2)
    if (tid < CPB * NP) {
        int gp = base * NP + tid;
        if (gp < B * NP) {
            const float* pp = pos + (size_t)gp * 3;
            float x = pp[0], y = pp[1], z = pp[2];
            float n2 = fmaf(z, z, fmaf(y, y, x * x));
            ptsF[tid] = make_float4(x, y, z, n2);
        } else {
            ptsF[tid] = make_float4(0.f, 0.f, 0.f, 0.f);
        }
    }
    __syncthreads();                                              // S1

    const int c = tid / NP;
    const int i = tid - c * NP;
    const bool active = (tid < CPB * NP) && (base + c < B);

    float vals[32];
    float ox = 0.f, oy = 0.f, oz = 0.f, oo = 0.f;

    if (active) {
        const float4* cp = &ptsF[c * NP];
        float4 own = cp[i];                       // dynamic LDS read, once
        ox = own.x; oy = own.y; oz = own.z; oo = own.w;

        // own outer products + coords -> LDS (vectorized: 2x b128 + 1x b32)
        *(float4*)&sb[tid][0] = make_float4(ox * ox, ox * oy, ox * oz, oy * oy);
        *(float4*)&sb[tid][4] = make_float4(oy * oz, oz * oz, ox, oy);
        sb[tid][8] = oz;

        // keys: key_j = n2_j - 2 p_j.o  (3-fma form; monotone shift of d2)
        const float nx2 = -2.0f * ox, ny2 = -2.0f * oy, nz2 = -2.0f * oz;
        #pragma unroll
        for (int j = 0; j < NP; ++j) {
            float4 q = cp[j];
            float key = fmaf(q.z, nz2, fmaf(q.y, ny2, fmaf(q.x, nx2, q.w)));
            vals[j] = packdi(key, j);
            if ((j % 5) == 4) asm volatile("" ::: "memory");  // bound in-flight loads
        }
        vals[30] = packdi(1e11f, 30);
        vals[31] = packdi(1e11f, 31);

        // --- Batcher odd-even mergesort: lower 16 asc, upper 16 desc ---
        #pragma unroll
        for (int p = 1; p < 16; p <<= 1) {
            #pragma unroll
            for (int k = p; k >= 1; k >>= 1) {
                #pragma unroll
                for (int j = (k & (p - 1)); j + k < 16; j += 2 * k) {
                    #pragma unroll
                    for (int ii = 0; ii < k; ++ii) {
                        if (ii + j + k < 16 &&
                            ((ii + j) / (2 * p)) == ((ii + j + k) / (2 * p))) {
                            CEA(ii + j, ii + j + k);
                            CED(16 + ii + j, 16 + ii + j + k);
                        }
                    }
                }
            }
        }
        // --- bitonic k=32 split: BOTH sides. Lower = 16-smallest SET (needed
        //     by pass B), upper = 16-largest bitonic (for rank extraction). ---
        #pragma unroll
        for (int q = 0; q < 16; ++q) { CEA(q, 16 + q); }
        // --- bitonic merge of upper 16, pruned to the cone of 20..29 ---
        #pragma unroll
        for (int q = 0; q < 8; ++q) { CEA(16 + q, 24 + q); }
        CEA(16, 20) CEA(17, 21) CEA(18, 22) CEA(19, 23)
        CEA(24, 28) CEA(25, 29) CEA(26, 30) CEA(27, 31)
        CEA(20, 22) CEA(21, 23) CEA(24, 26) CEA(25, 27) CEA(28, 30) CEA(29, 31)
        CEA(20, 21) CEA(22, 23) CEA(24, 25) CEA(26, 27) CEA(28, 29)
    }
    __syncthreads();                                              // S2

    // G,s reduce: 144 threads (9 components x 16 clouds)
    if (tid < CPB * 9) {
        int cc   = tid / 9;
        int comp = tid - cc * 9;
        if (base + cc < B) {
            float s = 0.0f;
            #pragma unroll
            for (int k = 0; k < NP; ++k) s += sb[cc * NP + k][comp];
            Gs[cc][comp] = s;
        }
    }
    __syncthreads();                                              // S3

    if (active) {
        const float4* cp = &ptsF[c * NP];
        const float thr_key = __uint_as_float(__float_as_uint(vals[20]) & ~31u);
        const float thr_d2  = thr_key + oo;                 // rank-20 d2
        const float scale   = sqrtf(thr_d2 + EPS) + EPS;
        const float inv_s   = __builtin_amdgcn_rcpf(scale);

        // cov of ALL 30 rels from cloud G,s:  C = G - s o^T - o s^T + 30 o o^T
        float4 g0 = *(const float4*)&Gs[c][0];   // gxx gxy gxz gyy
        float4 g1 = *(const float4*)&Gs[c][4];   // gyz gzz sx  sy
        float  sx = g1.z, sy = g1.w, sz = Gs[c][8];
        float ax = fmaf(30.f, ox, -sx);
        float ay = fmaf(30.f, oy, -sy);
        float az = fmaf(30.f, oz, -sz);
        float cxx = fmaf(ox, ax, fmaf(-sx, ox, g0.x));
        float cxy = fmaf(oy, ax, fmaf(-sy, ox, g0.y));
        float cxz = fmaf(oz, ax, fmaf(-sz, ox, g0.z));
        float cyy = fmaf(oy, ay, fmaf(-sy, oy, g0.w));
        float cyz = fmaf(oz, ay, fmaf(-sz, oy, g1.x));
        float czz = fmaf(oz, az, fmaf(-sz, oz, g1.y));

        // subtract the 9 excluded outer products (ranks 21..29, sorted upper)
        #pragma unroll
        for (int q2 = 21; q2 < 30; ++q2) {
            int idx = (int)(__float_as_uint(vals[q2]) & 31u);
            float4 p = cp[idx];
            float dx = p.x - ox, dy = p.y - oy, dz = p.z - oz;
            cxx = fmaf(-dx, dx, cxx); cxy = fmaf(-dx, dy, cxy); cxz = fmaf(-dx, dz, cxz);
            cyy = fmaf(-dy, dy, cyy); cyz = fmaf(-dy, dz, cyz); czz = fmaf(-dz, dz, czz);
        }

        // power iteration x8 == C^8 v0: trace-norm + 3 symmetric squarings
        float tr = cxx + cyy + czz + 1e-30f;
        float rt = __builtin_amdgcn_rcpf(tr);
        float xx = cxx*rt, xy = cxy*rt, xz = cxz*rt;
        float yy = cyy*rt, yz = cyz*rt, zz = czz*rt;
        #pragma unroll
        for (int it = 0; it < 3; ++it) {
            float nxx = fmaf(xx, xx, fmaf(xy, xy, xz * xz));
            float nxy = fmaf(xy, xx + yy, xz * yz);
            float nxz = fmaf(xz, xx + zz, xy * yz);
            float nyy = fmaf(xy, xy, fmaf(yy, yy, yz * yz));
            float nyz = fmaf(yz, yy + zz, xy * xz);
            float nzz = fmaf(xz, xz, fmaf(yz, yz, zz * zz));
            xx = nxx; xy = nxy; xz = nxz; yy = nyy; yz = nyz; zz = nzz;
        }
        float vx = xx + xy + xz;
        float vy = xy + yy + yz;
        float vz = xz + yz + zz;
        float nn = fmaf(vz, vz, fmaf(vy, vy, vx * vx)) + 1e-30f;
        float rr2 = __builtin_amdgcn_rsqf(nn) * inv_s * 2.0f;
        const float wax = vx * rr2, way = vy * rr2, waz = vz * rr2;
        const float c0  = 2.0f - fmaf(oz, waz, fmaf(oy, way, ox * wax));

        // pass B over the 21 SELECTED points: vals[0..15] = 16-nearest set,
        // vals[16..20] = ranks 16..20. Self among them, u ~= 2 (subtracted).
        float a0 = 0.f, a1 = 0.f, a3 = 0.f, s1 = 0.f;
        #pragma unroll
        for (int q = 0; q < 21; ++q) {
            int idx = (int)(__float_as_uint(vals[q]) & 31u);
            float4 p = cp[idx];
            float ur = fmaf(p.z, waz, fmaf(p.y, way, fmaf(p.x, wax, c0)));
            a0 += satf(1.0f - ur);               // ur >= -eps: no abs needed
            a1 += satf(1.0f - fabsf(ur - 1.0f));
            a3 += satf(1.0f - fabsf(ur - 3.0f));
            s1 += ur;
            if ((q % 5) == 4) asm volatile("" ::: "memory");
        }
        const float P  = 21.0f - a0 - a1 - a3;   // a2 + a4
        const float Q  = s1 - a1 - 3.0f * a3;    // 2*a2 + 4*a4
        const float a4 = fmaf(0.5f, Q, -P);
        const float a2 = P - a4 - 1.0f;          // self sits at u=2

        // sigmoid via exp2; W/b_dsc uniform scalar loads (SGPR operands)
        #pragma unroll
        for (int f = 0; f < FN; ++f) {
            float acc = fmaf(a0, W[0*FN+f],
                        fmaf(a1, W[1*FN+f],
                        fmaf(a2, W[2*FN+f],
                        fmaf(a3, W[3*FN+f],
                             a4 * W[4*FN+f]))));
            float bn = b_dsc[f] * (-1.4426950408889634f);        // -log2e * b
            float z2 = fmaf(acc, -0.07213475204444817f, bn);     // -log2e/20
            sb[tid][f] = __builtin_amdgcn_rcpf(1.0f + exp2f(z2));
        }
    }
    __syncthreads();                                              // S4

    // ys reduce (tid<160)
    if (tid < CPB * FN) {
        int c2 = tid / FN;
        float s = 0.0f;
        #pragma unroll
        for (int jj = 0; jj < NP; ++jj) s += sb[c2 * NP + jj][tid - c2 * FN];
        ysS[tid] = (base + c2 < B) ? s * (1.0f / (float)NP) : 0.0f;
    }
    __syncthreads();                                              // S5

    // layer 1: half 0 (waves 0-3) = clouds 0..7, half 1 (waves 4-7) = 8..15.
    {
        const int  hu    = tid & 255;
        const int  ybase = (w >= 4) ? 80 : 0;     // wave-uniform
        const int  rbase = (w >= 4) ? 8 : 0;
        float ya = ysS[ybase + lane];
        float yb = ysS[ybase + 64 + (lane & 15)];
        float wv[FN];
        #pragma unroll
        for (int f = 0; f < FN; ++f) wv[f] = w1[f * 256 + hu];
        float bb = b1[hu];
        #pragma unroll
        for (int cc = 0; cc < 8; ++cc) {
            float acc = bb;
            #pragma unroll
            for (int f = 0; f < FN; ++f) {
                const int flat = cc * FN + f;
                float yv = (flat < 64) ? rlanef(ya, flat) : rlanef(yb, flat - 64);
                acc = fmaf(yv, wv[f], acc);
            }
            float h = acc > 0.0f ? acc : __expf(acc) - 1.0f;
            hA[hA_idx(rbase + cc, hu)] = bf16r(h);
        }
    }
    __syncthreads();                                              // S6

    // layer 2: waves 0..2 each own one 16-col N-tile; B-frags global->regs.
    if (w < 3) {
        const int  n   = w * 16 + (lane & 15);
        const bool nok = n < 40;
        const int  kg  = (lane >> 4) * 8;
        float4v acc = {0.f, 0.f, 0.f, 0.f};
        #pragma unroll
        for (int s = 0; s < 8; ++s) {
            short8v bfr;
            #pragma unroll
            for (int j = 0; j < 8; ++j) {
                float f = nok ? w2[(s * 32 + kg + j) * 40 + n] : 0.0f;
                bfr[j] = (short)bf16r(f);
            }
            short8v a = *(const short8v*)&hA[hA_idx(lane & 15, kg + s * 32)];
            acc = __builtin_amdgcn_mfma_f32_16x16x32_bf16(a, bfr, acc, 0, 0, 0);
        }
        // C/D: col=lane&15 (our n), row=(lane>>4)*4+r  [m89-verified]
        if (nok) {
            const float bc = b2[n];
            const int   r0 = (lane >> 4) * 4;
            #pragma unroll
            for (int r = 0; r < 4; ++r) {
                Lg[r0 + r][n] = acc[r] + bc;
            }
        }
    }
    __syncthreads();                                              // S7

    // log_softmax: 16-lane group per cloud (tid<256)
    if (tid < CPB * 16) {
        int cl = tid >> 4, l = tid & 15;
        float v0 = Lg[cl][l];
        float v1 = Lg[cl][l + 16];
        float v2 = (l < 8) ? Lg[cl][l + 32] : -INFINITY;
        float m = fmaxf(fmaxf(v0, v1), v2);
        #pragma unroll
        for (int msk = 1; msk < 16; msk <<= 1) m = fmaxf(m, __shfl_xor(m, msk));
        float e = __expf(v0 - m) + __expf(v1 - m) + ((l < 8) ? __expf(v2 - m) : 0.0f);
        #pragma unroll
        for (int msk = 1; msk < 16; msk <<= 1) e += __shfl_xor(e, msk);
        float ls = m + __logf(e);
        int cloud = base + cl;
        if (cloud < B) {
            float* op = out + (size_t)cloud * 40;
            op[l]      = v0 - ls;
            op[16 + l] = v1 - ls;
            if (l < 8) op[32 + l] = v2 - ls;
        }
    }
}

extern "C" void kernel_launch(void* const* d_in, const int* in_sizes, int n_in,
                              void* d_out, int out_size, void* d_ws, size_t ws_size,
                              hipStream_t stream) {
    const float* pos   = (const float*)d_in[0];
    const float* W     = (const float*)d_in[1];
    const float* b_dsc = (const float*)d_in[2];
    const float* w1    = (const float*)d_in[3];
    const float* b1    = (const float*)d_in[4];
    const float* w2    = (const float*)d_in[5];
    const float* b2    = (const float*)d_in[6];

    const int N = in_sizes[0] / 3;   // B*NP points
    const int B = N / NP;            // clouds

    const int grid = (B + CPB - 1) / CPB;
    fused_kernel<<<grid, T1, 0, stream>>>(pos, W, b_dsc, w1, b1, w2, b2,
                                          (float*)d_out, B);
}

// Round 17
// 29.804 us; speedup vs baseline: 3.1999x; 1.0058x over previous
//
#include <hip/hip_runtime.h>
#include <math.h>

#define NP 30      // points per cloud
#define KNN 20     // neighbors
#define KS 5       // spline control points
#define FN 10      // filter count
#define EPS 1e-8f
#define CPB 16     // clouds per block (fills the 16-row MFMA A-tile)
#define T1 512     // block size (8 waves)

typedef __attribute__((ext_vector_type(8))) short short8v;
typedef __attribute__((ext_vector_type(4))) float float4v;

__device__ __forceinline__ float satf(float x) {
    return fminf(fmaxf(x, 0.0f), 1.0f);   // folds to clamp modifier
}
__device__ __forceinline__ unsigned short bf16r(float f) {   // f32 -> bf16 RNE
    unsigned u = __float_as_uint(f);
    u += 0x7fffu + ((u >> 16) & 1u);
    return (unsigned short)(u >> 16);
}
// hA swizzle: 16B granule g of row r -> g ^ (r&7); kills stride-512B conflicts
__device__ __forceinline__ int hA_idx(int row, int col) {
    return row * 256 + ((((col >> 3) ^ (row & 7)) << 3) | (col & 7));
}
// pack point index into low 5 mantissa bits (sort stays float-compare)
__device__ __forceinline__ float packdi(float v, int j) {
    return __uint_as_float((__float_as_uint(v) & ~31u) | (unsigned)j);
}

// compare-exchange helpers (ascending / descending)
#define CEA(A, B) { float a_ = vals[A], b_ = vals[B]; vals[A] = fminf(a_, b_); vals[B] = fmaxf(a_, b_); }
#define CED(A, B) { float a_ = vals[A], b_ = vals[B]; vals[A] = fmaxf(a_, b_); vals[B] = fminf(a_, b_); }

// Fused dsc -> MLP -> log_softmax. One 512-thread block = 16 clouds.
// R17: layer 1 moved to MFMA (was 160 readlane + 160 fma per thread on all
// 8 waves). ys staged as zero-padded bf16 A-tile [16][40]; each wave does
// 2 N-tiles: ds_read_b128 A-frag + clamped w1 B-frag loads + 1 MFMA + elu.
__global__ __launch_bounds__(T1, 4) void fused_kernel(
    const float* __restrict__ pos,     // [B*NP, 3]
    const float* __restrict__ W,       // [KS, FN]
    const float* __restrict__ b_dsc,   // [FN]
    const float* __restrict__ w1,      // [FN, 256]
    const float* __restrict__ b1,      // [256]
    const float* __restrict__ w2,      // [256, 40]
    const float* __restrict__ b2,      // [40]
    float* __restrict__ out,           // [B, 40]
    int B)
{
    __shared__ float4 ptsF[CPB * NP];                       // x,y,z,|p|^2
    __shared__ __align__(16) float sb[CPB * NP][12];        // outer-staging / sigmoid
    __shared__ __align__(16) float Gs[CPB][12];             // gxx..gzz sx sy sz
    __shared__ __align__(16) unsigned short ysbf[CPB * 40]; // bf16 ys A-tile, K-pad 40
    __shared__ __align__(16) unsigned short hA[16 * 256];   // bf16 A-tile (layer 2)
    __shared__ float Lg[CPB][48];

    const int tid  = threadIdx.x;
    const int base = blockIdx.x * CPB;
    const int w    = tid >> 6;
    const int lane = tid & 63;

    // stage: one point per thread (xyz + |p|^2)
    if (tid < CPB * NP) {
        int gp = base * NP + tid;
        if (gp < B * NP) {
            const float* pp = pos + (size_t)gp * 3;
            float x = pp[0], y = pp[1], z = pp[2];
            float n2 = fmaf(z, z, fmaf(y, y, x * x));
            ptsF[tid] = make_float4(x, y, z, n2);
        } else {
            ptsF[tid] = make_float4(0.f, 0.f, 0.f, 0.f);
        }
    }
    // zero ysbf (640 u16 = 320 u32); reduce overwrites f<10 slots after S4
    if (tid < 320) ((unsigned*)ysbf)[tid] = 0u;
    __syncthreads();                                              // S1

    const int c = tid / NP;
    const int i = tid - c * NP;
    const bool active = (tid < CPB * NP) && (base + c < B);

    float vals[32];
    float ox = 0.f, oy = 0.f, oz = 0.f, oo = 0.f;

    if (active) {
        const float4* cp = &ptsF[c * NP];
        float4 own = cp[i];                       // dynamic LDS read, once
        ox = own.x; oy = own.y; oz = own.z; oo = own.w;

        // own outer products + coords -> LDS (vectorized: 2x b128 + 1x b32)
        *(float4*)&sb[tid][0] = make_float4(ox * ox, ox * oy, ox * oz, oy * oy);
        *(float4*)&sb[tid][4] = make_float4(oy * oz, oz * oz, ox, oy);
        sb[tid][8] = oz;

        // keys: key_j = n2_j - 2 p_j.o  (3-fma form; monotone shift of d2)
        const float nx2 = -2.0f * ox, ny2 = -2.0f * oy, nz2 = -2.0f * oz;
        #pragma unroll
        for (int j = 0; j < NP; ++j) {
            float4 q = cp[j];
            float key = fmaf(q.z, nz2, fmaf(q.y, ny2, fmaf(q.x, nx2, q.w)));
            vals[j] = packdi(key, j);
            if ((j % 5) == 4) asm volatile("" ::: "memory");  // bound in-flight loads
        }
        vals[30] = packdi(1e11f, 30);
        vals[31] = packdi(1e11f, 31);

        // --- Batcher odd-even mergesort: lower 16 asc, upper 16 desc ---
        #pragma unroll
        for (int p = 1; p < 16; p <<= 1) {
            #pragma unroll
            for (int k = p; k >= 1; k >>= 1) {
                #pragma unroll
                for (int j = (k & (p - 1)); j + k < 16; j += 2 * k) {
                    #pragma unroll
                    for (int ii = 0; ii < k; ++ii) {
                        if (ii + j + k < 16 &&
                            ((ii + j) / (2 * p)) == ((ii + j + k) / (2 * p))) {
                            CEA(ii + j, ii + j + k);
                            CED(16 + ii + j, 16 + ii + j + k);
                        }
                    }
                }
            }
        }
        // --- bitonic k=32 split: BOTH sides (lower = 16-smallest SET) ---
        #pragma unroll
        for (int q = 0; q < 16; ++q) { CEA(q, 16 + q); }
        // --- bitonic merge of upper 16, pruned to the cone of 20..29 ---
        #pragma unroll
        for (int q = 0; q < 8; ++q) { CEA(16 + q, 24 + q); }
        CEA(16, 20) CEA(17, 21) CEA(18, 22) CEA(19, 23)
        CEA(24, 28) CEA(25, 29) CEA(26, 30) CEA(27, 31)
        CEA(20, 22) CEA(21, 23) CEA(24, 26) CEA(25, 27) CEA(28, 30) CEA(29, 31)
        CEA(20, 21) CEA(22, 23) CEA(24, 25) CEA(26, 27) CEA(28, 29)
    }
    __syncthreads();                                              // S2

    // G,s reduce: 144 threads (9 components x 16 clouds)
    if (tid < CPB * 9) {
        int cc   = tid / 9;
        int comp = tid - cc * 9;
        if (base + cc < B) {
            float s = 0.0f;
            #pragma unroll
            for (int k = 0; k < NP; ++k) s += sb[cc * NP + k][comp];
            Gs[cc][comp] = s;
        }
    }
    __syncthreads();                                              // S3

    if (active) {
        const float4* cp = &ptsF[c * NP];
        const float thr_key = __uint_as_float(__float_as_uint(vals[20]) & ~31u);
        const float thr_d2  = thr_key + oo;                 // rank-20 d2
        const float scale   = sqrtf(thr_d2 + EPS) + EPS;
        const float inv_s   = __builtin_amdgcn_rcpf(scale);

        // cov of ALL 30 rels from cloud G,s:  C = G - s o^T - o s^T + 30 o o^T
        float4 g0 = *(const float4*)&Gs[c][0];   // gxx gxy gxz gyy
        float4 g1 = *(const float4*)&Gs[c][4];   // gyz gzz sx  sy
        float  sx = g1.z, sy = g1.w, sz = Gs[c][8];
        float ax = fmaf(30.f, ox, -sx);
        float ay = fmaf(30.f, oy, -sy);
        float az = fmaf(30.f, oz, -sz);
        float cxx = fmaf(ox, ax, fmaf(-sx, ox, g0.x));
        float cxy = fmaf(oy, ax, fmaf(-sy, ox, g0.y));
        float cxz = fmaf(oz, ax, fmaf(-sz, ox, g0.z));
        float cyy = fmaf(oy, ay, fmaf(-sy, oy, g0.w));
        float cyz = fmaf(oz, ay, fmaf(-sz, oy, g1.x));
        float czz = fmaf(oz, az, fmaf(-sz, oz, g1.y));

        // subtract the 9 excluded outer products (ranks 21..29, sorted upper)
        #pragma unroll
        for (int q2 = 21; q2 < 30; ++q2) {
            int idx = (int)(__float_as_uint(vals[q2]) & 31u);
            float4 p = cp[idx];
            float dx = p.x - ox, dy = p.y - oy, dz = p.z - oz;
            cxx = fmaf(-dx, dx, cxx); cxy = fmaf(-dx, dy, cxy); cxz = fmaf(-dx, dz, cxz);
            cyy = fmaf(-dy, dy, cyy); cyz = fmaf(-dy, dz, cyz); czz = fmaf(-dz, dz, czz);
        }

        // power iteration x8 == C^8 v0: trace-norm + 3 symmetric squarings
        float tr = cxx + cyy + czz + 1e-30f;
        float rt = __builtin_amdgcn_rcpf(tr);
        float xx = cxx*rt, xy = cxy*rt, xz = cxz*rt;
        float yy = cyy*rt, yz = cyz*rt, zz = czz*rt;
        #pragma unroll
        for (int it = 0; it < 3; ++it) {
            float nxx = fmaf(xx, xx, fmaf(xy, xy, xz * xz));
            float nxy = fmaf(xy, xx + yy, xz * yz);
            float nxz = fmaf(xz, xx + zz, xy * yz);
            float nyy = fmaf(xy, xy, fmaf(yy, yy, yz * yz));
            float nyz = fmaf(yz, yy + zz, xy * xz);
            float nzz = fmaf(xz, xz, fmaf(yz, yz, zz * zz));
            xx = nxx; xy = nxy; xz = nxz; yy = nyy; yz = nyz; zz = nzz;
        }
        float vx = xx + xy + xz;
        float vy = xy + yy + yz;
        float vz = xz + yz + zz;
        float nn = fmaf(vz, vz, fmaf(vy, vy, vx * vx)) + 1e-30f;
        float rr2 = __builtin_amdgcn_rsqf(nn) * inv_s * 2.0f;
        const float wax = vx * rr2, way = vy * rr2, waz = vz * rr2;
        const float c0  = 2.0f - fmaf(oz, waz, fmaf(oy, way, ox * wax));

        // pass B over the 21 SELECTED points: vals[0..15] = 16-nearest set,
        // vals[16..20] = ranks 16..20. Self among them, u ~= 2 (subtracted).
        float a0 = 0.f, a1 = 0.f, a3 = 0.f, s1 = 0.f;
        #pragma unroll
        for (int q = 0; q < 21; ++q) {
            int idx = (int)(__float_as_uint(vals[q]) & 31u);
            float4 p = cp[idx];
            float ur = fmaf(p.z, waz, fmaf(p.y, way, fmaf(p.x, wax, c0)));
            a0 += satf(1.0f - ur);               // ur >= -eps: no abs needed
            a1 += satf(1.0f - fabsf(ur - 1.0f));
            a3 += satf(1.0f - fabsf(ur - 3.0f));
            s1 += ur;
            if ((q % 5) == 4) asm volatile("" ::: "memory");
        }
        const float P  = 21.0f - a0 - a1 - a3;   // a2 + a4
        const float Q  = s1 - a1 - 3.0f * a3;    // 2*a2 + 4*a4
        const float a4 = fmaf(0.5f, Q, -P);
        const float a2 = P - a4 - 1.0f;          // self sits at u=2

        // sigmoid via exp2; W/b_dsc uniform scalar loads (SGPR operands)
        #pragma unroll
        for (int f = 0; f < FN; ++f) {
            float acc = fmaf(a0, W[0*FN+f],
                        fmaf(a1, W[1*FN+f],
                        fmaf(a2, W[2*FN+f],
                        fmaf(a3, W[3*FN+f],
                             a4 * W[4*FN+f]))));
            float bn = b_dsc[f] * (-1.4426950408889634f);        // -log2e * b
            float z2 = fmaf(acc, -0.07213475204444817f, bn);     // -log2e/20
            sb[tid][f] = __builtin_amdgcn_rcpf(1.0f + exp2f(z2));
        }
    }
    __syncthreads();                                              // S4

    // ys reduce (tid<160) -> bf16 into the zero-padded A-tile
    if (tid < CPB * FN) {
        int c2 = tid / FN;
        int f  = tid - c2 * FN;
        float s = 0.0f;
        #pragma unroll
        for (int jj = 0; jj < NP; ++jj) s += sb[c2 * NP + jj][f];
        float ym = (base + c2 < B) ? s * (1.0f / (float)NP) : 0.0f;
        ysbf[c2 * 40 + f] = bf16r(ym);
    }
    __syncthreads();                                              // S5

    // layer 1 via MFMA: h[16][256] = ys[16][10pad32] @ w1[10][256] + b1; elu.
    // Each wave: 2 N-tiles. A-frag: lane holds ysbf[m=lane&15][k=kg..kg+7].
    {
        const int kg = (lane >> 4) * 8;
        short8v a = *(const short8v*)&ysbf[(lane & 15) * 40 + kg];
        #pragma unroll
        for (int t2 = 0; t2 < 2; ++t2) {
            const int n = (w * 2 + t2) * 16 + (lane & 15);
            short8v bfr;
            #pragma unroll
            for (int j = 0; j < 8; ++j) {
                int k = kg + j;
                float f = (k < FN) ? w1[k * 256 + n] : 0.0f;
                bfr[j] = (short)bf16r(f);
            }
            float4v acc = {0.f, 0.f, 0.f, 0.f};
            acc = __builtin_amdgcn_mfma_f32_16x16x32_bf16(a, bfr, acc, 0, 0, 0);
            // C/D: col=lane&15 -> n-within-tile; row=(lane>>4)*4+r -> cloud
            const float bb = b1[n];
            #pragma unroll
            for (int r = 0; r < 4; ++r) {
                int cl = (lane >> 4) * 4 + r;
                float h = acc[r] + bb;
                h = h > 0.0f ? h : __expf(h) - 1.0f;
                hA[hA_idx(cl, n)] = bf16r(h);
            }
        }
    }
    __syncthreads();                                              // S6

    // layer 2: waves 0..2 each own one 16-col N-tile; B-frags global->regs.
    if (w < 3) {
        const int  n   = w * 16 + (lane & 15);
        const bool nok = n < 40;
        const int  kg  = (lane >> 4) * 8;
        float4v acc = {0.f, 0.f, 0.f, 0.f};
        #pragma unroll
        for (int s = 0; s < 8; ++s) {
            short8v bfr;
            #pragma unroll
            for (int j = 0; j < 8; ++j) {
                float f = nok ? w2[(s * 32 + kg + j) * 40 + n] : 0.0f;
                bfr[j] = (short)bf16r(f);
            }
            short8v a = *(const short8v*)&hA[hA_idx(lane & 15, kg + s * 32)];
            acc = __builtin_amdgcn_mfma_f32_16x16x32_bf16(a, bfr, acc, 0, 0, 0);
        }
        // C/D: col=lane&15 (our n), row=(lane>>4)*4+r  [m89-verified]
        if (nok) {
            const float bc = b2[n];
            const int   r0 = (lane >> 4) * 4;
            #pragma unroll
            for (int r = 0; r < 4; ++r) {
                Lg[r0 + r][n] = acc[r] + bc;
            }
        }
    }
    __syncthreads();                                              // S7

    // log_softmax: 16-lane group per cloud (tid<256)
    if (tid < CPB * 16) {
        int cl = tid >> 4, l = tid & 15;
        float v0 = Lg[cl][l];
        float v1 = Lg[cl][l + 16];
        float v2 = (l < 8) ? Lg[cl][l + 32] : -INFINITY;
        float m = fmaxf(fmaxf(v0, v1), v2);
        #pragma unroll
        for (int msk = 1; msk < 16; msk <<= 1) m = fmaxf(m, __shfl_xor(m, msk));
        float e = __expf(v0 - m) + __expf(v1 - m) + ((l < 8) ? __expf(v2 - m) : 0.0f);
        #pragma unroll
        for (int msk = 1; msk < 16; msk <<= 1) e += __shfl_xor(e, msk);
        float ls = m + __logf(e);
        int cloud = base + cl;
        if (cloud < B) {
            float* op = out + (size_t)cloud * 40;
            op[l]      = v0 - ls;
            op[16 + l] = v1 - ls;
            if (l < 8) op[32 + l] = v2 - ls;
        }
    }
}

extern "C" void kernel_launch(void* const* d_in, const int* in_sizes, int n_in,
                              void* d_out, int out_size, void* d_ws, size_t ws_size,
                              hipStream_t stream) {
    const float* pos   = (const float*)d_in[0];
    const float* W     = (const float*)d_in[1];
    const float* b_dsc = (const float*)d_in[2];
    const float* w1    = (const float*)d_in[3];
    const float* b1    = (const float*)d_in[4];
    const float* w2    = (const float*)d_in[5];
    const float* b2    = (const float*)d_in[6];

    const int N = in_sizes[0] / 3;   // B*NP points
    const int B = N / NP;            // clouds

    const int grid = (B + CPB - 1) / CPB;
    fused_kernel<<<grid, T1, 0, stream>>>(pos, W, b_dsc, w1, b1, w2, b2,
                                          (float*)d_out, B);
}